// Round 1
// baseline (4417.961 us; speedup 1.0000x reference)
//
#include <hip/hip_runtime.h>
#include <cstdint>
#include <cstddef>
#include <math.h>

#define KNN 7

// ---------------- workspace layout (in floats) ----------------
static const size_t OFF_ARENA = 0;          // 10,240,000  patches / U / inner0
static const size_t OFF_XS0   = 10240000;   // 10,240,000
static const size_t OFF_XS1   = 20480000;   //  2,560,000
static const size_t OFF_LAST  = 23040000;   //  2,560,000  score (GNN) / last (FPN)
static const size_t OFF_EMB   = 25600000;   //    409,600
static const size_t OFF_EMB2  = 26009600;   //    409,600
static const size_t OFF_XL    = 26419200;   //  3,276,800
static const size_t OFF_XR    = 29696000;   //  3,276,800
static const size_t OFF_H1    = 32972800;   //  3,276,800
static const size_t OFF_XL2   = 36249600;   //    409,600
static const size_t OFF_XR2   = 36659200;   //    409,600
static const size_t OFF_CAT   = 37068800;   //    819,200
static const size_t OFF_HC    = 37888000;   //    409,600
static const size_t OFF_E     = 38297600;   //    102,400
static const size_t OFF_SRCF  = 38400000;   //     11,200 ints
static const size_t OFF_SRCS  = 38411200;   //     11,200 ints
// total ~154 MB

// ============================ generic tiled GEMM ============================
// C[M,N] = A[M,K] * B  (+bias, act, +Dmat). A row-major, K % 16 == 0.
// BT_NT: B is [N,K] row-major (dot of rows). BT_NN: B is [K,N]. BT_CONV: B is
// an image [Cin,imH,imW], K = Cin*9, implicit im2col for 3x3 SAME conv.
enum { BT_NT = 0, BT_NN = 1, BT_CONV = 2 };

template<int BT, int ACT, int BAX, bool ADDMAT>
__global__ __launch_bounds__(256)
void gemm_k(const float* __restrict__ A, const float* __restrict__ B,
            const float* __restrict__ bias, const float* __restrict__ Dmat, int Dld,
            float* __restrict__ C, int M, int N, int K, int imH, int imW)
{
    __shared__ float As[16][68];   // [k][m], stride 68 keeps float4 reads conflict-light
    __shared__ float Bs[16][68];   // [k][n]
    const int tid = threadIdx.x;
    const int bm0 = blockIdx.y * 64;
    const int bn0 = blockIdx.x * 64;
    const int tx = tid & 15, ty = tid >> 4;
    const int lrow = tid >> 2;         // 0..63
    const int lk4  = (tid & 3) << 2;   // 0,4,8,12
    const int bkr  = tid >> 4;         // 0..15
    const int bn4  = (tid & 15) << 2;  // 0..60
    float acc[4][4] = {{0.f,0.f,0.f,0.f},{0.f,0.f,0.f,0.f},{0.f,0.f,0.f,0.f},{0.f,0.f,0.f,0.f}};

    for (int k0 = 0; k0 < K; k0 += 16) {
        {   // A tile
            const int m = bm0 + lrow;
            float4 v = {0.f, 0.f, 0.f, 0.f};
            if (m < M) v = *(const float4*)(A + (size_t)m * K + (k0 + lk4));
            As[lk4 + 0][lrow] = v.x; As[lk4 + 1][lrow] = v.y;
            As[lk4 + 2][lrow] = v.z; As[lk4 + 3][lrow] = v.w;
        }
        if (BT == BT_NT) {
            const int nn = bn0 + lrow;
            float4 v = {0.f, 0.f, 0.f, 0.f};
            if (nn < N) v = *(const float4*)(B + (size_t)nn * K + (k0 + lk4));
            Bs[lk4 + 0][lrow] = v.x; Bs[lk4 + 1][lrow] = v.y;
            Bs[lk4 + 2][lrow] = v.z; Bs[lk4 + 3][lrow] = v.w;
        } else if (BT == BT_NN) {
            const int kk = k0 + bkr;
            const int nn = bn0 + bn4;
            float4 v = {0.f, 0.f, 0.f, 0.f};
            if (nn + 3 < N) {
                v = *(const float4*)(B + (size_t)kk * N + nn);
            } else if (nn < N) {
                const float* p = B + (size_t)kk * N;
                v.x = p[nn];
                if (nn + 1 < N) v.y = p[nn + 1];
                if (nn + 2 < N) v.z = p[nn + 2];
            }
            *(float4*)&Bs[bkr][bn4] = v;
        } else { // BT_CONV: implicit im2col, 3x3 SAME
            const int kk = k0 + bkr;
            const int c = kk / 9;
            const int j = kk - c * 9;
            const int dy = j / 3 - 1;
            const int dx = j - (j / 3) * 3 - 1;
            const float* img = B + (size_t)c * imH * imW;
            #pragma unroll
            for (int u = 0; u < 4; u++) {
                const int p = bn0 + bn4 + u;
                float val = 0.f;
                if (p < N) {
                    const int py = p / imW;
                    const int y = py + dy;
                    const int x = (p - py * imW) + dx;
                    if (y >= 0 && y < imH && x >= 0 && x < imW) val = img[y * imW + x];
                }
                Bs[bkr][bn4 + u] = val;
            }
        }
        __syncthreads();
        #pragma unroll
        for (int k = 0; k < 16; k++) {
            const float4 av = *(const float4*)&As[k][ty << 2];
            const float4 bv = *(const float4*)&Bs[k][tx << 2];
            const float a0 = av.x, a1 = av.y, a2 = av.z, a3 = av.w;
            const float b0 = bv.x, b1 = bv.y, b2 = bv.z, b3 = bv.w;
            acc[0][0] = fmaf(a0,b0,acc[0][0]); acc[0][1] = fmaf(a0,b1,acc[0][1]);
            acc[0][2] = fmaf(a0,b2,acc[0][2]); acc[0][3] = fmaf(a0,b3,acc[0][3]);
            acc[1][0] = fmaf(a1,b0,acc[1][0]); acc[1][1] = fmaf(a1,b1,acc[1][1]);
            acc[1][2] = fmaf(a1,b2,acc[1][2]); acc[1][3] = fmaf(a1,b3,acc[1][3]);
            acc[2][0] = fmaf(a2,b0,acc[2][0]); acc[2][1] = fmaf(a2,b1,acc[2][1]);
            acc[2][2] = fmaf(a2,b2,acc[2][2]); acc[2][3] = fmaf(a2,b3,acc[2][3]);
            acc[3][0] = fmaf(a3,b0,acc[3][0]); acc[3][1] = fmaf(a3,b1,acc[3][1]);
            acc[3][2] = fmaf(a3,b2,acc[3][2]); acc[3][3] = fmaf(a3,b3,acc[3][3]);
        }
        __syncthreads();
    }
    #pragma unroll
    for (int i = 0; i < 4; i++) {
        const int m = bm0 + (ty << 2) + i;
        if (m >= M) continue;
        #pragma unroll
        for (int jj = 0; jj < 4; jj++) {
            const int nn = bn0 + (tx << 2) + jj;
            if (nn >= N) continue;
            float v = acc[i][jj];
            if (bias != nullptr) v += (BAX == 0) ? bias[m] : bias[nn];
            if (ACT == 1) v = fmaxf(v, 0.f);
            if (ADDMAT) v += Dmat[(size_t)m * Dld + nn];
            C[(size_t)m * N + nn] = v;
        }
    }
}

template<int BT, int ACT, int BAX, bool ADDMAT>
static inline void gemm(hipStream_t s, const float* A, const float* B, const float* bias,
                        const float* D, int Dld, float* C, int M, int N, int K,
                        int imH = 0, int imW = 0)
{
    dim3 g((N + 63) / 64, (M + 63) / 64);
    gemm_k<BT, ACT, BAX, ADDMAT><<<g, dim3(256), 0, s>>>(A, B, bias, D, Dld, C, M, N, K, imH, imW);
}

// ============================ small kernels ============================

// patches[p, c*25+a*5+b] = f[c, (p/nw)*5+a, (p%nw)*5+b]
__global__ void extract_patches_k(const float* __restrict__ f, float* __restrict__ patches,
                                  int nw, int H, int total)
{
    int idx = blockIdx.x * 256 + threadIdx.x;
    if (idx >= total) return;
    int q = idx % 6400;
    int p = idx / 6400;
    int c = q / 25;
    int rem = q - c * 25;
    int a = rem / 5, b = rem - (rem / 5) * 5;
    int ih = p / nw, iw = p - (p / nw) * nw;
    patches[idx] = f[(size_t)c * H * H + (size_t)(ih * 5 + a) * H + (iw * 5 + b)];
}

// per-row top-7 of score, tie-break smallest index (XLA TopK stability);
// srcCols[r*7+s] = col if (col>row && val!=0) else -1
__global__ void topk_feat_k(const float* __restrict__ score, int* __restrict__ srcCols, int n)
{
    const int r = blockIdx.x;
    const int lane = threadIdx.x;
    const float* row = score + (size_t)r * n;
    int   sel[KNN];
    float selv[KNN];
    #pragma unroll
    for (int t = 0; t < KNN; t++) {
        float best = -__builtin_huge_valf();
        int   bidx = 0x7fffffff;
        for (int c = lane; c < n; c += 64) {
            bool taken = false;
            #pragma unroll
            for (int u = 0; u < KNN; u++)
                if (u < t && sel[u] == c) taken = true;
            if (taken) continue;
            float v = row[c];
            if (v > best || (v == best && c < bidx)) { best = v; bidx = c; }
        }
        #pragma unroll
        for (int off = 32; off > 0; off >>= 1) {
            float ov = __shfl_down(best, off);
            int   oi = __shfl_down(bidx, off);
            if (ov > best || (ov == best && oi < bidx)) { best = ov; bidx = oi; }
        }
        best = __shfl(best, 0);
        bidx = __shfl(bidx, 0);
        sel[t] = bidx; selv[t] = best;
    }
    if (lane < KNN) {
        int c = -1; float v = 0.f;
        #pragma unroll
        for (int t = 0; t < KNN; t++)
            if (lane == t) { c = sel[t]; v = selv[t]; }
        srcCols[r * KNN + lane] = (c > r && v != 0.0f) ? c : -1;
    }
}

// spatial top-7 nearest (top_k of -dist): exact integer squared distances,
// tie-break smallest index via key = (d2<<11)|c. val!=0 <=> c!=r (subsumed by c>r).
__global__ void topk_spatial_k(int* __restrict__ srcCols, int n, int nw)
{
    const int r = blockIdx.x;
    const int lane = threadIdx.x;
    const int ri = r / nw, rj = r - (r / nw) * nw;
    int sel[KNN];
    #pragma unroll
    for (int t = 0; t < KNN; t++) {
        int bkey = 0x7fffffff;
        for (int c = lane; c < n; c += 64) {
            bool taken = false;
            #pragma unroll
            for (int u = 0; u < KNN; u++)
                if (u < t && sel[u] == c) taken = true;
            if (taken) continue;
            const int ci = c / nw, cj = c - (c / nw) * nw;
            const int dy = (ri - ci) * 5, dx = (rj - cj) * 5;
            const int d2 = dy * dy + dx * dx;
            const int key = (d2 << 11) | c;
            if (key < bkey) bkey = key;
        }
        #pragma unroll
        for (int off = 32; off > 0; off >>= 1) {
            int ok = __shfl_down(bkey, off);
            if (ok < bkey) bkey = ok;
        }
        bkey = __shfl(bkey, 0);
        sel[t] = bkey & 2047;
    }
    if (lane < KNN) {
        int c = -1;
        #pragma unroll
        for (int t = 0; t < KNN; t++) if (lane == t) c = sel[t];
        srcCols[r * KNN + lane] = (c > r) ? c : -1;
    }
}

// e[(r*8+s)*H+h] = sum_d leakyrelu(xl[src,h,d]+xr[r,h,d], 0.2) * att[h,d]
// s in [0,7): candidate (skip if masked); s==7: self loop. D = 256.
__global__ void gat_logits_k(const float* __restrict__ xl, const float* __restrict__ xr,
                             const float* __restrict__ att, const int* __restrict__ srcCols,
                             float* __restrict__ e, int n, int H)
{
    const int wid = (blockIdx.x * blockDim.x + threadIdx.x) >> 6;
    const int lane = threadIdx.x & 63;
    if (wid >= n * 8 * H) return;
    const int h = wid % H;
    const int es = wid / H;          // r*8 + s
    const int r = es >> 3, s = es & 7;
    int src;
    if (s == 7) src = r;
    else { src = srcCols[r * KNN + s]; if (src < 0) return; }
    const float* pl = xl + ((size_t)src * H + h) * 256;
    const float* pr = xr + ((size_t)r * H + h) * 256;
    const float* pa = att + (size_t)h * 256;
    float sum = 0.f;
    #pragma unroll
    for (int it = 0; it < 4; it++) {
        const int d = lane + it * 64;
        float m = pl[d] + pr[d];
        m = (m > 0.f) ? m : 0.2f * m;
        sum += m * pa[d];
    }
    #pragma unroll
    for (int off = 32; off > 0; off >>= 1) sum += __shfl_down(sum, off);
    if (lane == 0) e[(size_t)es * H + h] = sum;
}

// per (node,head) softmax over (valid candidates + self) then aggregate xl[src],
// + bias, ELU. One wave per (r,h); lane covers 4 consecutive d.
__global__ void gat_aggregate_k(const float* __restrict__ xl, const float* __restrict__ e,
                                const int* __restrict__ srcCols, const float* __restrict__ bias,
                                float* __restrict__ out, int n, int H, int ostride, int ooff)
{
    const int wid = (blockIdx.x * blockDim.x + threadIdx.x) >> 6;
    const int lane = threadIdx.x & 63;
    if (wid >= n * H) return;
    const int h = wid % H;
    const int r = wid / H;
    const float eself = e[(size_t)(r * 8 + 7) * H + h];
    float mx = eself;
    #pragma unroll
    for (int ss = 0; ss < KNN; ss++) {
        const int c = srcCols[r * KNN + ss];
        if (c >= 0) mx = fmaxf(mx, e[(size_t)(r * 8 + ss) * H + h]);
    }
    float denom = expf(eself - mx);
    #pragma unroll
    for (int ss = 0; ss < KNN; ss++) {
        const int c = srcCols[r * KNN + ss];
        if (c >= 0) denom += expf(e[(size_t)(r * 8 + ss) * H + h] - mx);
    }
    const float inv = 1.f / (denom + 1e-16f);
    const int d0 = lane << 2;
    float o0, o1, o2, o3;
    {
        const float a = expf(eself - mx) * inv;
        const float4 v = *(const float4*)(xl + ((size_t)r * H + h) * 256 + d0);
        o0 = a * v.x; o1 = a * v.y; o2 = a * v.z; o3 = a * v.w;
    }
    #pragma unroll
    for (int ss = 0; ss < KNN; ss++) {
        const int c = srcCols[r * KNN + ss];
        if (c < 0) continue;
        const float a = expf(e[(size_t)(r * 8 + ss) * H + h] - mx) * inv;
        const float4 v = *(const float4*)(xl + ((size_t)c * H + h) * 256 + d0);
        o0 = fmaf(a, v.x, o0); o1 = fmaf(a, v.y, o1);
        o2 = fmaf(a, v.z, o2); o3 = fmaf(a, v.w, o3);
    }
    const float* bb = bias + (size_t)h * 256 + d0;
    o0 += bb[0]; o1 += bb[1]; o2 += bb[2]; o3 += bb[3];
    o0 = (o0 > 0.f) ? o0 : (expf(o0) - 1.f);
    o1 = (o1 > 0.f) ? o1 : (expf(o1) - 1.f);
    o2 = (o2 > 0.f) ? o2 : (expf(o2) - 1.f);
    o3 = (o3 > 0.f) ? o3 : (expf(o3) - 1.f);
    float4 res = {o0, o1, o2, o3};
    *(float4*)(out + (size_t)r * ostride + ooff + (size_t)h * 256 + d0) = res;
}

// xs[o,y,x] = f[o,y,x] + relu(U[p, o*25 + (y%5)*5 + (x%5)] + b[o]),
// p = (x/5)*nw + (y/5)   <- reference's swapdims spatial transpose
__global__ void scatter_convT_k(const float* __restrict__ f, const float* __restrict__ U,
                                const float* __restrict__ bias, float* __restrict__ xs,
                                int nw, int H, int total)
{
    int idx = blockIdx.x * 256 + threadIdx.x;
    if (idx >= total) return;
    int x = idx % H;
    int t = idx / H;
    int y = t % H;
    int o = t / H;
    int j = y / 5, a = y - j * 5;
    int i = x / 5, b = x - i * 5;
    int p = i * nw + j;
    float v = U[(size_t)p * 6400 + o * 25 + a * 5 + b] + bias[o];
    v = fmaxf(v, 0.f);
    xs[idx] = f[idx] + v;
}

__global__ void upsample_add_k(float* __restrict__ acc, const float* __restrict__ last,
                               int H, int Hs, int total)
{
    int idx = blockIdx.x * 256 + threadIdx.x;
    if (idx >= total) return;
    int x = idx % H;
    int t = idx / H;
    int y = t % H;
    int c = t / H;
    acc[idx] += last[(size_t)c * Hs * Hs + (size_t)(y >> 1) * Hs + (x >> 1)];
}

// ============================ orchestration ============================
static void run_level(void* const* d_in, float* ws, int l, int H, hipStream_t s)
{
    const float* f = (const float*)d_in[l];   // d_in[0]=feat0, d_in[1]=feat1
    const int nh = H / 5, nw = nh, n = nh * nw, HW = H * H;

    const float* convT_w = (const float*)d_in[6]  + (size_t)l * 1638400;
    const float* convT_b = (const float*)d_in[7]  + l * 256;
    const float* conv1_w = (const float*)d_in[8]  + (size_t)l * 1638400;
    const float* conv1_b = (const float*)d_in[9]  + l * 256;
    const float* fc2_w   = (const float*)d_in[10] + (size_t)l * 65536;
    const float* fc2_b   = (const float*)d_in[11] + l * 256;
    const float* fc3_w   = (const float*)d_in[12] + (size_t)l * 131072;
    const float* fc3_b   = (const float*)d_in[13] + l * 256;
    const float* g1_wl   = (const float*)d_in[14] + (size_t)l * 524288;
    const float* g1_bl   = (const float*)d_in[15] + l * 2048;
    const float* g1_wr   = (const float*)d_in[16] + (size_t)l * 524288;
    const float* g1_br   = (const float*)d_in[17] + l * 2048;
    const float* g1_att  = (const float*)d_in[18] + l * 2048;
    const float* g1_bias = (const float*)d_in[19] + l * 2048;
    const float* g2_wl   = (const float*)d_in[20] + (size_t)l * 524288;
    const float* g2_bl   = (const float*)d_in[21] + l * 256;
    const float* g2_wr   = (const float*)d_in[22] + (size_t)l * 524288;
    const float* g2_br   = (const float*)d_in[23] + l * 256;
    const float* g2_att  = (const float*)d_in[24] + l * 256;
    const float* g2_bias = (const float*)d_in[25] + l * 256;
    const float* g3_wl   = (const float*)d_in[26] + (size_t)l * 524288;
    const float* g3_bl   = (const float*)d_in[27] + l * 2048;
    const float* g3_wr   = (const float*)d_in[28] + (size_t)l * 524288;
    const float* g3_br   = (const float*)d_in[29] + l * 2048;
    const float* g3_att  = (const float*)d_in[30] + l * 2048;
    const float* g3_bias = (const float*)d_in[31] + l * 2048;
    const float* g4_wl   = (const float*)d_in[32] + (size_t)l * 524288;
    const float* g4_bl   = (const float*)d_in[33] + l * 256;
    const float* g4_wr   = (const float*)d_in[34] + (size_t)l * 524288;
    const float* g4_br   = (const float*)d_in[35] + l * 256;
    const float* g4_att  = (const float*)d_in[36] + l * 256;
    const float* g4_bias = (const float*)d_in[37] + l * 256;

    float* patches = ws + OFF_ARENA;   // also U
    float* xs    = ws + (l == 0 ? OFF_XS0 : OFF_XS1);
    float* emb   = ws + OFF_EMB;
    float* emb2  = ws + OFF_EMB2;
    float* score = ws + OFF_LAST;
    float* xl    = ws + OFF_XL;
    float* xr    = ws + OFF_XR;
    float* h1    = ws + OFF_H1;        // g1 out, then g3 out (t1)
    float* xl2   = ws + OFF_XL2;
    float* xr2   = ws + OFF_XR2;
    float* cat   = ws + OFF_CAT;       // [:, :256] = h (g2 out), [:, 256:] = h2 (g4 out)
    float* hc    = ws + OFF_HC;
    float* ebuf  = ws + OFF_E;
    int* srcF = (int*)(ws + OFF_SRCF);
    int* srcS = (int*)(ws + OFF_SRCS);

    { int tot = n * 6400;
      extract_patches_k<<<dim3((tot + 255) / 256), dim3(256), 0, s>>>(f, patches, nw, H, tot); }

    gemm<BT_NT, 1, 1, false>(s, patches, conv1_w, conv1_b, nullptr, 0, emb, n, 256, 6400);
    gemm<BT_NT, 1, 1, false>(s, emb, fc2_w, fc2_b, nullptr, 0, emb2, n, 256, 256);
    gemm<BT_NT, 0, 1, false>(s, emb2, emb2, nullptr, nullptr, 0, score, n, n, 256);
    topk_feat_k<<<dim3(n), dim3(64), 0, s>>>(score, srcF, n);

    // g1: feature graph, emb2 -> h1 [n,2048], heads=8
    gemm<BT_NN, 0, 1, false>(s, emb2, g1_wl, g1_bl, nullptr, 0, xl, n, 2048, 256);
    gemm<BT_NN, 0, 1, false>(s, emb2, g1_wr, g1_br, nullptr, 0, xr, n, 2048, 256);
    { int tw = n * 8 * 8;
      gat_logits_k<<<dim3((tw + 3) / 4), dim3(256), 0, s>>>(xl, xr, g1_att, srcF, ebuf, n, 8);
      int aw = n * 8;
      gat_aggregate_k<<<dim3((aw + 3) / 4), dim3(256), 0, s>>>(xl, ebuf, srcF, g1_bias, h1, n, 8, 2048, 0); }

    // g2: feature graph, h1 -> cat[:, :256], heads=1
    gemm<BT_NN, 0, 1, false>(s, h1, g2_wl, g2_bl, nullptr, 0, xl2, n, 256, 2048);
    gemm<BT_NN, 0, 1, false>(s, h1, g2_wr, g2_br, nullptr, 0, xr2, n, 256, 2048);
    { int tw = n * 8;
      gat_logits_k<<<dim3((tw + 3) / 4), dim3(256), 0, s>>>(xl2, xr2, g2_att, srcF, ebuf, n, 1);
      int aw = n;
      gat_aggregate_k<<<dim3((aw + 3) / 4), dim3(256), 0, s>>>(xl2, ebuf, srcF, g2_bias, cat, n, 1, 512, 0); }

    topk_spatial_k<<<dim3(n), dim3(64), 0, s>>>(srcS, n, nw);

    // g3: spatial graph, emb2 -> h1 (t1) [n,2048], heads=8
    gemm<BT_NN, 0, 1, false>(s, emb2, g3_wl, g3_bl, nullptr, 0, xl, n, 2048, 256);
    gemm<BT_NN, 0, 1, false>(s, emb2, g3_wr, g3_br, nullptr, 0, xr, n, 2048, 256);
    { int tw = n * 8 * 8;
      gat_logits_k<<<dim3((tw + 3) / 4), dim3(256), 0, s>>>(xl, xr, g3_att, srcS, ebuf, n, 8);
      int aw = n * 8;
      gat_aggregate_k<<<dim3((aw + 3) / 4), dim3(256), 0, s>>>(xl, ebuf, srcS, g3_bias, h1, n, 8, 2048, 0); }

    // g4: spatial graph, h1 -> cat[:, 256:], heads=1
    gemm<BT_NN, 0, 1, false>(s, h1, g4_wl, g4_bl, nullptr, 0, xl2, n, 256, 2048);
    gemm<BT_NN, 0, 1, false>(s, h1, g4_wr, g4_br, nullptr, 0, xr2, n, 256, 2048);
    { int tw = n * 8;
      gat_logits_k<<<dim3((tw + 3) / 4), dim3(256), 0, s>>>(xl2, xr2, g4_att, srcS, ebuf, n, 1);
      int aw = n;
      gat_aggregate_k<<<dim3((aw + 3) / 4), dim3(256), 0, s>>>(xl2, ebuf, srcS, g4_bias, cat, n, 1, 512, 256); }

    // hc = relu(cat @ fc3_w^T + fc3_b) + h2
    gemm<BT_NT, 1, 1, true>(s, cat, fc3_w, fc3_b, cat + 256, 512, hc, n, 256, 512);
    // U[p, o*25+a*5+b] = hc @ convT_w (viewed [256, 6400] NN)
    gemm<BT_NN, 0, 1, false>(s, hc, convT_w, nullptr, nullptr, 0, patches, n, 6400, 256);
    { int tot = 256 * HW;
      scatter_convT_k<<<dim3((tot + 255) / 256), dim3(256), 0, s>>>(f, patches, convT_b, xs, nw, H, tot); }
}

extern "C" void kernel_launch(void* const* d_in, const int* in_sizes, int n_in,
                              void* d_out, int out_size, void* d_ws, size_t ws_size,
                              hipStream_t stream)
{
    float* ws  = (float*)d_ws;
    float* out = (float*)d_out;

    run_level(d_in, ws, 0, 200, stream);
    run_level(d_in, ws, 1, 100, stream);

    const float* inner_w = (const float*)d_in[2];
    const float* inner_b = (const float*)d_in[3];
    const float* layer_w = (const float*)d_in[4];
    const float* layer_b = (const float*)d_in[5];
    float* xs0    = ws + OFF_XS0;
    float* xs1    = ws + OFF_XS1;
    float* last   = ws + OFF_LAST;
    float* inner0 = ws + OFF_ARENA;

    // last = conv1x1(xs1, inner_w[1]); out1 = conv3x3(last, layer_w[1])
    gemm<BT_NN, 0, 0, false>(stream, inner_w + 65536, xs1, inner_b + 256, nullptr, 0,
                             last, 256, 10000, 256);
    gemm<BT_CONV, 0, 0, false>(stream, layer_w + 589824, last, layer_b + 256, nullptr, 0,
                               out + 10240000, 256, 10000, 2304, 100, 100);
    // inner0 = conv1x1(xs0, inner_w[0]); inner0 += nearest(last); out0 = conv3x3
    gemm<BT_NN, 0, 0, false>(stream, inner_w, xs0, inner_b, nullptr, 0,
                             inner0, 256, 40000, 256);
    { int tot = 256 * 40000;
      upsample_add_k<<<dim3((tot + 255) / 256), dim3(256), 0, stream>>>(inner0, last, 200, 100, tot); }
    gemm<BT_CONV, 0, 0, false>(stream, layer_w, inner0, layer_b, nullptr, 0,
                               out, 256, 40000, 2304, 200, 200);
}

// Round 2
// 2834.338 us; speedup vs baseline: 1.5587x; 1.5587x over previous
//
#include <hip/hip_runtime.h>
#include <cstdint>
#include <cstddef>
#include <math.h>

#define KNN 7

using short8  = __attribute__((ext_vector_type(8))) short;
using floatx4 = __attribute__((ext_vector_type(4))) float;

// ---------------- workspace layout (in floats) ----------------
static const size_t OFF_ARENA = 0;          // 10,240,000  patches / U / inner0
static const size_t OFF_XS0   = 10240000;   // 10,240,000
static const size_t OFF_XS1   = 20480000;   //  2,560,000
static const size_t OFF_LAST  = 23040000;   //  2,560,000  score (GNN) / last (FPN)
static const size_t OFF_EMB   = 25600000;   //    409,600
static const size_t OFF_EMB2  = 26009600;   //    409,600
static const size_t OFF_XL    = 26419200;   //  3,276,800  (FPN: bf16 image arena, spans XL+XR)
static const size_t OFF_XR    = 29696000;   //  3,276,800
static const size_t OFF_H1    = 32972800;   //  3,276,800
static const size_t OFF_XL2   = 36249600;   //    409,600
static const size_t OFF_XR2   = 36659200;   //    409,600
static const size_t OFF_CAT   = 37068800;   //    819,200
static const size_t OFF_HC    = 37888000;   //    409,600
static const size_t OFF_E     = 38297600;   //    102,400
static const size_t OFF_SRCF  = 38400000;   //     11,200 ints
static const size_t OFF_SRCS  = 38411200;   //     11,200 ints
static const size_t OFF_BF_A  = 38422400;   //  1,700,000 floats = 3.4M bf16 (A casts)
static const size_t OFF_BF_W  = 40122400;   //    850,000 floats = 1.7M bf16 (W casts)
// total ~164 MB

static __device__ __forceinline__ unsigned short f2bf(float f) {
    union { float f; unsigned u; } v; v.f = f;
    unsigned u = v.u;
    unsigned r = u + 0x7fffu + ((u >> 16) & 1u);   // RNE
    return (unsigned short)(r >> 16);
}

// ============================ fp32 tiled GEMM (NT only; exact path) ============
// C[M,N] = A[M,K] * B[N,K]^T  (+bias axis n, relu opt)
template<int ACT, bool BIAS>
__global__ __launch_bounds__(256)
void gemm_k(const float* __restrict__ A, const float* __restrict__ B,
            const float* __restrict__ bias, float* __restrict__ C, int M, int N, int K)
{
    __shared__ float As[16][68];
    __shared__ float Bs[16][68];
    const int tid = threadIdx.x;
    const int bm0 = blockIdx.y * 64;
    const int bn0 = blockIdx.x * 64;
    const int tx = tid & 15, ty = tid >> 4;
    const int lrow = tid >> 2;
    const int lk4  = (tid & 3) << 2;
    float acc[4][4] = {{0.f,0.f,0.f,0.f},{0.f,0.f,0.f,0.f},{0.f,0.f,0.f,0.f},{0.f,0.f,0.f,0.f}};

    for (int k0 = 0; k0 < K; k0 += 16) {
        {
            const int m = bm0 + lrow;
            float4 v = {0.f,0.f,0.f,0.f};
            if (m < M) v = *(const float4*)(A + (size_t)m * K + (k0 + lk4));
            As[lk4+0][lrow]=v.x; As[lk4+1][lrow]=v.y; As[lk4+2][lrow]=v.z; As[lk4+3][lrow]=v.w;
        }
        {
            const int nn = bn0 + lrow;
            float4 v = {0.f,0.f,0.f,0.f};
            if (nn < N) v = *(const float4*)(B + (size_t)nn * K + (k0 + lk4));
            Bs[lk4+0][lrow]=v.x; Bs[lk4+1][lrow]=v.y; Bs[lk4+2][lrow]=v.z; Bs[lk4+3][lrow]=v.w;
        }
        __syncthreads();
        #pragma unroll
        for (int k = 0; k < 16; k++) {
            const float4 av = *(const float4*)&As[k][ty << 2];
            const float4 bv = *(const float4*)&Bs[k][tx << 2];
            const float a0=av.x,a1=av.y,a2=av.z,a3=av.w;
            const float b0=bv.x,b1=bv.y,b2=bv.z,b3=bv.w;
            acc[0][0]=fmaf(a0,b0,acc[0][0]); acc[0][1]=fmaf(a0,b1,acc[0][1]);
            acc[0][2]=fmaf(a0,b2,acc[0][2]); acc[0][3]=fmaf(a0,b3,acc[0][3]);
            acc[1][0]=fmaf(a1,b0,acc[1][0]); acc[1][1]=fmaf(a1,b1,acc[1][1]);
            acc[1][2]=fmaf(a1,b2,acc[1][2]); acc[1][3]=fmaf(a1,b3,acc[1][3]);
            acc[2][0]=fmaf(a2,b0,acc[2][0]); acc[2][1]=fmaf(a2,b1,acc[2][1]);
            acc[2][2]=fmaf(a2,b2,acc[2][2]); acc[2][3]=fmaf(a2,b3,acc[2][3]);
            acc[3][0]=fmaf(a3,b0,acc[3][0]); acc[3][1]=fmaf(a3,b1,acc[3][1]);
            acc[3][2]=fmaf(a3,b2,acc[3][2]); acc[3][3]=fmaf(a3,b3,acc[3][3]);
        }
        __syncthreads();
    }
    #pragma unroll
    for (int i = 0; i < 4; i++) {
        const int m = bm0 + (ty << 2) + i;
        if (m >= M) continue;
        #pragma unroll
        for (int jj = 0; jj < 4; jj++) {
            const int nn = bn0 + (tx << 2) + jj;
            if (nn >= N) continue;
            float v = acc[i][jj];
            if (BIAS) v += bias[nn];
            if (ACT == 1) v = fmaxf(v, 0.f);
            C[(size_t)m * N + nn] = v;
        }
    }
}

template<int ACT, bool BIAS>
static inline void gemm32(hipStream_t s, const float* A, const float* B, const float* bias,
                          float* C, int M, int N, int K)
{
    dim3 g((N + 63) / 64, (M + 63) / 64);
    gemm_k<ACT, BIAS><<<g, dim3(256), 0, s>>>(A, B, bias, C, M, N, K);
}

// ============================ bf16 MFMA GEMM ============================
// C[M,N] = A[M,K](bf16) * B(bf16)  (+bias, relu, +Dmat fp32). K % 32 == 0.
// BT_NT: B is [N,K] row-major. BT_CONV: B is bf16 image [Cin,imH,imW], K=Cin*9.
enum { BT_NT = 0, BT_CONV = 2 };

template<int BT, int ACT, int BAX, bool ADDMAT>
__global__ __launch_bounds__(256)
void bgemm_k(const unsigned short* __restrict__ A, const unsigned short* __restrict__ B,
             const float* __restrict__ bias, const float* __restrict__ Dmat, int Dld,
             float* __restrict__ C, int M, int N, int K, int imH, int imW)
{
    __shared__ unsigned short Asl[128][40];   // [m][k] bf16, +20-bank row stride
    __shared__ unsigned short Bsl[128][40];   // [n][k]
    const int tid  = threadIdx.x;
    const int lane = tid & 63;
    const int wid  = tid >> 6;
    const int quad = lane >> 4;
    const int l15  = lane & 15;
    const int wy = wid >> 1, wx = wid & 1;
    const int bm0 = blockIdx.y * 128;
    const int bn0 = blockIdx.x * 128;

    floatx4 zero = {0.f, 0.f, 0.f, 0.f};
    floatx4 acc[4][4];
    #pragma unroll
    for (int i = 0; i < 4; i++)
        #pragma unroll
        for (int j = 0; j < 4; j++) acc[i][j] = zero;

    const int srow = tid >> 1;          // 0..127
    const int skc  = (tid & 1) << 4;    // 0 or 16

    for (int k0 = 0; k0 < K; k0 += 32) {
        {   // A tile: [128 m][32 k]
            const int m = bm0 + srow;
            uint4 v0 = {0,0,0,0}, v1 = {0,0,0,0};
            if (m < M) {
                const uint4* p = (const uint4*)(A + (size_t)m * K + k0 + skc);
                v0 = p[0]; v1 = p[1];
            }
            *(uint4*)&Asl[srow][skc]     = v0;
            *(uint4*)&Asl[srow][skc + 8] = v1;
        }
        if (BT == BT_NT) {
            const int nn = bn0 + srow;
            uint4 v0 = {0,0,0,0}, v1 = {0,0,0,0};
            if (nn < N) {
                const uint4* p = (const uint4*)(B + (size_t)nn * K + k0 + skc);
                v0 = p[0]; v1 = p[1];
            }
            *(uint4*)&Bsl[srow][skc]     = v0;
            *(uint4*)&Bsl[srow][skc + 8] = v1;
        } else {   // CONV: implicit im2col gather, staged via registers -> 16B LDS writes
            const int pl = tid & 127;
            const int kh = (tid >> 7) << 4;   // 0 or 16
            const int p = bn0 + pl;
            int py = 0, px = 0;
            const bool pok = p < N;
            if (pok) { py = p / imW; px = p - py * imW; }
            unsigned short tmp[16];
            #pragma unroll
            for (int i = 0; i < 16; i++) {
                const int kk = k0 + kh + i;
                const int c = kk / 9;
                const int j = kk - c * 9;
                const int dy = j / 3 - 1;
                const int dx = j - (j / 3) * 3 - 1;
                unsigned short val = 0;
                if (pok) {
                    const int y = py + dy, x = px + dx;
                    if (y >= 0 && y < imH && x >= 0 && x < imW)
                        val = B[(size_t)c * imH * imW + (size_t)y * imW + x];
                }
                tmp[i] = val;
            }
            *(uint4*)&Bsl[pl][kh]     = *(uint4*)&tmp[0];
            *(uint4*)&Bsl[pl][kh + 8] = *(uint4*)&tmp[8];
        }
        __syncthreads();
        short8 af[4], bfr[4];
        #pragma unroll
        for (int i = 0; i < 4; i++)
            af[i] = *(const short8*)&Asl[wy * 64 + i * 16 + l15][quad * 8];
        #pragma unroll
        for (int j = 0; j < 4; j++)
            bfr[j] = *(const short8*)&Bsl[wx * 64 + j * 16 + l15][quad * 8];
        #pragma unroll
        for (int i = 0; i < 4; i++)
            #pragma unroll
            for (int j = 0; j < 4; j++)
                acc[i][j] = __builtin_amdgcn_mfma_f32_16x16x32_bf16(af[i], bfr[j], acc[i][j], 0, 0, 0);
        __syncthreads();
    }

    // epilogue: C/D layout col=lane&15, row=quad*4+reg (verified mapping)
    #pragma unroll
    for (int i = 0; i < 4; i++) {
        #pragma unroll
        for (int r = 0; r < 4; r++) {
            const int m = bm0 + wy * 64 + i * 16 + quad * 4 + r;
            if (m >= M) continue;
            #pragma unroll
            for (int j = 0; j < 4; j++) {
                const int n = bn0 + wx * 64 + j * 16 + l15;
                if (n >= N) continue;
                float v = acc[i][j][r];
                if (bias != nullptr) v += (BAX == 0) ? bias[m] : bias[n];
                if (ACT == 1) v = fmaxf(v, 0.f);
                if (ADDMAT) v += Dmat[(size_t)m * Dld + n];
                C[(size_t)m * N + n] = v;
            }
        }
    }
}

template<int BT, int ACT, int BAX, bool ADDMAT>
static inline void bgemm(hipStream_t s, const unsigned short* A, const unsigned short* B,
                         const float* bias, const float* D, int Dld, float* C,
                         int M, int N, int K, int imH = 0, int imW = 0)
{
    dim3 g((N + 127) / 128, (M + 127) / 128);
    bgemm_k<BT, ACT, BAX, ADDMAT><<<g, dim3(256), 0, s>>>(A, B, bias, D, Dld, C, M, N, K, imH, imW);
}

// ============================ cast kernels ============================
__global__ void cast_bf16_k(const float* __restrict__ in, unsigned short* __restrict__ out, int total)
{
    const int i4 = (blockIdx.x * 256 + threadIdx.x) * 4;
    if (i4 + 4 <= total) {
        const float4 v = *(const float4*)(in + i4);
        ushort4 o;
        o.x = f2bf(v.x); o.y = f2bf(v.y); o.z = f2bf(v.z); o.w = f2bf(v.w);
        *(ushort4*)(out + i4) = o;
    } else {
        for (int i = i4; i < total; i++) out[i] = f2bf(in[i]);
    }
}

static inline void cast_bf(hipStream_t s, const float* in, unsigned short* out, int total)
{
    cast_bf16_k<<<dim3((total / 4 + 255) / 256), dim3(256), 0, s>>>(in, out, total);
}

// transposing cast: in fp32 [K,N] -> out bf16 [N,K]
__global__ void cast_t_k(const float* __restrict__ in, unsigned short* __restrict__ out, int K, int N)
{
    __shared__ float tile[64][65];
    const int n0 = blockIdx.x * 64;
    const int k0 = blockIdx.y * 64;
    const int t = threadIdx.x;
    const int r = t >> 2;
    const int c4 = (t & 3) << 4;
    {
        const int k = k0 + r;
        if (k < K && n0 + c4 + 16 <= N) {
            const float4* p = (const float4*)(in + (size_t)k * N + n0 + c4);
            *(float4*)&tile[r][c4]      = p[0];
            *(float4*)&tile[r][c4 + 4]  = p[1];
            *(float4*)&tile[r][c4 + 8]  = p[2];
            *(float4*)&tile[r][c4 + 12] = p[3];
        } else {
            for (int i = 0; i < 16; i++)
                tile[r][c4 + i] = (k < K && n0 + c4 + i < N) ? in[(size_t)k * N + n0 + c4 + i] : 0.f;
        }
    }
    __syncthreads();
    const int n = n0 + r;
    if (n >= N) return;
    unsigned short tmp[16];
    #pragma unroll
    for (int i = 0; i < 16; i++) tmp[i] = f2bf(tile[c4 + i][r]);
    if (k0 + 64 <= K) {
        *(uint4*)(out + (size_t)n * K + k0 + c4)     = *(uint4*)&tmp[0];
        *(uint4*)(out + (size_t)n * K + k0 + c4 + 8) = *(uint4*)&tmp[8];
    } else {
        for (int i = 0; i < 16; i++)
            if (k0 + c4 + i < K) out[(size_t)n * K + k0 + c4 + i] = tmp[i];
    }
}

static inline void cast_t(hipStream_t s, const float* in, unsigned short* out, int K, int N)
{
    cast_t_k<<<dim3((N + 63) / 64, (K + 63) / 64), dim3(256), 0, s>>>(in, out, K, N);
}

// ============================ small kernels (unchanged from R1) ============================
__global__ void extract_patches_k(const float* __restrict__ f, float* __restrict__ patches,
                                  int nw, int H, int total)
{
    int idx = blockIdx.x * 256 + threadIdx.x;
    if (idx >= total) return;
    int q = idx % 6400;
    int p = idx / 6400;
    int c = q / 25;
    int rem = q - c * 25;
    int a = rem / 5, b = rem - (rem / 5) * 5;
    int ih = p / nw, iw = p - (p / nw) * nw;
    patches[idx] = f[(size_t)c * H * H + (size_t)(ih * 5 + a) * H + (iw * 5 + b)];
}

__global__ void topk_feat_k(const float* __restrict__ score, int* __restrict__ srcCols, int n)
{
    const int r = blockIdx.x;
    const int lane = threadIdx.x;
    const float* row = score + (size_t)r * n;
    int   sel[KNN];
    float selv[KNN];
    #pragma unroll
    for (int t = 0; t < KNN; t++) {
        float best = -__builtin_huge_valf();
        int   bidx = 0x7fffffff;
        for (int c = lane; c < n; c += 64) {
            bool taken = false;
            #pragma unroll
            for (int u = 0; u < KNN; u++)
                if (u < t && sel[u] == c) taken = true;
            if (taken) continue;
            float v = row[c];
            if (v > best || (v == best && c < bidx)) { best = v; bidx = c; }
        }
        #pragma unroll
        for (int off = 32; off > 0; off >>= 1) {
            float ov = __shfl_down(best, off);
            int   oi = __shfl_down(bidx, off);
            if (ov > best || (ov == best && oi < bidx)) { best = ov; bidx = oi; }
        }
        best = __shfl(best, 0);
        bidx = __shfl(bidx, 0);
        sel[t] = bidx; selv[t] = best;
    }
    if (lane < KNN) {
        int c = -1; float v = 0.f;
        #pragma unroll
        for (int t = 0; t < KNN; t++)
            if (lane == t) { c = sel[t]; v = selv[t]; }
        srcCols[r * KNN + lane] = (c > r && v != 0.0f) ? c : -1;
    }
}

__global__ void topk_spatial_k(int* __restrict__ srcCols, int n, int nw)
{
    const int r = blockIdx.x;
    const int lane = threadIdx.x;
    const int ri = r / nw, rj = r - (r / nw) * nw;
    int sel[KNN];
    #pragma unroll
    for (int t = 0; t < KNN; t++) {
        int bkey = 0x7fffffff;
        for (int c = lane; c < n; c += 64) {
            bool taken = false;
            #pragma unroll
            for (int u = 0; u < KNN; u++)
                if (u < t && sel[u] == c) taken = true;
            if (taken) continue;
            const int ci = c / nw, cj = c - (c / nw) * nw;
            const int dy = (ri - ci) * 5, dx = (rj - cj) * 5;
            const int d2 = dy * dy + dx * dx;
            const int key = (d2 << 11) | c;
            if (key < bkey) bkey = key;
        }
        #pragma unroll
        for (int off = 32; off > 0; off >>= 1) {
            int ok = __shfl_down(bkey, off);
            if (ok < bkey) bkey = ok;
        }
        bkey = __shfl(bkey, 0);
        sel[t] = bkey & 2047;
    }
    if (lane < KNN) {
        int c = -1;
        #pragma unroll
        for (int t = 0; t < KNN; t++) if (lane == t) c = sel[t];
        srcCols[r * KNN + lane] = (c > r) ? c : -1;
    }
}

__global__ void gat_logits_k(const float* __restrict__ xl, const float* __restrict__ xr,
                             const float* __restrict__ att, const int* __restrict__ srcCols,
                             float* __restrict__ e, int n, int H)
{
    const int wid = (blockIdx.x * blockDim.x + threadIdx.x) >> 6;
    const int lane = threadIdx.x & 63;
    if (wid >= n * 8 * H) return;
    const int h = wid % H;
    const int es = wid / H;
    const int r = es >> 3, s = es & 7;
    int src;
    if (s == 7) src = r;
    else { src = srcCols[r * KNN + s]; if (src < 0) return; }
    const float* pl = xl + ((size_t)src * H + h) * 256;
    const float* pr = xr + ((size_t)r * H + h) * 256;
    const float* pa = att + (size_t)h * 256;
    float sum = 0.f;
    #pragma unroll
    for (int it = 0; it < 4; it++) {
        const int d = lane + it * 64;
        float m = pl[d] + pr[d];
        m = (m > 0.f) ? m : 0.2f * m;
        sum += m * pa[d];
    }
    #pragma unroll
    for (int off = 32; off > 0; off >>= 1) sum += __shfl_down(sum, off);
    if (lane == 0) e[(size_t)es * H + h] = sum;
}

__global__ void gat_aggregate_k(const float* __restrict__ xl, const float* __restrict__ e,
                                const int* __restrict__ srcCols, const float* __restrict__ bias,
                                float* __restrict__ out, int n, int H, int ostride, int ooff)
{
    const int wid = (blockIdx.x * blockDim.x + threadIdx.x) >> 6;
    const int lane = threadIdx.x & 63;
    if (wid >= n * H) return;
    const int h = wid % H;
    const int r = wid / H;
    const float eself = e[(size_t)(r * 8 + 7) * H + h];
    float mx = eself;
    #pragma unroll
    for (int ss = 0; ss < KNN; ss++) {
        const int c = srcCols[r * KNN + ss];
        if (c >= 0) mx = fmaxf(mx, e[(size_t)(r * 8 + ss) * H + h]);
    }
    float denom = expf(eself - mx);
    #pragma unroll
    for (int ss = 0; ss < KNN; ss++) {
        const int c = srcCols[r * KNN + ss];
        if (c >= 0) denom += expf(e[(size_t)(r * 8 + ss) * H + h] - mx);
    }
    const float inv = 1.f / (denom + 1e-16f);
    const int d0 = lane << 2;
    float o0, o1, o2, o3;
    {
        const float a = expf(eself - mx) * inv;
        const float4 v = *(const float4*)(xl + ((size_t)r * H + h) * 256 + d0);
        o0 = a * v.x; o1 = a * v.y; o2 = a * v.z; o3 = a * v.w;
    }
    #pragma unroll
    for (int ss = 0; ss < KNN; ss++) {
        const int c = srcCols[r * KNN + ss];
        if (c < 0) continue;
        const float a = expf(e[(size_t)(r * 8 + ss) * H + h] - mx) * inv;
        const float4 v = *(const float4*)(xl + ((size_t)c * H + h) * 256 + d0);
        o0 = fmaf(a, v.x, o0); o1 = fmaf(a, v.y, o1);
        o2 = fmaf(a, v.z, o2); o3 = fmaf(a, v.w, o3);
    }
    const float* bb = bias + (size_t)h * 256 + d0;
    o0 += bb[0]; o1 += bb[1]; o2 += bb[2]; o3 += bb[3];
    o0 = (o0 > 0.f) ? o0 : (expf(o0) - 1.f);
    o1 = (o1 > 0.f) ? o1 : (expf(o1) - 1.f);
    o2 = (o2 > 0.f) ? o2 : (expf(o2) - 1.f);
    o3 = (o3 > 0.f) ? o3 : (expf(o3) - 1.f);
    float4 res = {o0, o1, o2, o3};
    *(float4*)(out + (size_t)r * ostride + ooff + (size_t)h * 256 + d0) = res;
}

__global__ void scatter_convT_k(const float* __restrict__ f, const float* __restrict__ U,
                                const float* __restrict__ bias, float* __restrict__ xs,
                                int nw, int H, int total)
{
    int idx = blockIdx.x * 256 + threadIdx.x;
    if (idx >= total) return;
    int x = idx % H;
    int t = idx / H;
    int y = t % H;
    int o = t / H;
    int j = y / 5, a = y - j * 5;
    int i = x / 5, b = x - i * 5;
    int p = i * nw + j;
    float v = U[(size_t)p * 6400 + o * 25 + a * 5 + b] + bias[o];
    v = fmaxf(v, 0.f);
    xs[idx] = f[idx] + v;
}

__global__ void upsample_add_k(float* __restrict__ acc, const float* __restrict__ last,
                               int H, int Hs, int total)
{
    int idx = blockIdx.x * 256 + threadIdx.x;
    if (idx >= total) return;
    int x = idx % H;
    int t = idx / H;
    int y = t % H;
    int c = t / H;
    acc[idx] += last[(size_t)c * Hs * Hs + (size_t)(y >> 1) * Hs + (x >> 1)];
}

// ============================ orchestration ============================
static void run_level(void* const* d_in, float* ws, int l, int H, hipStream_t s)
{
    const float* f = (const float*)d_in[l];
    const int nh = H / 5, nw = nh, n = nh * nw, HW = H * H;

    const float* convT_w = (const float*)d_in[6]  + (size_t)l * 1638400;
    const float* convT_b = (const float*)d_in[7]  + l * 256;
    const float* conv1_w = (const float*)d_in[8]  + (size_t)l * 1638400;
    const float* conv1_b = (const float*)d_in[9]  + l * 256;
    const float* fc2_w   = (const float*)d_in[10] + (size_t)l * 65536;
    const float* fc2_b   = (const float*)d_in[11] + l * 256;
    const float* fc3_w   = (const float*)d_in[12] + (size_t)l * 131072;
    const float* fc3_b   = (const float*)d_in[13] + l * 256;
    const float* g1_wl   = (const float*)d_in[14] + (size_t)l * 524288;
    const float* g1_bl   = (const float*)d_in[15] + l * 2048;
    const float* g1_wr   = (const float*)d_in[16] + (size_t)l * 524288;
    const float* g1_br   = (const float*)d_in[17] + l * 2048;
    const float* g1_att  = (const float*)d_in[18] + l * 2048;
    const float* g1_bias = (const float*)d_in[19] + l * 2048;
    const float* g2_wl   = (const float*)d_in[20] + (size_t)l * 524288;
    const float* g2_bl   = (const float*)d_in[21] + l * 256;
    const float* g2_wr   = (const float*)d_in[22] + (size_t)l * 524288;
    const float* g2_br   = (const float*)d_in[23] + l * 256;
    const float* g2_att  = (const float*)d_in[24] + l * 256;
    const float* g2_bias = (const float*)d_in[25] + l * 256;
    const float* g3_wl   = (const float*)d_in[26] + (size_t)l * 524288;
    const float* g3_bl   = (const float*)d_in[27] + l * 2048;
    const float* g3_wr   = (const float*)d_in[28] + (size_t)l * 524288;
    const float* g3_br   = (const float*)d_in[29] + l * 2048;
    const float* g3_att  = (const float*)d_in[30] + l * 2048;
    const float* g3_bias = (const float*)d_in[31] + l * 2048;
    const float* g4_wl   = (const float*)d_in[32] + (size_t)l * 524288;
    const float* g4_bl   = (const float*)d_in[33] + l * 256;
    const float* g4_wr   = (const float*)d_in[34] + (size_t)l * 524288;
    const float* g4_br   = (const float*)d_in[35] + l * 256;
    const float* g4_att  = (const float*)d_in[36] + l * 256;
    const float* g4_bias = (const float*)d_in[37] + l * 256;

    float* patches = ws + OFF_ARENA;   // also U
    float* xs    = ws + (l == 0 ? OFF_XS0 : OFF_XS1);
    float* emb   = ws + OFF_EMB;
    float* emb2  = ws + OFF_EMB2;
    float* score = ws + OFF_LAST;
    float* xl    = ws + OFF_XL;
    float* xr    = ws + OFF_XR;
    float* h1    = ws + OFF_H1;
    float* xl2   = ws + OFF_XL2;
    float* xr2   = ws + OFF_XR2;
    float* cat   = ws + OFF_CAT;
    float* hc    = ws + OFF_HC;
    float* ebuf  = ws + OFF_E;
    int* srcF = (int*)(ws + OFF_SRCF);
    int* srcS = (int*)(ws + OFF_SRCS);
    unsigned short* ba = (unsigned short*)(ws + OFF_BF_A);
    unsigned short* bw = (unsigned short*)(ws + OFF_BF_W);

    { int tot = n * 6400;
      extract_patches_k<<<dim3((tot + 255) / 256), dim3(256), 0, s>>>(f, patches, nw, H, tot); }

    // exact fp32 path feeding the top-k graph selection
    gemm32<1, true>(s, patches, conv1_w, conv1_b, emb, n, 256, 6400);
    gemm32<1, true>(s, emb, fc2_w, fc2_b, emb2, n, 256, 256);
    gemm32<0, false>(s, emb2, emb2, nullptr, score, n, n, 256);
    topk_feat_k<<<dim3(n), dim3(64), 0, s>>>(score, srcF, n);
    topk_spatial_k<<<dim3(n), dim3(64), 0, s>>>(srcS, n, nw);

    // g1: feature graph, emb2 -> h1 [n,2048], heads=8 (bf16 MFMA)
    cast_bf(s, emb2, ba, n * 256);
    cast_t(s, g1_wl, bw, 256, 2048);
    bgemm<BT_NT, 0, 1, false>(s, ba, bw, g1_bl, nullptr, 0, xl, n, 2048, 256);
    cast_t(s, g1_wr, bw, 256, 2048);
    bgemm<BT_NT, 0, 1, false>(s, ba, bw, g1_br, nullptr, 0, xr, n, 2048, 256);
    { int tw = n * 8 * 8;
      gat_logits_k<<<dim3((tw + 3) / 4), dim3(256), 0, s>>>(xl, xr, g1_att, srcF, ebuf, n, 8);
      int aw = n * 8;
      gat_aggregate_k<<<dim3((aw + 3) / 4), dim3(256), 0, s>>>(xl, ebuf, srcF, g1_bias, h1, n, 8, 2048, 0); }

    // g2: feature graph, h1 -> cat[:, :256], heads=1
    cast_bf(s, h1, ba, n * 2048);
    cast_t(s, g2_wl, bw, 2048, 256);
    bgemm<BT_NT, 0, 1, false>(s, ba, bw, g2_bl, nullptr, 0, xl2, n, 256, 2048);
    cast_t(s, g2_wr, bw, 2048, 256);
    bgemm<BT_NT, 0, 1, false>(s, ba, bw, g2_br, nullptr, 0, xr2, n, 256, 2048);
    { int tw = n * 8;
      gat_logits_k<<<dim3((tw + 3) / 4), dim3(256), 0, s>>>(xl2, xr2, g2_att, srcF, ebuf, n, 1);
      int aw = n;
      gat_aggregate_k<<<dim3((aw + 3) / 4), dim3(256), 0, s>>>(xl2, ebuf, srcF, g2_bias, cat, n, 1, 512, 0); }

    // g3: spatial graph, emb2 -> h1 [n,2048], heads=8
    cast_bf(s, emb2, ba, n * 256);
    cast_t(s, g3_wl, bw, 256, 2048);
    bgemm<BT_NT, 0, 1, false>(s, ba, bw, g3_bl, nullptr, 0, xl, n, 2048, 256);
    cast_t(s, g3_wr, bw, 256, 2048);
    bgemm<BT_NT, 0, 1, false>(s, ba, bw, g3_br, nullptr, 0, xr, n, 2048, 256);
    { int tw = n * 8 * 8;
      gat_logits_k<<<dim3((tw + 3) / 4), dim3(256), 0, s>>>(xl, xr, g3_att, srcS, ebuf, n, 8);
      int aw = n * 8;
      gat_aggregate_k<<<dim3((aw + 3) / 4), dim3(256), 0, s>>>(xl, ebuf, srcS, g3_bias, h1, n, 8, 2048, 0); }

    // g4: spatial graph, h1 -> cat[:, 256:], heads=1
    cast_bf(s, h1, ba, n * 2048);
    cast_t(s, g4_wl, bw, 2048, 256);
    bgemm<BT_NT, 0, 1, false>(s, ba, bw, g4_bl, nullptr, 0, xl2, n, 256, 2048);
    cast_t(s, g4_wr, bw, 2048, 256);
    bgemm<BT_NT, 0, 1, false>(s, ba, bw, g4_br, nullptr, 0, xr2, n, 256, 2048);
    { int tw = n * 8;
      gat_logits_k<<<dim3((tw + 3) / 4), dim3(256), 0, s>>>(xl2, xr2, g4_att, srcS, ebuf, n, 1);
      int aw = n;
      gat_aggregate_k<<<dim3((aw + 3) / 4), dim3(256), 0, s>>>(xl2, ebuf, srcS, g4_bias, cat, n, 1, 512, 256); }

    // hc = relu(cat @ fc3_w^T + fc3_b) + h2
    cast_bf(s, cat, ba, n * 512);
    cast_bf(s, fc3_w, bw, 131072);                 // already [N=256, K=512]
    bgemm<BT_NT, 1, 1, true>(s, ba, bw, fc3_b, cat + 256, 512, hc, n, 256, 512);
    // U = hc @ convT_w  ([256,6400] -> transposed to [6400,256])
    cast_bf(s, hc, ba, n * 256);
    cast_t(s, convT_w, bw, 256, 6400);
    bgemm<BT_NT, 0, 1, false>(s, ba, bw, nullptr, nullptr, 0, patches, n, 6400, 256);
    { int tot = 256 * HW;
      scatter_convT_k<<<dim3((tot + 255) / 256), dim3(256), 0, s>>>(f, patches, convT_b, xs, nw, H, tot); }
}

extern "C" void kernel_launch(void* const* d_in, const int* in_sizes, int n_in,
                              void* d_out, int out_size, void* d_ws, size_t ws_size,
                              hipStream_t stream)
{
    float* ws  = (float*)d_ws;
    float* out = (float*)d_out;

    run_level(d_in, ws, 0, 200, stream);
    run_level(d_in, ws, 1, 100, stream);

    const float* inner_w = (const float*)d_in[2];
    const float* inner_b = (const float*)d_in[3];
    const float* layer_w = (const float*)d_in[4];
    const float* layer_b = (const float*)d_in[5];
    float* xs0    = ws + OFF_XS0;
    float* xs1    = ws + OFF_XS1;
    float* last   = ws + OFF_LAST;
    float* inner0 = ws + OFF_ARENA;
    unsigned short* bimg = (unsigned short*)(ws + OFF_XL);   // XL+XR span: 13.1M bf16 capacity
    unsigned short* bw   = (unsigned short*)(ws + OFF_BF_W);

    // last = conv1x1(xs1); out1 = conv3x3(last)
    cast_t(stream, xs1, bimg, 256, 10000);                    // [10000,256]
    cast_bf(stream, inner_w + 65536, bw, 65536);              // [256,256] = [M,K]
    bgemm<BT_NT, 0, 0, false>(stream, bw, bimg, inner_b + 256, nullptr, 0,
                              last, 256, 10000, 256);
    cast_bf(stream, last, bimg, 2560000);                     // image [256,100,100]
    cast_bf(stream, layer_w + 589824, bw, 589824);            // [256,2304]
    bgemm<BT_CONV, 0, 0, false>(stream, bw, bimg, layer_b + 256, nullptr, 0,
                                out + 10240000, 256, 10000, 2304, 100, 100);

    // inner0 = conv1x1(xs0) + nearest(last); out0 = conv3x3(inner0)
    cast_t(stream, xs0, bimg, 256, 40000);                    // [40000,256]
    cast_bf(stream, inner_w, bw, 65536);
    bgemm<BT_NT, 0, 0, false>(stream, bw, bimg, inner_b, nullptr, 0,
                              inner0, 256, 40000, 256);
    { int tot = 256 * 40000;
      upsample_add_k<<<dim3((tot + 255) / 256), dim3(256), 0, stream>>>(inner0, last, 200, 100, tot); }
    cast_bf(stream, inner0, bimg, 10240000);                  // image [256,200,200]
    cast_bf(stream, layer_w, bw, 589824);
    bgemm<BT_CONV, 0, 0, false>(stream, bw, bimg, layer_b, nullptr, 0,
                                out, 256, 40000, 2304, 200, 200);
}

// Round 3
// 2169.367 us; speedup vs baseline: 2.0365x; 1.3065x over previous
//
#include <hip/hip_runtime.h>
#include <cstdint>
#include <cstddef>
#include <math.h>

#define KNN 7

using short8  = __attribute__((ext_vector_type(8))) short;
using floatx4 = __attribute__((ext_vector_type(4))) float;

// ---------------- workspace layout (in floats) ----------------
static const size_t OFF_ARENA = 0;          // 10,240,000  patches / U / inner0
static const size_t OFF_XS0   = 10240000;   // 10,240,000
static const size_t OFF_XS1   = 20480000;   //  2,560,000
static const size_t OFF_LAST  = 23040000;   //  2,560,000  score (GNN) / last (FPN)
static const size_t OFF_EMB   = 25600000;   //    409,600
static const size_t OFF_EMB2  = 26009600;   //    409,600
static const size_t OFF_XL    = 26419200;   //  3,276,800  (also split-K partials / FPN bf16 arena)
static const size_t OFF_XR    = 29696000;   //  3,276,800
static const size_t OFF_H1    = 32972800;   //  3,276,800
static const size_t OFF_XL2   = 36249600;   //    409,600
static const size_t OFF_XR2   = 36659200;   //    409,600
static const size_t OFF_CAT   = 37068800;   //    819,200
static const size_t OFF_HC    = 37888000;   //    409,600
static const size_t OFF_E     = 38297600;   //    102,400
static const size_t OFF_SRCF  = 38400000;   //     11,200 ints
static const size_t OFF_SRCS  = 38411200;   //     11,200 ints
static const size_t OFF_BF_A  = 38422400;   //  1,700,000 floats = 3.4M bf16 (A casts)
static const size_t OFF_BF_W  = 40122400;   //    850,000 floats = 1.7M bf16 (W casts)
// total ~164 MB

static __device__ __forceinline__ unsigned short f2bf(float f) {
    union { float f; unsigned u; } v; v.f = f;
    unsigned u = v.u;
    unsigned r = u + 0x7fffu + ((u >> 16) & 1u);   // RNE
    return (unsigned short)(r >> 16);
}

// ============================ fp32 tiled GEMM (NT; exact path) ============
// C[M,N] = A[M,K] * B[N,K]^T  (+bias axis n, relu opt)
template<int ACT, bool BIAS>
__global__ __launch_bounds__(256)
void gemm_k(const float* __restrict__ A, const float* __restrict__ B,
            const float* __restrict__ bias, float* __restrict__ C, int M, int N, int K)
{
    __shared__ float As[16][68];
    __shared__ float Bs[16][68];
    const int tid = threadIdx.x;
    const int bm0 = blockIdx.y * 64;
    const int bn0 = blockIdx.x * 64;
    const int tx = tid & 15, ty = tid >> 4;
    const int lrow = tid >> 2;
    const int lk4  = (tid & 3) << 2;
    float acc[4][4] = {{0.f,0.f,0.f,0.f},{0.f,0.f,0.f,0.f},{0.f,0.f,0.f,0.f},{0.f,0.f,0.f,0.f}};

    for (int k0 = 0; k0 < K; k0 += 16) {
        {
            const int m = bm0 + lrow;
            float4 v = {0.f,0.f,0.f,0.f};
            if (m < M) v = *(const float4*)(A + (size_t)m * K + (k0 + lk4));
            As[lk4+0][lrow]=v.x; As[lk4+1][lrow]=v.y; As[lk4+2][lrow]=v.z; As[lk4+3][lrow]=v.w;
        }
        {
            const int nn = bn0 + lrow;
            float4 v = {0.f,0.f,0.f,0.f};
            if (nn < N) v = *(const float4*)(B + (size_t)nn * K + (k0 + lk4));
            Bs[lk4+0][lrow]=v.x; Bs[lk4+1][lrow]=v.y; Bs[lk4+2][lrow]=v.z; Bs[lk4+3][lrow]=v.w;
        }
        __syncthreads();
        #pragma unroll
        for (int k = 0; k < 16; k++) {
            const float4 av = *(const float4*)&As[k][ty << 2];
            const float4 bv = *(const float4*)&Bs[k][tx << 2];
            const float a0=av.x,a1=av.y,a2=av.z,a3=av.w;
            const float b0=bv.x,b1=bv.y,b2=bv.z,b3=bv.w;
            acc[0][0]=fmaf(a0,b0,acc[0][0]); acc[0][1]=fmaf(a0,b1,acc[0][1]);
            acc[0][2]=fmaf(a0,b2,acc[0][2]); acc[0][3]=fmaf(a0,b3,acc[0][3]);
            acc[1][0]=fmaf(a1,b0,acc[1][0]); acc[1][1]=fmaf(a1,b1,acc[1][1]);
            acc[1][2]=fmaf(a1,b2,acc[1][2]); acc[1][3]=fmaf(a1,b3,acc[1][3]);
            acc[2][0]=fmaf(a2,b0,acc[2][0]); acc[2][1]=fmaf(a2,b1,acc[2][1]);
            acc[2][2]=fmaf(a2,b2,acc[2][2]); acc[2][3]=fmaf(a2,b3,acc[2][3]);
            acc[3][0]=fmaf(a3,b0,acc[3][0]); acc[3][1]=fmaf(a3,b1,acc[3][1]);
            acc[3][2]=fmaf(a3,b2,acc[3][2]); acc[3][3]=fmaf(a3,b3,acc[3][3]);
        }
        __syncthreads();
    }
    #pragma unroll
    for (int i = 0; i < 4; i++) {
        const int m = bm0 + (ty << 2) + i;
        if (m >= M) continue;
        #pragma unroll
        for (int jj = 0; jj < 4; jj++) {
            const int nn = bn0 + (tx << 2) + jj;
            if (nn >= N) continue;
            float v = acc[i][jj];
            if (BIAS) v += bias[nn];
            if (ACT == 1) v = fmaxf(v, 0.f);
            C[(size_t)m * N + nn] = v;
        }
    }
}

template<int ACT, bool BIAS>
static inline void gemm32(hipStream_t s, const float* A, const float* B, const float* bias,
                          float* C, int M, int N, int K)
{
    dim3 g((N + 63) / 64, (M + 63) / 64);
    gemm_k<ACT, BIAS><<<g, dim3(256), 0, s>>>(A, B, bias, C, M, N, K);
}

// ---- split-K variant: partial[s][M][N] = A[:, s*Kc:(s+1)*Kc] * B^T slice ----
__global__ __launch_bounds__(256)
void gemm32_sk_k(const float* __restrict__ A, const float* __restrict__ B,
                 float* __restrict__ part, int M, int N, int K, int Kc)
{
    __shared__ float As[16][68];
    __shared__ float Bs[16][68];
    const int tid = threadIdx.x;
    const int bm0 = blockIdx.y * 64;
    const int bn0 = blockIdx.x * 64;
    const int sblk = blockIdx.z;
    const int kbeg = sblk * Kc;
    const int kend = (kbeg + Kc < K) ? kbeg + Kc : K;
    const int tx = tid & 15, ty = tid >> 4;
    const int lrow = tid >> 2;
    const int lk4  = (tid & 3) << 2;
    float acc[4][4] = {{0.f,0.f,0.f,0.f},{0.f,0.f,0.f,0.f},{0.f,0.f,0.f,0.f},{0.f,0.f,0.f,0.f}};

    for (int k0 = kbeg; k0 < kend; k0 += 16) {
        {
            const int m = bm0 + lrow;
            float4 v = {0.f,0.f,0.f,0.f};
            if (m < M) v = *(const float4*)(A + (size_t)m * K + (k0 + lk4));
            As[lk4+0][lrow]=v.x; As[lk4+1][lrow]=v.y; As[lk4+2][lrow]=v.z; As[lk4+3][lrow]=v.w;
        }
        {
            const int nn = bn0 + lrow;
            float4 v = {0.f,0.f,0.f,0.f};
            if (nn < N) v = *(const float4*)(B + (size_t)nn * K + (k0 + lk4));
            Bs[lk4+0][lrow]=v.x; Bs[lk4+1][lrow]=v.y; Bs[lk4+2][lrow]=v.z; Bs[lk4+3][lrow]=v.w;
        }
        __syncthreads();
        #pragma unroll
        for (int k = 0; k < 16; k++) {
            const float4 av = *(const float4*)&As[k][ty << 2];
            const float4 bv = *(const float4*)&Bs[k][tx << 2];
            const float a0=av.x,a1=av.y,a2=av.z,a3=av.w;
            const float b0=bv.x,b1=bv.y,b2=bv.z,b3=bv.w;
            acc[0][0]=fmaf(a0,b0,acc[0][0]); acc[0][1]=fmaf(a0,b1,acc[0][1]);
            acc[0][2]=fmaf(a0,b2,acc[0][2]); acc[0][3]=fmaf(a0,b3,acc[0][3]);
            acc[1][0]=fmaf(a1,b0,acc[1][0]); acc[1][1]=fmaf(a1,b1,acc[1][1]);
            acc[1][2]=fmaf(a1,b2,acc[1][2]); acc[1][3]=fmaf(a1,b3,acc[1][3]);
            acc[2][0]=fmaf(a2,b0,acc[2][0]); acc[2][1]=fmaf(a2,b1,acc[2][1]);
            acc[2][2]=fmaf(a2,b2,acc[2][2]); acc[2][3]=fmaf(a2,b3,acc[2][3]);
            acc[3][0]=fmaf(a3,b0,acc[3][0]); acc[3][1]=fmaf(a3,b1,acc[3][1]);
            acc[3][2]=fmaf(a3,b2,acc[3][2]); acc[3][3]=fmaf(a3,b3,acc[3][3]);
        }
        __syncthreads();
    }
    float* P = part + (size_t)sblk * M * N;
    #pragma unroll
    for (int i = 0; i < 4; i++) {
        const int m = bm0 + (ty << 2) + i;
        if (m >= M) continue;
        #pragma unroll
        for (int jj = 0; jj < 4; jj++) {
            const int nn = bn0 + (tx << 2) + jj;
            if (nn >= N) continue;
            P[(size_t)m * N + nn] = acc[i][jj];
        }
    }
}

// reduce S partial slabs, + bias(axis n) + relu
template<int ACT, bool BIAS>
__global__ void sk_reduce_k(const float* __restrict__ part, const float* __restrict__ bias,
                            float* __restrict__ C, int MN, int N, int S)
{
    const int i4 = (blockIdx.x * 256 + threadIdx.x) * 4;
    if (i4 >= MN) return;
    float4 a = *(const float4*)(part + i4);
    for (int s = 1; s < S; s++) {
        const float4 b = *(const float4*)(part + (size_t)s * MN + i4);
        a.x += b.x; a.y += b.y; a.z += b.z; a.w += b.w;
    }
    if (BIAS) {
        const int n = i4 % N;
        a.x += bias[n]; a.y += bias[n + 1]; a.z += bias[n + 2]; a.w += bias[n + 3];
    }
    if (ACT == 1) {
        a.x = fmaxf(a.x, 0.f); a.y = fmaxf(a.y, 0.f);
        a.z = fmaxf(a.z, 0.f); a.w = fmaxf(a.w, 0.f);
    }
    *(float4*)(C + i4) = a;
}

// split-K GEMM driver: S slices, Kc multiple of 16
template<int ACT, bool BIAS>
static inline void gemm32_sk(hipStream_t s, const float* A, const float* B, const float* bias,
                             float* C, float* part, int M, int N, int K, int S)
{
    const int Kc = ((K / S + 15) / 16) * 16;
    dim3 g((N + 63) / 64, (M + 63) / 64, S);
    gemm32_sk_k<<<g, dim3(256), 0, s>>>(A, B, part, M, N, K, Kc);
    const int MN = M * N;
    sk_reduce_k<ACT, BIAS><<<dim3((MN / 4 + 255) / 256), dim3(256), 0, s>>>(part, bias, C, MN, N, S);
}

// ============================ bf16 MFMA GEMM ============================
enum { BT_NT = 0, BT_CONV = 2 };

template<int BT, int ACT, int BAX, bool ADDMAT>
__global__ __launch_bounds__(256)
void bgemm_k(const unsigned short* __restrict__ A, const unsigned short* __restrict__ B,
             const float* __restrict__ bias, const float* __restrict__ Dmat, int Dld,
             float* __restrict__ C, int M, int N, int K, int imH, int imW)
{
    __shared__ unsigned short Asl[128][40];
    __shared__ unsigned short Bsl[128][40];
    const int tid  = threadIdx.x;
    const int lane = tid & 63;
    const int wid  = tid >> 6;
    const int quad = lane >> 4;
    const int l15  = lane & 15;
    const int wy = wid >> 1, wx = wid & 1;
    const int bm0 = blockIdx.y * 128;
    const int bn0 = blockIdx.x * 128;

    floatx4 zero = {0.f, 0.f, 0.f, 0.f};
    floatx4 acc[4][4];
    #pragma unroll
    for (int i = 0; i < 4; i++)
        #pragma unroll
        for (int j = 0; j < 4; j++) acc[i][j] = zero;

    const int srow = tid >> 1;
    const int skc  = (tid & 1) << 4;

    for (int k0 = 0; k0 < K; k0 += 32) {
        {
            const int m = bm0 + srow;
            uint4 v0 = {0,0,0,0}, v1 = {0,0,0,0};
            if (m < M) {
                const uint4* p = (const uint4*)(A + (size_t)m * K + k0 + skc);
                v0 = p[0]; v1 = p[1];
            }
            *(uint4*)&Asl[srow][skc]     = v0;
            *(uint4*)&Asl[srow][skc + 8] = v1;
        }
        if (BT == BT_NT) {
            const int nn = bn0 + srow;
            uint4 v0 = {0,0,0,0}, v1 = {0,0,0,0};
            if (nn < N) {
                const uint4* p = (const uint4*)(B + (size_t)nn * K + k0 + skc);
                v0 = p[0]; v1 = p[1];
            }
            *(uint4*)&Bsl[srow][skc]     = v0;
            *(uint4*)&Bsl[srow][skc + 8] = v1;
        } else {
            const int pl = tid & 127;
            const int kh = (tid >> 7) << 4;
            const int p = bn0 + pl;
            int py = 0, px = 0;
            const bool pok = p < N;
            if (pok) { py = p / imW; px = p - py * imW; }
            unsigned short tmp[16];
            #pragma unroll
            for (int i = 0; i < 16; i++) {
                const int kk = k0 + kh + i;
                const int c = kk / 9;
                const int j = kk - c * 9;
                const int dy = j / 3 - 1;
                const int dx = j - (j / 3) * 3 - 1;
                unsigned short val = 0;
                if (pok) {
                    const int y = py + dy, x = px + dx;
                    if (y >= 0 && y < imH && x >= 0 && x < imW)
                        val = B[(size_t)c * imH * imW + (size_t)y * imW + x];
                }
                tmp[i] = val;
            }
            *(uint4*)&Bsl[pl][kh]     = *(uint4*)&tmp[0];
            *(uint4*)&Bsl[pl][kh + 8] = *(uint4*)&tmp[8];
        }
        __syncthreads();
        short8 af[4], bfr[4];
        #pragma unroll
        for (int i = 0; i < 4; i++)
            af[i] = *(const short8*)&Asl[wy * 64 + i * 16 + l15][quad * 8];
        #pragma unroll
        for (int j = 0; j < 4; j++)
            bfr[j] = *(const short8*)&Bsl[wx * 64 + j * 16 + l15][quad * 8];
        #pragma unroll
        for (int i = 0; i < 4; i++)
            #pragma unroll
            for (int j = 0; j < 4; j++)
                acc[i][j] = __builtin_amdgcn_mfma_f32_16x16x32_bf16(af[i], bfr[j], acc[i][j], 0, 0, 0);
        __syncthreads();
    }

    #pragma unroll
    for (int i = 0; i < 4; i++) {
        #pragma unroll
        for (int r = 0; r < 4; r++) {
            const int m = bm0 + wy * 64 + i * 16 + quad * 4 + r;
            if (m >= M) continue;
            #pragma unroll
            for (int j = 0; j < 4; j++) {
                const int n = bn0 + wx * 64 + j * 16 + l15;
                if (n >= N) continue;
                float v = acc[i][j][r];
                if (bias != nullptr) v += (BAX == 0) ? bias[m] : bias[n];
                if (ACT == 1) v = fmaxf(v, 0.f);
                if (ADDMAT) v += Dmat[(size_t)m * Dld + n];
                C[(size_t)m * N + n] = v;
            }
        }
    }
}

template<int BT, int ACT, int BAX, bool ADDMAT>
static inline void bgemm(hipStream_t s, const unsigned short* A, const unsigned short* B,
                         const float* bias, const float* D, int Dld, float* C,
                         int M, int N, int K, int imH = 0, int imW = 0)
{
    dim3 g((N + 127) / 128, (M + 127) / 128);
    bgemm_k<BT, ACT, BAX, ADDMAT><<<g, dim3(256), 0, s>>>(A, B, bias, D, Dld, C, M, N, K, imH, imW);
}

// ============================ cast kernels ============================
__global__ void cast_bf16_k(const float* __restrict__ in, unsigned short* __restrict__ out, int total)
{
    const int i4 = (blockIdx.x * 256 + threadIdx.x) * 4;
    if (i4 + 4 <= total) {
        const float4 v = *(const float4*)(in + i4);
        ushort4 o;
        o.x = f2bf(v.x); o.y = f2bf(v.y); o.z = f2bf(v.z); o.w = f2bf(v.w);
        *(ushort4*)(out + i4) = o;
    } else {
        for (int i = i4; i < total; i++) out[i] = f2bf(in[i]);
    }
}

static inline void cast_bf(hipStream_t s, const float* in, unsigned short* out, int total)
{
    cast_bf16_k<<<dim3((total / 4 + 255) / 256), dim3(256), 0, s>>>(in, out, total);
}

__global__ void cast_t_k(const float* __restrict__ in, unsigned short* __restrict__ out, int K, int N)
{
    __shared__ float tile[64][65];
    const int n0 = blockIdx.x * 64;
    const int k0 = blockIdx.y * 64;
    const int t = threadIdx.x;
    const int r = t >> 2;
    const int c4 = (t & 3) << 4;
    {
        const int k = k0 + r;
        if (k < K && n0 + c4 + 16 <= N) {
            const float4* p = (const float4*)(in + (size_t)k * N + n0 + c4);
            *(float4*)&tile[r][c4]      = p[0];
            *(float4*)&tile[r][c4 + 4]  = p[1];
            *(float4*)&tile[r][c4 + 8]  = p[2];
            *(float4*)&tile[r][c4 + 12] = p[3];
        } else {
            for (int i = 0; i < 16; i++)
                tile[r][c4 + i] = (k < K && n0 + c4 + i < N) ? in[(size_t)k * N + n0 + c4 + i] : 0.f;
        }
    }
    __syncthreads();
    const int n = n0 + r;
    if (n >= N) return;
    unsigned short tmp[16];
    #pragma unroll
    for (int i = 0; i < 16; i++) tmp[i] = f2bf(tile[c4 + i][r]);
    if (k0 + 64 <= K) {
        *(uint4*)(out + (size_t)n * K + k0 + c4)     = *(uint4*)&tmp[0];
        *(uint4*)(out + (size_t)n * K + k0 + c4 + 8) = *(uint4*)&tmp[8];
    } else {
        for (int i = 0; i < 16; i++)
            if (k0 + c4 + i < K) out[(size_t)n * K + k0 + c4 + i] = tmp[i];
    }
}

static inline void cast_t(hipStream_t s, const float* in, unsigned short* out, int K, int N)
{
    cast_t_k<<<dim3((N + 63) / 64, (K + 63) / 64), dim3(256), 0, s>>>(in, out, K, N);
}

// ============================ small kernels ============================
__global__ void extract_patches_k(const float* __restrict__ f, float* __restrict__ patches,
                                  int nw, int H, int total)
{
    int idx = blockIdx.x * 256 + threadIdx.x;
    if (idx >= total) return;
    int q = idx % 6400;
    int p = idx / 6400;
    int c = q / 25;
    int rem = q - c * 25;
    int a = rem / 5, b = rem - (rem / 5) * 5;
    int ih = p / nw, iw = p - (p / nw) * nw;
    patches[idx] = f[(size_t)c * H * H + (size_t)(ih * 5 + a) * H + (iw * 5 + b)];
}

__global__ void topk_feat_k(const float* __restrict__ score, int* __restrict__ srcCols, int n)
{
    const int r = blockIdx.x;
    const int lane = threadIdx.x;
    const float* row = score + (size_t)r * n;
    int   sel[KNN];
    float selv[KNN];
    #pragma unroll
    for (int t = 0; t < KNN; t++) {
        float best = -__builtin_huge_valf();
        int   bidx = 0x7fffffff;
        for (int c = lane; c < n; c += 64) {
            bool taken = false;
            #pragma unroll
            for (int u = 0; u < KNN; u++)
                if (u < t && sel[u] == c) taken = true;
            if (taken) continue;
            float v = row[c];
            if (v > best || (v == best && c < bidx)) { best = v; bidx = c; }
        }
        #pragma unroll
        for (int off = 32; off > 0; off >>= 1) {
            float ov = __shfl_down(best, off);
            int   oi = __shfl_down(bidx, off);
            if (ov > best || (ov == best && oi < bidx)) { best = ov; bidx = oi; }
        }
        best = __shfl(best, 0);
        bidx = __shfl(bidx, 0);
        sel[t] = bidx; selv[t] = best;
    }
    if (lane < KNN) {
        int c = -1; float v = 0.f;
        #pragma unroll
        for (int t = 0; t < KNN; t++)
            if (lane == t) { c = sel[t]; v = selv[t]; }
        srcCols[r * KNN + lane] = (c > r && v != 0.0f) ? c : -1;
    }
}

__global__ void topk_spatial_k(int* __restrict__ srcCols, int n, int nw)
{
    const int r = blockIdx.x;
    const int lane = threadIdx.x;
    const int ri = r / nw, rj = r - (r / nw) * nw;
    int sel[KNN];
    #pragma unroll
    for (int t = 0; t < KNN; t++) {
        int bkey = 0x7fffffff;
        for (int c = lane; c < n; c += 64) {
            bool taken = false;
            #pragma unroll
            for (int u = 0; u < KNN; u++)
                if (u < t && sel[u] == c) taken = true;
            if (taken) continue;
            const int ci = c / nw, cj = c - (c / nw) * nw;
            const int dy = (ri - ci) * 5, dx = (rj - cj) * 5;
            const int d2 = dy * dy + dx * dx;
            const int key = (d2 << 11) | c;
            if (key < bkey) bkey = key;
        }
        #pragma unroll
        for (int off = 32; off > 0; off >>= 1) {
            int ok = __shfl_down(bkey, off);
            if (ok < bkey) bkey = ok;
        }
        bkey = __shfl(bkey, 0);
        sel[t] = bkey & 2047;
    }
    if (lane < KNN) {
        int c = -1;
        #pragma unroll
        for (int t = 0; t < KNN; t++) if (lane == t) c = sel[t];
        srcCols[r * KNN + lane] = (c > r) ? c : -1;
    }
}

__global__ void gat_logits_k(const float* __restrict__ xl, const float* __restrict__ xr,
                             const float* __restrict__ att, const int* __restrict__ srcCols,
                             float* __restrict__ e, int n, int H)
{
    const int wid = (blockIdx.x * blockDim.x + threadIdx.x) >> 6;
    const int lane = threadIdx.x & 63;
    if (wid >= n * 8 * H) return;
    const int h = wid % H;
    const int es = wid / H;
    const int r = es >> 3, s = es & 7;
    int src;
    if (s == 7) src = r;
    else { src = srcCols[r * KNN + s]; if (src < 0) return; }
    const float* pl = xl + ((size_t)src * H + h) * 256;
    const float* pr = xr + ((size_t)r * H + h) * 256;
    const float* pa = att + (size_t)h * 256;
    float sum = 0.f;
    #pragma unroll
    for (int it = 0; it < 4; it++) {
        const int d = lane + it * 64;
        float m = pl[d] + pr[d];
        m = (m > 0.f) ? m : 0.2f * m;
        sum += m * pa[d];
    }
    #pragma unroll
    for (int off = 32; off > 0; off >>= 1) sum += __shfl_down(sum, off);
    if (lane == 0) e[(size_t)es * H + h] = sum;
}

__global__ void gat_aggregate_k(const float* __restrict__ xl, const float* __restrict__ e,
                                const int* __restrict__ srcCols, const float* __restrict__ bias,
                                float* __restrict__ out, int n, int H, int ostride, int ooff)
{
    const int wid = (blockIdx.x * blockDim.x + threadIdx.x) >> 6;
    const int lane = threadIdx.x & 63;
    if (wid >= n * H) return;
    const int h = wid % H;
    const int r = wid / H;
    const float eself = e[(size_t)(r * 8 + 7) * H + h];
    float mx = eself;
    #pragma unroll
    for (int ss = 0; ss < KNN; ss++) {
        const int c = srcCols[r * KNN + ss];
        if (c >= 0) mx = fmaxf(mx, e[(size_t)(r * 8 + ss) * H + h]);
    }
    float denom = expf(eself - mx);
    #pragma unroll
    for (int ss = 0; ss < KNN; ss++) {
        const int c = srcCols[r * KNN + ss];
        if (c >= 0) denom += expf(e[(size_t)(r * 8 + ss) * H + h] - mx);
    }
    const float inv = 1.f / (denom + 1e-16f);
    const int d0 = lane << 2;
    float o0, o1, o2, o3;
    {
        const float a = expf(eself - mx) * inv;
        const float4 v = *(const float4*)(xl + ((size_t)r * H + h) * 256 + d0);
        o0 = a * v.x; o1 = a * v.y; o2 = a * v.z; o3 = a * v.w;
    }
    #pragma unroll
    for (int ss = 0; ss < KNN; ss++) {
        const int c = srcCols[r * KNN + ss];
        if (c < 0) continue;
        const float a = expf(e[(size_t)(r * 8 + ss) * H + h] - mx) * inv;
        const float4 v = *(const float4*)(xl + ((size_t)c * H + h) * 256 + d0);
        o0 = fmaf(a, v.x, o0); o1 = fmaf(a, v.y, o1);
        o2 = fmaf(a, v.z, o2); o3 = fmaf(a, v.w, o3);
    }
    const float* bb = bias + (size_t)h * 256 + d0;
    o0 += bb[0]; o1 += bb[1]; o2 += bb[2]; o3 += bb[3];
    o0 = (o0 > 0.f) ? o0 : (expf(o0) - 1.f);
    o1 = (o1 > 0.f) ? o1 : (expf(o1) - 1.f);
    o2 = (o2 > 0.f) ? o2 : (expf(o2) - 1.f);
    o3 = (o3 > 0.f) ? o3 : (expf(o3) - 1.f);
    float4 res = {o0, o1, o2, o3};
    *(float4*)(out + (size_t)r * ostride + ooff + (size_t)h * 256 + d0) = res;
}

__global__ void scatter_convT_k(const float* __restrict__ f, const float* __restrict__ U,
                                const float* __restrict__ bias, float* __restrict__ xs,
                                int nw, int H, int total)
{
    int idx = blockIdx.x * 256 + threadIdx.x;
    if (idx >= total) return;
    int x = idx % H;
    int t = idx / H;
    int y = t % H;
    int o = t / H;
    int j = y / 5, a = y - j * 5;
    int i = x / 5, b = x - i * 5;
    int p = i * nw + j;
    float v = U[(size_t)p * 6400 + o * 25 + a * 5 + b] + bias[o];
    v = fmaxf(v, 0.f);
    xs[idx] = f[idx] + v;
}

__global__ void upsample_add_k(float* __restrict__ acc, const float* __restrict__ last,
                               int H, int Hs, int total)
{
    int idx = blockIdx.x * 256 + threadIdx.x;
    if (idx >= total) return;
    int x = idx % H;
    int t = idx / H;
    int y = t % H;
    int c = t / H;
    acc[idx] += last[(size_t)c * Hs * Hs + (size_t)(y >> 1) * Hs + (x >> 1)];
}

// ============================ orchestration ============================
static void run_level(void* const* d_in, float* ws, int l, int H, hipStream_t s)
{
    const float* f = (const float*)d_in[l];
    const int nh = H / 5, nw = nh, n = nh * nw, HW = H * H;

    const float* convT_w = (const float*)d_in[6]  + (size_t)l * 1638400;
    const float* convT_b = (const float*)d_in[7]  + l * 256;
    const float* conv1_w = (const float*)d_in[8]  + (size_t)l * 1638400;
    const float* conv1_b = (const float*)d_in[9]  + l * 256;
    const float* fc2_w   = (const float*)d_in[10] + (size_t)l * 65536;
    const float* fc2_b   = (const float*)d_in[11] + l * 256;
    const float* fc3_w   = (const float*)d_in[12] + (size_t)l * 131072;
    const float* fc3_b   = (const float*)d_in[13] + l * 256;
    const float* g1_wl   = (const float*)d_in[14] + (size_t)l * 524288;
    const float* g1_bl   = (const float*)d_in[15] + l * 2048;
    const float* g1_wr   = (const float*)d_in[16] + (size_t)l * 524288;
    const float* g1_br   = (const float*)d_in[17] + l * 2048;
    const float* g1_att  = (const float*)d_in[18] + l * 2048;
    const float* g1_bias = (const float*)d_in[19] + l * 2048;
    const float* g2_wl   = (const float*)d_in[20] + (size_t)l * 524288;
    const float* g2_bl   = (const float*)d_in[21] + l * 256;
    const float* g2_wr   = (const float*)d_in[22] + (size_t)l * 524288;
    const float* g2_br   = (const float*)d_in[23] + l * 256;
    const float* g2_att  = (const float*)d_in[24] + l * 256;
    const float* g2_bias = (const float*)d_in[25] + l * 256;
    const float* g3_wl   = (const float*)d_in[26] + (size_t)l * 524288;
    const float* g3_bl   = (const float*)d_in[27] + l * 2048;
    const float* g3_wr   = (const float*)d_in[28] + (size_t)l * 524288;
    const float* g3_br   = (const float*)d_in[29] + l * 2048;
    const float* g3_att  = (const float*)d_in[30] + l * 2048;
    const float* g3_bias = (const float*)d_in[31] + l * 2048;
    const float* g4_wl   = (const float*)d_in[32] + (size_t)l * 524288;
    const float* g4_bl   = (const float*)d_in[33] + l * 256;
    const float* g4_wr   = (const float*)d_in[34] + (size_t)l * 524288;
    const float* g4_br   = (const float*)d_in[35] + l * 256;
    const float* g4_att  = (const float*)d_in[36] + l * 256;
    const float* g4_bias = (const float*)d_in[37] + l * 256;

    float* patches = ws + OFF_ARENA;   // also U
    float* xs    = ws + (l == 0 ? OFF_XS0 : OFF_XS1);
    float* emb   = ws + OFF_EMB;
    float* emb2  = ws + OFF_EMB2;
    float* score = ws + OFF_LAST;
    float* xl    = ws + OFF_XL;
    float* xr    = ws + OFF_XR;
    float* h1    = ws + OFF_H1;
    float* xl2   = ws + OFF_XL2;
    float* xr2   = ws + OFF_XR2;
    float* cat   = ws + OFF_CAT;
    float* hc    = ws + OFF_HC;
    float* ebuf  = ws + OFF_E;
    int* srcF = (int*)(ws + OFF_SRCF);
    int* srcS = (int*)(ws + OFF_SRCS);
    unsigned short* ba = (unsigned short*)(ws + OFF_BF_A);
    unsigned short* bw = (unsigned short*)(ws + OFF_BF_W);
    float* skpart = ws + OFF_XL;   // free until g1; 16*1600*256 = 6.55M floats fits XL+XR

    { int tot = n * 6400;
      extract_patches_k<<<dim3((tot + 255) / 256), dim3(256), 0, s>>>(f, patches, nw, H, tot); }

    // exact fp32 path feeding the top-k graph selection (split-K for occupancy)
    gemm32_sk<1, true>(s, patches, conv1_w, conv1_b, emb, skpart, n, 256, 6400, 16);
    gemm32<1, true>(s, emb, fc2_w, fc2_b, emb2, n, 256, 256);
    gemm32<0, false>(s, emb2, emb2, nullptr, score, n, n, 256);
    topk_feat_k<<<dim3(n), dim3(64), 0, s>>>(score, srcF, n);
    topk_spatial_k<<<dim3(n), dim3(64), 0, s>>>(srcS, n, nw);

    // g1: feature graph, emb2 -> h1 [n,2048], heads=8 (bf16 MFMA)
    cast_bf(s, emb2, ba, n * 256);
    cast_t(s, g1_wl, bw, 256, 2048);
    bgemm<BT_NT, 0, 1, false>(s, ba, bw, g1_bl, nullptr, 0, xl, n, 2048, 256);
    cast_t(s, g1_wr, bw, 256, 2048);
    bgemm<BT_NT, 0, 1, false>(s, ba, bw, g1_br, nullptr, 0, xr, n, 2048, 256);
    { int tw = n * 8 * 8;
      gat_logits_k<<<dim3((tw + 3) / 4), dim3(256), 0, s>>>(xl, xr, g1_att, srcF, ebuf, n, 8);
      int aw = n * 8;
      gat_aggregate_k<<<dim3((aw + 3) / 4), dim3(256), 0, s>>>(xl, ebuf, srcF, g1_bias, h1, n, 8, 2048, 0); }

    // g2: feature graph, h1 -> cat[:, :256], heads=1
    cast_bf(s, h1, ba, n * 2048);
    cast_t(s, g2_wl, bw, 2048, 256);
    bgemm<BT_NT, 0, 1, false>(s, ba, bw, g2_bl, nullptr, 0, xl2, n, 256, 2048);
    cast_t(s, g2_wr, bw, 2048, 256);
    bgemm<BT_NT, 0, 1, false>(s, ba, bw, g2_br, nullptr, 0, xr2, n, 256, 2048);
    { int tw = n * 8;
      gat_logits_k<<<dim3((tw + 3) / 4), dim3(256), 0, s>>>(xl2, xr2, g2_att, srcF, ebuf, n, 1);
      int aw = n;
      gat_aggregate_k<<<dim3((aw + 3) / 4), dim3(256), 0, s>>>(xl2, ebuf, srcF, g2_bias, cat, n, 1, 512, 0); }

    // g3: spatial graph, emb2 -> h1 [n,2048], heads=8
    cast_bf(s, emb2, ba, n * 256);
    cast_t(s, g3_wl, bw, 256, 2048);
    bgemm<BT_NT, 0, 1, false>(s, ba, bw, g3_bl, nullptr, 0, xl, n, 2048, 256);
    cast_t(s, g3_wr, bw, 256, 2048);
    bgemm<BT_NT, 0, 1, false>(s, ba, bw, g3_br, nullptr, 0, xr, n, 2048, 256);
    { int tw = n * 8 * 8;
      gat_logits_k<<<dim3((tw + 3) / 4), dim3(256), 0, s>>>(xl, xr, g3_att, srcS, ebuf, n, 8);
      int aw = n * 8;
      gat_aggregate_k<<<dim3((aw + 3) / 4), dim3(256), 0, s>>>(xl, ebuf, srcS, g3_bias, h1, n, 8, 2048, 0); }

    // g4: spatial graph, h1 -> cat[:, 256:], heads=1
    cast_bf(s, h1, ba, n * 2048);
    cast_t(s, g4_wl, bw, 2048, 256);
    bgemm<BT_NT, 0, 1, false>(s, ba, bw, g4_bl, nullptr, 0, xl2, n, 256, 2048);
    cast_t(s, g4_wr, bw, 2048, 256);
    bgemm<BT_NT, 0, 1, false>(s, ba, bw, g4_br, nullptr, 0, xr2, n, 256, 2048);
    { int tw = n * 8;
      gat_logits_k<<<dim3((tw + 3) / 4), dim3(256), 0, s>>>(xl2, xr2, g4_att, srcS, ebuf, n, 1);
      int aw = n;
      gat_aggregate_k<<<dim3((aw + 3) / 4), dim3(256), 0, s>>>(xl2, ebuf, srcS, g4_bias, cat, n, 1, 512, 256); }

    // hc = relu(cat @ fc3_w^T + fc3_b) + h2
    cast_bf(s, cat, ba, n * 512);
    cast_bf(s, fc3_w, bw, 131072);
    bgemm<BT_NT, 1, 1, true>(s, ba, bw, fc3_b, cat + 256, 512, hc, n, 256, 512);
    // U = hc @ convT_w
    cast_bf(s, hc, ba, n * 256);
    cast_t(s, convT_w, bw, 256, 6400);
    bgemm<BT_NT, 0, 1, false>(s, ba, bw, nullptr, nullptr, 0, patches, n, 6400, 256);
    { int tot = 256 * HW;
      scatter_convT_k<<<dim3((tot + 255) / 256), dim3(256), 0, s>>>(f, patches, convT_b, xs, nw, H, tot); }
}

extern "C" void kernel_launch(void* const* d_in, const int* in_sizes, int n_in,
                              void* d_out, int out_size, void* d_ws, size_t ws_size,
                              hipStream_t stream)
{
    float* ws  = (float*)d_ws;
    float* out = (float*)d_out;

    run_level(d_in, ws, 0, 200, stream);
    run_level(d_in, ws, 1, 100, stream);

    const float* inner_w = (const float*)d_in[2];
    const float* inner_b = (const float*)d_in[3];
    const float* layer_w = (const float*)d_in[4];
    const float* layer_b = (const float*)d_in[5];
    float* xs0    = ws + OFF_XS0;
    float* xs1    = ws + OFF_XS1;
    float* last   = ws + OFF_LAST;
    float* inner0 = ws + OFF_ARENA;
    unsigned short* bimg = (unsigned short*)(ws + OFF_XL);
    unsigned short* bw   = (unsigned short*)(ws + OFF_BF_W);

    // last = conv1x1(xs1); out1 = conv3x3(last)
    cast_t(stream, xs1, bimg, 256, 10000);
    cast_bf(stream, inner_w + 65536, bw, 65536);
    bgemm<BT_NT, 0, 0, false>(stream, bw, bimg, inner_b + 256, nullptr, 0,
                              last, 256, 10000, 256);
    cast_bf(stream, last, bimg, 2560000);
    cast_bf(stream, layer_w + 589824, bw, 589824);
    bgemm<BT_CONV, 0, 0, false>(stream, bw, bimg, layer_b + 256, nullptr, 0,
                                out + 10240000, 256, 10000, 2304, 100, 100);

    // inner0 = conv1x1(xs0) + nearest(last); out0 = conv3x3(inner0)
    cast_t(stream, xs0, bimg, 256, 40000);
    cast_bf(stream, inner_w, bw, 65536);
    bgemm<BT_NT, 0, 0, false>(stream, bw, bimg, inner_b, nullptr, 0,
                              inner0, 256, 40000, 256);
    { int tot = 256 * 40000;
      upsample_add_k<<<dim3((tot + 255) / 256), dim3(256), 0, stream>>>(inner0, last, 200, 100, tot); }
    cast_bf(stream, inner0, bimg, 10240000);
    cast_bf(stream, layer_w, bw, 589824);
    bgemm<BT_CONV, 0, 0, false>(stream, bw, bimg, layer_b, nullptr, 0,
                                out, 256, 40000, 2304, 200, 200);
}

// Round 4
// 1610.640 us; speedup vs baseline: 2.7430x; 1.3469x over previous
//
#include <hip/hip_runtime.h>
#include <cstdint>
#include <cstddef>
#include <math.h>

#define KNN 7

using short8  = __attribute__((ext_vector_type(8))) short;
using floatx4 = __attribute__((ext_vector_type(4))) float;

// ---------------- workspace layout (in floats) ----------------
static const size_t OFF_ARENA = 0;          // 10,240,000  patches / U / inner0
static const size_t OFF_XS0   = 10240000;   // 10,240,000
static const size_t OFF_XS1   = 20480000;   //  2,560,000
static const size_t OFF_LAST  = 23040000;   //  2,560,000  score (GNN) / last (FPN)
static const size_t OFF_EMB   = 25600000;   //    409,600
static const size_t OFF_EMB2  = 26009600;   //    409,600
static const size_t OFF_XL    = 26419200;   //  6,553,600 XL+XR: xlr / split-K part / FPN bf16 img
static const size_t OFF_H1    = 32972800;   //  3,276,800
static const size_t OFF_XL2   = 36249600;   //    819,200 (xlr2 spans XL2+XR2)
static const size_t OFF_CAT   = 37068800;   //    819,200
static const size_t OFF_HC    = 37888000;   //    409,600 (also bcat scratch during GAT)
static const size_t OFF_E     = 38297600;   //    102,400
static const size_t OFF_SRCF  = 38400000;   //     11,200 ints
static const size_t OFF_SRCS  = 38411200;   //     11,200 ints
static const size_t OFF_BF_A  = 38422400;   //  1,700,000 floats = 3.4M bf16 (A casts)
static const size_t OFF_BF_W  = 40122400;   //    850,000 floats = 1.7M bf16 (W casts)
// total ~164 MB

static __device__ __forceinline__ unsigned short f2bf(float f) {
    union { float f; unsigned u; } v; v.f = f;
    unsigned u = v.u;
    unsigned r = u + 0x7fffu + ((u >> 16) & 1u);   // RNE
    return (unsigned short)(r >> 16);
}

// ============================ fp32 tiled GEMM (NT; exact path) ============
template<int ACT, bool BIAS>
__global__ __launch_bounds__(256)
void gemm_k(const float* __restrict__ A, const float* __restrict__ B,
            const float* __restrict__ bias, float* __restrict__ C, int M, int N, int K)
{
    __shared__ float As[16][68];
    __shared__ float Bs[16][68];
    const int tid = threadIdx.x;
    const int bm0 = blockIdx.y * 64;
    const int bn0 = blockIdx.x * 64;
    const int tx = tid & 15, ty = tid >> 4;
    const int lrow = tid >> 2;
    const int lk4  = (tid & 3) << 2;
    float acc[4][4] = {{0.f,0.f,0.f,0.f},{0.f,0.f,0.f,0.f},{0.f,0.f,0.f,0.f},{0.f,0.f,0.f,0.f}};

    for (int k0 = 0; k0 < K; k0 += 16) {
        {
            const int m = bm0 + lrow;
            float4 v = {0.f,0.f,0.f,0.f};
            if (m < M) v = *(const float4*)(A + (size_t)m * K + (k0 + lk4));
            As[lk4+0][lrow]=v.x; As[lk4+1][lrow]=v.y; As[lk4+2][lrow]=v.z; As[lk4+3][lrow]=v.w;
        }
        {
            const int nn = bn0 + lrow;
            float4 v = {0.f,0.f,0.f,0.f};
            if (nn < N) v = *(const float4*)(B + (size_t)nn * K + (k0 + lk4));
            Bs[lk4+0][lrow]=v.x; Bs[lk4+1][lrow]=v.y; Bs[lk4+2][lrow]=v.z; Bs[lk4+3][lrow]=v.w;
        }
        __syncthreads();
        #pragma unroll
        for (int k = 0; k < 16; k++) {
            const float4 av = *(const float4*)&As[k][ty << 2];
            const float4 bv = *(const float4*)&Bs[k][tx << 2];
            const float a0=av.x,a1=av.y,a2=av.z,a3=av.w;
            const float b0=bv.x,b1=bv.y,b2=bv.z,b3=bv.w;
            acc[0][0]=fmaf(a0,b0,acc[0][0]); acc[0][1]=fmaf(a0,b1,acc[0][1]);
            acc[0][2]=fmaf(a0,b2,acc[0][2]); acc[0][3]=fmaf(a0,b3,acc[0][3]);
            acc[1][0]=fmaf(a1,b0,acc[1][0]); acc[1][1]=fmaf(a1,b1,acc[1][1]);
            acc[1][2]=fmaf(a1,b2,acc[1][2]); acc[1][3]=fmaf(a1,b3,acc[1][3]);
            acc[2][0]=fmaf(a2,b0,acc[2][0]); acc[2][1]=fmaf(a2,b1,acc[2][1]);
            acc[2][2]=fmaf(a2,b2,acc[2][2]); acc[2][3]=fmaf(a2,b3,acc[2][3]);
            acc[3][0]=fmaf(a3,b0,acc[3][0]); acc[3][1]=fmaf(a3,b1,acc[3][1]);
            acc[3][2]=fmaf(a3,b2,acc[3][2]); acc[3][3]=fmaf(a3,b3,acc[3][3]);
        }
        __syncthreads();
    }
    #pragma unroll
    for (int i = 0; i < 4; i++) {
        const int m = bm0 + (ty << 2) + i;
        if (m >= M) continue;
        #pragma unroll
        for (int jj = 0; jj < 4; jj++) {
            const int nn = bn0 + (tx << 2) + jj;
            if (nn >= N) continue;
            float v = acc[i][jj];
            if (BIAS) v += bias[nn];
            if (ACT == 1) v = fmaxf(v, 0.f);
            C[(size_t)m * N + nn] = v;
        }
    }
}

template<int ACT, bool BIAS>
static inline void gemm32(hipStream_t s, const float* A, const float* B, const float* bias,
                          float* C, int M, int N, int K)
{
    dim3 g((N + 63) / 64, (M + 63) / 64);
    gemm_k<ACT, BIAS><<<g, dim3(256), 0, s>>>(A, B, bias, C, M, N, K);
}

// ---- split-K variant ----
__global__ __launch_bounds__(256)
void gemm32_sk_k(const float* __restrict__ A, const float* __restrict__ B,
                 float* __restrict__ part, int M, int N, int K, int Kc)
{
    __shared__ float As[16][68];
    __shared__ float Bs[16][68];
    const int tid = threadIdx.x;
    const int bm0 = blockIdx.y * 64;
    const int bn0 = blockIdx.x * 64;
    const int sblk = blockIdx.z;
    const int kbeg = sblk * Kc;
    const int kend = (kbeg + Kc < K) ? kbeg + Kc : K;
    const int tx = tid & 15, ty = tid >> 4;
    const int lrow = tid >> 2;
    const int lk4  = (tid & 3) << 2;
    float acc[4][4] = {{0.f,0.f,0.f,0.f},{0.f,0.f,0.f,0.f},{0.f,0.f,0.f,0.f},{0.f,0.f,0.f,0.f}};

    for (int k0 = kbeg; k0 < kend; k0 += 16) {
        {
            const int m = bm0 + lrow;
            float4 v = {0.f,0.f,0.f,0.f};
            if (m < M) v = *(const float4*)(A + (size_t)m * K + (k0 + lk4));
            As[lk4+0][lrow]=v.x; As[lk4+1][lrow]=v.y; As[lk4+2][lrow]=v.z; As[lk4+3][lrow]=v.w;
        }
        {
            const int nn = bn0 + lrow;
            float4 v = {0.f,0.f,0.f,0.f};
            if (nn < N) v = *(const float4*)(B + (size_t)nn * K + (k0 + lk4));
            Bs[lk4+0][lrow]=v.x; Bs[lk4+1][lrow]=v.y; Bs[lk4+2][lrow]=v.z; Bs[lk4+3][lrow]=v.w;
        }
        __syncthreads();
        #pragma unroll
        for (int k = 0; k < 16; k++) {
            const float4 av = *(const float4*)&As[k][ty << 2];
            const float4 bv = *(const float4*)&Bs[k][tx << 2];
            const float a0=av.x,a1=av.y,a2=av.z,a3=av.w;
            const float b0=bv.x,b1=bv.y,b2=bv.z,b3=bv.w;
            acc[0][0]=fmaf(a0,b0,acc[0][0]); acc[0][1]=fmaf(a0,b1,acc[0][1]);
            acc[0][2]=fmaf(a0,b2,acc[0][2]); acc[0][3]=fmaf(a0,b3,acc[0][3]);
            acc[1][0]=fmaf(a1,b0,acc[1][0]); acc[1][1]=fmaf(a1,b1,acc[1][1]);
            acc[1][2]=fmaf(a1,b2,acc[1][2]); acc[1][3]=fmaf(a1,b3,acc[1][3]);
            acc[2][0]=fmaf(a2,b0,acc[2][0]); acc[2][1]=fmaf(a2,b1,acc[2][1]);
            acc[2][2]=fmaf(a2,b2,acc[2][2]); acc[2][3]=fmaf(a2,b3,acc[2][3]);
            acc[3][0]=fmaf(a3,b0,acc[3][0]); acc[3][1]=fmaf(a3,b1,acc[3][1]);
            acc[3][2]=fmaf(a3,b2,acc[3][2]); acc[3][3]=fmaf(a3,b3,acc[3][3]);
        }
        __syncthreads();
    }
    float* P = part + (size_t)sblk * M * N;
    #pragma unroll
    for (int i = 0; i < 4; i++) {
        const int m = bm0 + (ty << 2) + i;
        if (m >= M) continue;
        #pragma unroll
        for (int jj = 0; jj < 4; jj++) {
            const int nn = bn0 + (tx << 2) + jj;
            if (nn >= N) continue;
            P[(size_t)m * N + nn] = acc[i][jj];
        }
    }
}

template<int ACT, bool BIAS>
__global__ void sk_reduce_k(const float* __restrict__ part, const float* __restrict__ bias,
                            float* __restrict__ C, int MN, int N, int S)
{
    const int i4 = (blockIdx.x * 256 + threadIdx.x) * 4;
    if (i4 >= MN) return;
    float4 a = *(const float4*)(part + i4);
    for (int s = 1; s < S; s++) {
        const float4 b = *(const float4*)(part + (size_t)s * MN + i4);
        a.x += b.x; a.y += b.y; a.z += b.z; a.w += b.w;
    }
    if (BIAS) {
        const int n = i4 % N;
        a.x += bias[n]; a.y += bias[n + 1]; a.z += bias[n + 2]; a.w += bias[n + 3];
    }
    if (ACT == 1) {
        a.x = fmaxf(a.x, 0.f); a.y = fmaxf(a.y, 0.f);
        a.z = fmaxf(a.z, 0.f); a.w = fmaxf(a.w, 0.f);
    }
    *(float4*)(C + i4) = a;
}

template<int ACT, bool BIAS>
static inline void gemm32_sk(hipStream_t s, const float* A, const float* B, const float* bias,
                             float* C, float* part, int M, int N, int K, int S)
{
    const int Kc = ((K / S + 15) / 16) * 16;
    dim3 g((N + 63) / 64, (M + 63) / 64, S);
    gemm32_sk_k<<<g, dim3(256), 0, s>>>(A, B, part, M, N, K, Kc);
    const int MN = M * N;
    sk_reduce_k<ACT, BIAS><<<dim3((MN / 4 + 255) / 256), dim3(256), 0, s>>>(part, bias, C, MN, N, S);
}

// ============================ bf16 MFMA GEMM ============================
// BT_NT: B is [N,K] row-major bf16.
// BT_CONV2: 3x3 SAME conv, NHWC: B = bf16 image [imH*imW, 256] (position-major),
//           A = weights reordered [O][j*256+c] (tap-major). K = 9*256.
enum { BT_NT = 0, BT_CONV2 = 2 };

template<int BT, int ACT, int BAX, bool ADDMAT>
__global__ __launch_bounds__(256)
void bgemm_k(const unsigned short* __restrict__ A, const unsigned short* __restrict__ B,
             const float* __restrict__ bias, const float* __restrict__ Dmat, int Dld,
             float* __restrict__ C, int M, int N, int K, int imH, int imW)
{
    __shared__ unsigned short Asl[128][40];
    __shared__ unsigned short Bsl[128][40];
    const int tid  = threadIdx.x;
    const int lane = tid & 63;
    const int wid  = tid >> 6;
    const int quad = lane >> 4;
    const int l15  = lane & 15;
    const int wy = wid >> 1, wx = wid & 1;
    const int bm0 = blockIdx.y * 128;
    const int bn0 = blockIdx.x * 128;

    floatx4 zero = {0.f, 0.f, 0.f, 0.f};
    floatx4 acc[4][4];
    #pragma unroll
    for (int i = 0; i < 4; i++)
        #pragma unroll
        for (int j = 0; j < 4; j++) acc[i][j] = zero;

    const int srow = tid >> 1;          // 0..127
    const int skc  = (tid & 1) << 4;    // 0 or 16

    // CONV2: position geometry computed once
    int cy = 0, cx = 0;
    bool cok = false;
    if (BT == BT_CONV2) {
        const int p = bn0 + srow;
        cok = p < N;
        const int pp = cok ? p : 0;
        cy = pp / imW; cx = pp - cy * imW;
    }

    for (int k0 = 0; k0 < K; k0 += 32) {
        {   // A tile: [128 m][32 k]
            const int m = bm0 + srow;
            uint4 v0 = {0,0,0,0}, v1 = {0,0,0,0};
            if (m < M) {
                const uint4* p = (const uint4*)(A + (size_t)m * K + k0 + skc);
                v0 = p[0]; v1 = p[1];
            }
            *(uint4*)&Asl[srow][skc]     = v0;
            *(uint4*)&Asl[srow][skc + 8] = v1;
        }
        if (BT == BT_NT) {
            const int nn = bn0 + srow;
            uint4 v0 = {0,0,0,0}, v1 = {0,0,0,0};
            if (nn < N) {
                const uint4* p = (const uint4*)(B + (size_t)nn * K + k0 + skc);
                v0 = p[0]; v1 = p[1];
            }
            *(uint4*)&Bsl[srow][skc]     = v0;
            *(uint4*)&Bsl[srow][skc + 8] = v1;
        } else {   // CONV2: uniform tap per chunk, 2x dwordx4 per thread
            const int jj = k0 >> 8;                 // tap 0..8 (uniform)
            const int j3 = jj / 3;
            const int dy = j3 - 1, dx = jj - j3 * 3 - 1;
            const int c0 = k0 & 255;
            const int yy = cy + dy, xx = cx + dx;
            uint4 v0 = {0,0,0,0}, v1 = {0,0,0,0};
            if (cok && (unsigned)yy < (unsigned)imH && (unsigned)xx < (unsigned)imW) {
                const uint4* p = (const uint4*)(B + ((size_t)yy * imW + xx) * 256 + c0 + skc);
                v0 = p[0]; v1 = p[1];
            }
            *(uint4*)&Bsl[srow][skc]     = v0;
            *(uint4*)&Bsl[srow][skc + 8] = v1;
        }
        __syncthreads();
        short8 af[4], bfr[4];
        #pragma unroll
        for (int i = 0; i < 4; i++)
            af[i] = *(const short8*)&Asl[wy * 64 + i * 16 + l15][quad * 8];
        #pragma unroll
        for (int j = 0; j < 4; j++)
            bfr[j] = *(const short8*)&Bsl[wx * 64 + j * 16 + l15][quad * 8];
        #pragma unroll
        for (int i = 0; i < 4; i++)
            #pragma unroll
            for (int j = 0; j < 4; j++)
                acc[i][j] = __builtin_amdgcn_mfma_f32_16x16x32_bf16(af[i], bfr[j], acc[i][j], 0, 0, 0);
        __syncthreads();
    }

    #pragma unroll
    for (int i = 0; i < 4; i++) {
        #pragma unroll
        for (int r = 0; r < 4; r++) {
            const int m = bm0 + wy * 64 + i * 16 + quad * 4 + r;
            if (m >= M) continue;
            #pragma unroll
            for (int j = 0; j < 4; j++) {
                const int n = bn0 + wx * 64 + j * 16 + l15;
                if (n >= N) continue;
                float v = acc[i][j][r];
                if (bias != nullptr) v += (BAX == 0) ? bias[m] : bias[n];
                if (ACT == 1) v = fmaxf(v, 0.f);
                if (ADDMAT) v += Dmat[(size_t)m * Dld + n];
                C[(size_t)m * N + n] = v;
            }
        }
    }
}

template<int BT, int ACT, int BAX, bool ADDMAT>
static inline void bgemm(hipStream_t s, const unsigned short* A, const unsigned short* B,
                         const float* bias, const float* D, int Dld, float* C,
                         int M, int N, int K, int imH = 0, int imW = 0)
{
    dim3 g((N + 127) / 128, (M + 127) / 128);
    bgemm_k<BT, ACT, BAX, ADDMAT><<<g, dim3(256), 0, s>>>(A, B, bias, D, Dld, C, M, N, K, imH, imW);
}

// ============================ cast / reorder kernels ============================
__global__ void cast_bf16_k(const float* __restrict__ in, unsigned short* __restrict__ out, int total)
{
    const int i4 = (blockIdx.x * 256 + threadIdx.x) * 4;
    if (i4 + 4 <= total) {
        const float4 v = *(const float4*)(in + i4);
        ushort4 o;
        o.x = f2bf(v.x); o.y = f2bf(v.y); o.z = f2bf(v.z); o.w = f2bf(v.w);
        *(ushort4*)(out + i4) = o;
    } else {
        for (int i = i4; i < total; i++) out[i] = f2bf(in[i]);
    }
}

static inline void cast_bf(hipStream_t s, const float* in, unsigned short* out, int total)
{
    cast_bf16_k<<<dim3((total / 4 + 255) / 256), dim3(256), 0, s>>>(in, out, total);
}

__global__ void cast_t_k(const float* __restrict__ in, unsigned short* __restrict__ out, int K, int N)
{
    __shared__ float tile[64][65];
    const int n0 = blockIdx.x * 64;
    const int k0 = blockIdx.y * 64;
    const int t = threadIdx.x;
    const int r = t >> 2;
    const int c4 = (t & 3) << 4;
    {
        const int k = k0 + r;
        if (k < K && n0 + c4 + 16 <= N) {
            const float4* p = (const float4*)(in + (size_t)k * N + n0 + c4);
            *(float4*)&tile[r][c4]      = p[0];
            *(float4*)&tile[r][c4 + 4]  = p[1];
            *(float4*)&tile[r][c4 + 8]  = p[2];
            *(float4*)&tile[r][c4 + 12] = p[3];
        } else {
            for (int i = 0; i < 16; i++)
                tile[r][c4 + i] = (k < K && n0 + c4 + i < N) ? in[(size_t)k * N + n0 + c4 + i] : 0.f;
        }
    }
    __syncthreads();
    const int n = n0 + r;
    if (n >= N) return;
    unsigned short tmp[16];
    #pragma unroll
    for (int i = 0; i < 16; i++) tmp[i] = f2bf(tile[c4 + i][r]);
    if (k0 + 64 <= K) {
        *(uint4*)(out + (size_t)n * K + k0 + c4)     = *(uint4*)&tmp[0];
        *(uint4*)(out + (size_t)n * K + k0 + c4 + 8) = *(uint4*)&tmp[8];
    } else {
        for (int i = 0; i < 16; i++)
            if (k0 + c4 + i < K) out[(size_t)n * K + k0 + c4 + i] = tmp[i];
    }
}

static inline void cast_t(hipStream_t s, const float* in, unsigned short* out, int K, int N)
{
    cast_t_k<<<dim3((N + 63) / 64, (K + 63) / 64), dim3(256), 0, s>>>(in, out, K, N);
}

// conv3x3 weight reorder: in fp32 [O][C][3][3] -> out bf16 [O][j*256+c]
__global__ void reorder_w3_k(const float* __restrict__ in, unsigned short* __restrict__ out)
{
    const int idx = blockIdx.x * 256 + threadIdx.x;
    if (idx >= 589824) return;
    const int o = idx / 2304;
    const int r = idx - o * 2304;
    const int j = r >> 8;
    const int c = r & 255;
    out[idx] = f2bf(in[(size_t)o * 2304 + c * 9 + j]);
}

// ============================ small kernels ============================
__global__ void extract_patches_k(const float* __restrict__ f, float* __restrict__ patches,
                                  int nw, int H, int total)
{
    int idx = blockIdx.x * 256 + threadIdx.x;
    if (idx >= total) return;
    int q = idx % 6400;
    int p = idx / 6400;
    int c = q / 25;
    int rem = q - c * 25;
    int a = rem / 5, b = rem - (rem / 5) * 5;
    int ih = p / nw, iw = p - (p / nw) * nw;
    patches[idx] = f[(size_t)c * H * H + (size_t)(ih * 5 + a) * H + (iw * 5 + b)];
}

__global__ void topk_feat_k(const float* __restrict__ score, int* __restrict__ srcCols, int n)
{
    const int r = blockIdx.x;
    const int lane = threadIdx.x;
    const float* row = score + (size_t)r * n;
    int   sel[KNN];
    float selv[KNN];
    #pragma unroll
    for (int t = 0; t < KNN; t++) {
        float best = -__builtin_huge_valf();
        int   bidx = 0x7fffffff;
        for (int c = lane; c < n; c += 64) {
            bool taken = false;
            #pragma unroll
            for (int u = 0; u < KNN; u++)
                if (u < t && sel[u] == c) taken = true;
            if (taken) continue;
            float v = row[c];
            if (v > best || (v == best && c < bidx)) { best = v; bidx = c; }
        }
        #pragma unroll
        for (int off = 32; off > 0; off >>= 1) {
            float ov = __shfl_down(best, off);
            int   oi = __shfl_down(bidx, off);
            if (ov > best || (ov == best && oi < bidx)) { best = ov; bidx = oi; }
        }
        best = __shfl(best, 0);
        bidx = __shfl(bidx, 0);
        sel[t] = bidx; selv[t] = best;
    }
    if (lane < KNN) {
        int c = -1; float v = 0.f;
        #pragma unroll
        for (int t = 0; t < KNN; t++)
            if (lane == t) { c = sel[t]; v = selv[t]; }
        srcCols[r * KNN + lane] = (c > r && v != 0.0f) ? c : -1;
    }
}

__global__ void topk_spatial_k(int* __restrict__ srcCols, int n, int nw)
{
    const int r = blockIdx.x;
    const int lane = threadIdx.x;
    const int ri = r / nw, rj = r - (r / nw) * nw;
    int sel[KNN];
    #pragma unroll
    for (int t = 0; t < KNN; t++) {
        int bkey = 0x7fffffff;
        for (int c = lane; c < n; c += 64) {
            bool taken = false;
            #pragma unroll
            for (int u = 0; u < KNN; u++)
                if (u < t && sel[u] == c) taken = true;
            if (taken) continue;
            const int ci = c / nw, cj = c - (c / nw) * nw;
            const int dy = (ri - ci) * 5, dx = (rj - cj) * 5;
            const int d2 = dy * dy + dx * dx;
            const int key = (d2 << 11) | c;
            if (key < bkey) bkey = key;
        }
        #pragma unroll
        for (int off = 32; off > 0; off >>= 1) {
            int ok = __shfl_down(bkey, off);
            if (ok < bkey) bkey = ok;
        }
        bkey = __shfl(bkey, 0);
        sel[t] = bkey & 2047;
    }
    if (lane < KNN) {
        int c = -1;
        #pragma unroll
        for (int t = 0; t < KNN; t++) if (lane == t) c = sel[t];
        srcCols[r * KNN + lane] = (c > r) ? c : -1;
    }
}

// xl/xr rows have stride xstride; element (node,h,d) at node*xstride + h*256 + d
__global__ void gat_logits_k(const float* __restrict__ xl, const float* __restrict__ xr,
                             int xstride, const float* __restrict__ att,
                             const int* __restrict__ srcCols,
                             float* __restrict__ e, int n, int H)
{
    const int wid = (blockIdx.x * blockDim.x + threadIdx.x) >> 6;
    const int lane = threadIdx.x & 63;
    if (wid >= n * 8 * H) return;
    const int h = wid % H;
    const int es = wid / H;
    const int r = es >> 3, s = es & 7;
    int src;
    if (s == 7) src = r;
    else { src = srcCols[r * KNN + s]; if (src < 0) return; }
    const float* pl = xl + (size_t)src * xstride + h * 256;
    const float* pr = xr + (size_t)r * xstride + h * 256;
    const float* pa = att + (size_t)h * 256;
    float sum = 0.f;
    #pragma unroll
    for (int it = 0; it < 4; it++) {
        const int d = lane + it * 64;
        float m = pl[d] + pr[d];
        m = (m > 0.f) ? m : 0.2f * m;
        sum += m * pa[d];
    }
    #pragma unroll
    for (int off = 32; off > 0; off >>= 1) sum += __shfl_down(sum, off);
    if (lane == 0) e[(size_t)es * H + h] = sum;
}

__global__ void gat_aggregate_k(const float* __restrict__ xl, int xstride,
                                const float* __restrict__ e,
                                const int* __restrict__ srcCols, const float* __restrict__ bias,
                                float* __restrict__ out, int n, int H, int ostride, int ooff)
{
    const int wid = (blockIdx.x * blockDim.x + threadIdx.x) >> 6;
    const int lane = threadIdx.x & 63;
    if (wid >= n * H) return;
    const int h = wid % H;
    const int r = wid / H;
    const float eself = e[(size_t)(r * 8 + 7) * H + h];
    float mx = eself;
    #pragma unroll
    for (int ss = 0; ss < KNN; ss++) {
        const int c = srcCols[r * KNN + ss];
        if (c >= 0) mx = fmaxf(mx, e[(size_t)(r * 8 + ss) * H + h]);
    }
    float denom = expf(eself - mx);
    #pragma unroll
    for (int ss = 0; ss < KNN; ss++) {
        const int c = srcCols[r * KNN + ss];
        if (c >= 0) denom += expf(e[(size_t)(r * 8 + ss) * H + h] - mx);
    }
    const float inv = 1.f / (denom + 1e-16f);
    const int d0 = lane << 2;
    float o0, o1, o2, o3;
    {
        const float a = expf(eself - mx) * inv;
        const float4 v = *(const float4*)(xl + (size_t)r * xstride + h * 256 + d0);
        o0 = a * v.x; o1 = a * v.y; o2 = a * v.z; o3 = a * v.w;
    }
    #pragma unroll
    for (int ss = 0; ss < KNN; ss++) {
        const int c = srcCols[r * KNN + ss];
        if (c < 0) continue;
        const float a = expf(e[(size_t)(r * 8 + ss) * H + h] - mx) * inv;
        const float4 v = *(const float4*)(xl + (size_t)c * xstride + h * 256 + d0);
        o0 = fmaf(a, v.x, o0); o1 = fmaf(a, v.y, o1);
        o2 = fmaf(a, v.z, o2); o3 = fmaf(a, v.w, o3);
    }
    const float* bb = bias + (size_t)h * 256 + d0;
    o0 += bb[0]; o1 += bb[1]; o2 += bb[2]; o3 += bb[3];
    o0 = (o0 > 0.f) ? o0 : (expf(o0) - 1.f);
    o1 = (o1 > 0.f) ? o1 : (expf(o1) - 1.f);
    o2 = (o2 > 0.f) ? o2 : (expf(o2) - 1.f);
    o3 = (o3 > 0.f) ? o3 : (expf(o3) - 1.f);
    float4 res = {o0, o1, o2, o3};
    *(float4*)(out + (size_t)r * ostride + ooff + (size_t)h * 256 + d0) = res;
}

__global__ void scatter_convT_k(const float* __restrict__ f, const float* __restrict__ U,
                                const float* __restrict__ bias, float* __restrict__ xs,
                                int nw, int H, int total)
{
    int idx = blockIdx.x * 256 + threadIdx.x;
    if (idx >= total) return;
    int x = idx % H;
    int t = idx / H;
    int y = t % H;
    int o = t / H;
    int j = y / 5, a = y - j * 5;
    int i = x / 5, b = x - i * 5;
    int p = i * nw + j;
    float v = U[(size_t)p * 6400 + o * 25 + a * 5 + b] + bias[o];
    v = fmaxf(v, 0.f);
    xs[idx] = f[idx] + v;
}

__global__ void upsample_add_k(float* __restrict__ acc, const float* __restrict__ last,
                               int H, int Hs, int total)
{
    int idx = blockIdx.x * 256 + threadIdx.x;
    if (idx >= total) return;
    int x = idx % H;
    int t = idx / H;
    int y = t % H;
    int c = t / H;
    acc[idx] += last[(size_t)c * Hs * Hs + (size_t)(y >> 1) * Hs + (x >> 1)];
}

// ============================ orchestration ============================
static void run_level(void* const* d_in, float* ws, int l, int H, hipStream_t s)
{
    const float* f = (const float*)d_in[l];
    const int nh = H / 5, nw = nh, n = nh * nw, HW = H * H;

    const float* convT_w = (const float*)d_in[6]  + (size_t)l * 1638400;
    const float* convT_b = (const float*)d_in[7]  + l * 256;
    const float* conv1_w = (const float*)d_in[8]  + (size_t)l * 1638400;
    const float* conv1_b = (const float*)d_in[9]  + l * 256;
    const float* fc2_w   = (const float*)d_in[10] + (size_t)l * 65536;
    const float* fc2_b   = (const float*)d_in[11] + l * 256;
    const float* fc3_w   = (const float*)d_in[12] + (size_t)l * 131072;
    const float* fc3_b   = (const float*)d_in[13] + l * 256;
    const float* g1_wl   = (const float*)d_in[14] + (size_t)l * 524288;
    const float* g1_bl   = (const float*)d_in[15] + l * 2048;
    const float* g1_wr   = (const float*)d_in[16] + (size_t)l * 524288;
    const float* g1_br   = (const float*)d_in[17] + l * 2048;
    const float* g1_att  = (const float*)d_in[18] + l * 2048;
    const float* g1_bias = (const float*)d_in[19] + l * 2048;
    const float* g2_wl   = (const float*)d_in[20] + (size_t)l * 524288;
    const float* g2_bl   = (const float*)d_in[21] + l * 256;
    const float* g2_wr   = (const float*)d_in[22] + (size_t)l * 524288;
    const float* g2_br   = (const float*)d_in[23] + l * 256;
    const float* g2_att  = (const float*)d_in[24] + l * 256;
    const float* g2_bias = (const float*)d_in[25] + l * 256;
    const float* g3_wl   = (const float*)d_in[26] + (size_t)l * 524288;
    const float* g3_bl   = (const float*)d_in[27] + l * 2048;
    const float* g3_wr   = (const float*)d_in[28] + (size_t)l * 524288;
    const float* g3_br   = (const float*)d_in[29] + l * 2048;
    const float* g3_att  = (const float*)d_in[30] + l * 2048;
    const float* g3_bias = (const float*)d_in[31] + l * 2048;
    const float* g4_wl   = (const float*)d_in[32] + (size_t)l * 524288;
    const float* g4_bl   = (const float*)d_in[33] + l * 256;
    const float* g4_wr   = (const float*)d_in[34] + (size_t)l * 524288;
    const float* g4_br   = (const float*)d_in[35] + l * 256;
    const float* g4_att  = (const float*)d_in[36] + l * 256;
    const float* g4_bias = (const float*)d_in[37] + l * 256;

    float* patches = ws + OFF_ARENA;   // also U
    float* xs    = ws + (l == 0 ? OFF_XS0 : OFF_XS1);
    float* emb   = ws + OFF_EMB;
    float* emb2  = ws + OFF_EMB2;
    float* score = ws + OFF_LAST;
    float* xlr   = ws + OFF_XL;        // [n][4096] fused xl|xr (g1/g3); also split-K partials
    float* h1    = ws + OFF_H1;
    float* xlr2  = ws + OFF_XL2;       // [n][512]  fused xl|xr (g2/g4)
    float* cat   = ws + OFF_CAT;
    float* hc    = ws + OFF_HC;
    float* bcat  = ws + OFF_HC;        // bias concat scratch (hc written only after GATs)
    float* ebuf  = ws + OFF_E;
    int* srcF = (int*)(ws + OFF_SRCF);
    int* srcS = (int*)(ws + OFF_SRCS);
    unsigned short* ba = (unsigned short*)(ws + OFF_BF_A);
    unsigned short* bw = (unsigned short*)(ws + OFF_BF_W);

    { int tot = n * 6400;
      extract_patches_k<<<dim3((tot + 255) / 256), dim3(256), 0, s>>>(f, patches, nw, H, tot); }

    // exact fp32 path feeding the top-k graph selection (split-K for occupancy)
    gemm32_sk<1, true>(s, patches, conv1_w, conv1_b, emb, xlr, n, 256, 6400, 16);
    gemm32<1, true>(s, emb, fc2_w, fc2_b, emb2, n, 256, 256);
    gemm32<0, false>(s, emb2, emb2, nullptr, score, n, n, 256);
    topk_feat_k<<<dim3(n), dim3(64), 0, s>>>(score, srcF, n);
    topk_spatial_k<<<dim3(n), dim3(64), 0, s>>>(srcS, n, nw);

    // g1: feature graph, emb2 -> h1 [n,2048], heads=8 (fused wl|wr, N=4096)
    cast_bf(s, emb2, ba, n * 256);
    cast_t(s, g1_wl, bw, 256, 2048);
    cast_t(s, g1_wr, bw + 2048 * 256, 256, 2048);
    hipMemcpyAsync(bcat, g1_bl, 2048 * sizeof(float), hipMemcpyDeviceToDevice, s);
    hipMemcpyAsync(bcat + 2048, g1_br, 2048 * sizeof(float), hipMemcpyDeviceToDevice, s);
    bgemm<BT_NT, 0, 1, false>(s, ba, bw, bcat, nullptr, 0, xlr, n, 4096, 256);
    { int tw = n * 8 * 8;
      gat_logits_k<<<dim3((tw + 3) / 4), dim3(256), 0, s>>>(xlr, xlr + 2048, 4096, g1_att, srcF, ebuf, n, 8);
      int aw = n * 8;
      gat_aggregate_k<<<dim3((aw + 3) / 4), dim3(256), 0, s>>>(xlr, 4096, ebuf, srcF, g1_bias, h1, n, 8, 2048, 0); }

    // g2: feature graph, h1 -> cat[:, :256], heads=1 (fused, N=512)
    cast_bf(s, h1, ba, n * 2048);
    cast_t(s, g2_wl, bw, 2048, 256);
    cast_t(s, g2_wr, bw + 256 * 2048, 2048, 256);
    hipMemcpyAsync(bcat, g2_bl, 256 * sizeof(float), hipMemcpyDeviceToDevice, s);
    hipMemcpyAsync(bcat + 256, g2_br, 256 * sizeof(float), hipMemcpyDeviceToDevice, s);
    bgemm<BT_NT, 0, 1, false>(s, ba, bw, bcat, nullptr, 0, xlr2, n, 512, 2048);
    { int tw = n * 8;
      gat_logits_k<<<dim3((tw + 3) / 4), dim3(256), 0, s>>>(xlr2, xlr2 + 256, 512, g2_att, srcF, ebuf, n, 1);
      int aw = n;
      gat_aggregate_k<<<dim3((aw + 3) / 4), dim3(256), 0, s>>>(xlr2, 512, ebuf, srcF, g2_bias, cat, n, 1, 512, 0); }

    // g3: spatial graph, emb2 -> h1 [n,2048], heads=8
    cast_bf(s, emb2, ba, n * 256);
    cast_t(s, g3_wl, bw, 256, 2048);
    cast_t(s, g3_wr, bw + 2048 * 256, 256, 2048);
    hipMemcpyAsync(bcat, g3_bl, 2048 * sizeof(float), hipMemcpyDeviceToDevice, s);
    hipMemcpyAsync(bcat + 2048, g3_br, 2048 * sizeof(float), hipMemcpyDeviceToDevice, s);
    bgemm<BT_NT, 0, 1, false>(s, ba, bw, bcat, nullptr, 0, xlr, n, 4096, 256);
    { int tw = n * 8 * 8;
      gat_logits_k<<<dim3((tw + 3) / 4), dim3(256), 0, s>>>(xlr, xlr + 2048, 4096, g3_att, srcS, ebuf, n, 8);
      int aw = n * 8;
      gat_aggregate_k<<<dim3((aw + 3) / 4), dim3(256), 0, s>>>(xlr, 4096, ebuf, srcS, g3_bias, h1, n, 8, 2048, 0); }

    // g4: spatial graph, h1 -> cat[:, 256:], heads=1
    cast_bf(s, h1, ba, n * 2048);
    cast_t(s, g4_wl, bw, 2048, 256);
    cast_t(s, g4_wr, bw + 256 * 2048, 2048, 256);
    hipMemcpyAsync(bcat, g4_bl, 256 * sizeof(float), hipMemcpyDeviceToDevice, s);
    hipMemcpyAsync(bcat + 256, g4_br, 256 * sizeof(float), hipMemcpyDeviceToDevice, s);
    bgemm<BT_NT, 0, 1, false>(s, ba, bw, bcat, nullptr, 0, xlr2, n, 512, 2048);
    { int tw = n * 8;
      gat_logits_k<<<dim3((tw + 3) / 4), dim3(256), 0, s>>>(xlr2, xlr2 + 256, 512, g4_att, srcS, ebuf, n, 1);
      int aw = n;
      gat_aggregate_k<<<dim3((aw + 3) / 4), dim3(256), 0, s>>>(xlr2, 512, ebuf, srcS, g4_bias, cat, n, 1, 512, 256); }

    // hc = relu(cat @ fc3_w^T + fc3_b) + h2
    cast_bf(s, cat, ba, n * 512);
    cast_bf(s, fc3_w, bw, 131072);
    bgemm<BT_NT, 1, 1, true>(s, ba, bw, fc3_b, cat + 256, 512, hc, n, 256, 512);
    // U = hc @ convT_w
    cast_bf(s, hc, ba, n * 256);
    cast_t(s, convT_w, bw, 256, 6400);
    bgemm<BT_NT, 0, 1, false>(s, ba, bw, nullptr, nullptr, 0, patches, n, 6400, 256);
    { int tot = 256 * HW;
      scatter_convT_k<<<dim3((tot + 255) / 256), dim3(256), 0, s>>>(f, patches, convT_b, xs, nw, H, tot); }
}

extern "C" void kernel_launch(void* const* d_in, const int* in_sizes, int n_in,
                              void* d_out, int out_size, void* d_ws, size_t ws_size,
                              hipStream_t stream)
{
    float* ws  = (float*)d_ws;
    float* out = (float*)d_out;

    run_level(d_in, ws, 0, 200, stream);
    run_level(d_in, ws, 1, 100, stream);

    const float* inner_w = (const float*)d_in[2];
    const float* inner_b = (const float*)d_in[3];
    const float* layer_w = (const float*)d_in[4];
    const float* layer_b = (const float*)d_in[5];
    float* xs0    = ws + OFF_XS0;
    float* xs1    = ws + OFF_XS1;
    float* last   = ws + OFF_LAST;
    float* inner0 = ws + OFF_ARENA;
    unsigned short* bimg = (unsigned short*)(ws + OFF_XL);               // [HW,256] bf16
    unsigned short* bw1  = (unsigned short*)(ws + OFF_BF_W);             // 1x1 weights
    unsigned short* bwc  = (unsigned short*)(ws + OFF_BF_W + 100000);    // conv3x3 reordered

    // ---- level 1: last = conv1x1(xs1); out1 = conv3x3(last) ----
    cast_t(stream, xs1, bimg, 256, 10000);                    // [10000,256] bf16
    cast_bf(stream, inner_w + 65536, bw1, 65536);
    bgemm<BT_NT, 0, 0, false>(stream, bw1, bimg, inner_b + 256, nullptr, 0,
                              last, 256, 10000, 256);
    reorder_w3_k<<<dim3((589824 + 255) / 256), dim3(256), 0, stream>>>(layer_w + 589824, bwc);
    cast_t(stream, last, bimg, 256, 10000);                   // NHWC image of last
    bgemm<BT_CONV2, 0, 0, false>(stream, bwc, bimg, layer_b + 256, nullptr, 0,
                                 out + 10240000, 256, 10000, 2304, 100, 100);

    // ---- level 0: inner0 = conv1x1(xs0) + nearest(last); out0 = conv3x3(inner0) ----
    cast_t(stream, xs0, bimg, 256, 40000);                    // [40000,256] bf16
    cast_bf(stream, inner_w, bw1, 65536);
    bgemm<BT_NT, 0, 0, false>(stream, bw1, bimg, inner_b, nullptr, 0,
                              inner0, 256, 40000, 256);
    { int tot = 256 * 40000;
      upsample_add_k<<<dim3((tot + 255) / 256), dim3(256), 0, stream>>>(inner0, last, 200, 100, tot); }
    reorder_w3_k<<<dim3((589824 + 255) / 256), dim3(256), 0, stream>>>(layer_w, bwc);
    cast_t(stream, inner0, bimg, 256, 40000);                 // NHWC image of inner0
    bgemm<BT_CONV2, 0, 0, false>(stream, bwc, bimg, layer_b, nullptr, 0,
                                 out, 256, 40000, 2304, 200, 200);
}

// Round 5
// 1444.542 us; speedup vs baseline: 3.0584x; 1.1150x over previous
//
#include <hip/hip_runtime.h>
#include <cstdint>
#include <cstddef>
#include <math.h>

#define KNN 7

using short8  = __attribute__((ext_vector_type(8))) short;
using floatx4 = __attribute__((ext_vector_type(4))) float;

// ---------------- workspace layout (in floats) ----------------
static const size_t OFF_ARENA = 0;          // 10,240,000  patches / U / inner0
static const size_t OFF_XS0   = 10240000;   // 10,240,000
static const size_t OFF_XS1   = 20480000;   //  2,560,000
static const size_t OFF_LAST  = 23040000;   //  2,560,000  score (GNN) / last (FPN)
static const size_t OFF_EMB   = 25600000;   //    409,600
static const size_t OFF_EMB2  = 26009600;   //    409,600
static const size_t OFF_XL    = 26419200;   //  6,553,600 XL+XR: xlr / split-K part / FPN bf16 img
static const size_t OFF_H1    = 32972800;   //  3,276,800
static const size_t OFF_XL2   = 36249600;   //    819,200 (xlr2 spans XL2+XR2)
static const size_t OFF_CAT   = 37068800;   //    819,200
static const size_t OFF_HC    = 37888000;   //    409,600 (also bcat scratch during GAT)
static const size_t OFF_E     = 38297600;   //    102,400
static const size_t OFF_SRCF  = 38400000;   //     11,200 ints
static const size_t OFF_SRCS  = 38411200;   //     11,200 ints
static const size_t OFF_BF_A  = 38422400;   //  1,700,000 floats = 3.4M bf16 (A casts)
static const size_t OFF_BF_W  = 40122400;   //    850,000 floats = 1.7M bf16 (W casts)
// total ~164 MB

static __device__ __forceinline__ unsigned short f2bf(float f) {
    union { float f; unsigned u; } v; v.f = f;
    unsigned u = v.u;
    unsigned r = u + 0x7fffu + ((u >> 16) & 1u);   // RNE
    return (unsigned short)(r >> 16);
}

// ============================ fp32 tiled GEMM (NT; exact path) ============
// Register-prefetch pipelined: loads for chunk k+1 issued before chunk k's FMAs.
template<int ACT, bool BIAS>
__global__ __launch_bounds__(256)
void gemm_k(const float* __restrict__ A, const float* __restrict__ B,
            const float* __restrict__ bias, float* __restrict__ C, int M, int N, int K)
{
    __shared__ float As[16][68];
    __shared__ float Bs[16][68];
    const int tid = threadIdx.x;
    const int bm0 = blockIdx.y * 64;
    const int bn0 = blockIdx.x * 64;
    const int tx = tid & 15, ty = tid >> 4;
    const int lrow = tid >> 2;
    const int lk4  = (tid & 3) << 2;
    const int m = bm0 + lrow;
    const int nn = bn0 + lrow;
    const bool aok = m < M, bok = nn < N;
    float acc[4][4] = {{0.f,0.f,0.f,0.f},{0.f,0.f,0.f,0.f},{0.f,0.f,0.f,0.f},{0.f,0.f,0.f,0.f}};

    float4 va = {0.f,0.f,0.f,0.f}, vb = {0.f,0.f,0.f,0.f};
    if (aok) va = *(const float4*)(A + (size_t)m * K + lk4);
    if (bok) vb = *(const float4*)(B + (size_t)nn * K + lk4);

    for (int k0 = 0; k0 < K; k0 += 16) {
        As[lk4+0][lrow]=va.x; As[lk4+1][lrow]=va.y; As[lk4+2][lrow]=va.z; As[lk4+3][lrow]=va.w;
        Bs[lk4+0][lrow]=vb.x; Bs[lk4+1][lrow]=vb.y; Bs[lk4+2][lrow]=vb.z; Bs[lk4+3][lrow]=vb.w;
        __syncthreads();
        float4 na = {0.f,0.f,0.f,0.f}, nb = {0.f,0.f,0.f,0.f};
        const bool more = (k0 + 16) < K;
        if (more) {
            if (aok) na = *(const float4*)(A + (size_t)m * K + (k0 + 16 + lk4));
            if (bok) nb = *(const float4*)(B + (size_t)nn * K + (k0 + 16 + lk4));
        }
        #pragma unroll
        for (int k = 0; k < 16; k++) {
            const float4 av = *(const float4*)&As[k][ty << 2];
            const float4 bv = *(const float4*)&Bs[k][tx << 2];
            const float a0=av.x,a1=av.y,a2=av.z,a3=av.w;
            const float b0=bv.x,b1=bv.y,b2=bv.z,b3=bv.w;
            acc[0][0]=fmaf(a0,b0,acc[0][0]); acc[0][1]=fmaf(a0,b1,acc[0][1]);
            acc[0][2]=fmaf(a0,b2,acc[0][2]); acc[0][3]=fmaf(a0,b3,acc[0][3]);
            acc[1][0]=fmaf(a1,b0,acc[1][0]); acc[1][1]=fmaf(a1,b1,acc[1][1]);
            acc[1][2]=fmaf(a1,b2,acc[1][2]); acc[1][3]=fmaf(a1,b3,acc[1][3]);
            acc[2][0]=fmaf(a2,b0,acc[2][0]); acc[2][1]=fmaf(a2,b1,acc[2][1]);
            acc[2][2]=fmaf(a2,b2,acc[2][2]); acc[2][3]=fmaf(a2,b3,acc[2][3]);
            acc[3][0]=fmaf(a3,b0,acc[3][0]); acc[3][1]=fmaf(a3,b1,acc[3][1]);
            acc[3][2]=fmaf(a3,b2,acc[3][2]); acc[3][3]=fmaf(a3,b3,acc[3][3]);
        }
        __syncthreads();
        va = na; vb = nb;
    }
    #pragma unroll
    for (int i = 0; i < 4; i++) {
        const int mm = bm0 + (ty << 2) + i;
        if (mm >= M) continue;
        #pragma unroll
        for (int jj = 0; jj < 4; jj++) {
            const int nc = bn0 + (tx << 2) + jj;
            if (nc >= N) continue;
            float v = acc[i][jj];
            if (BIAS) v += bias[nc];
            if (ACT == 1) v = fmaxf(v, 0.f);
            C[(size_t)mm * N + nc] = v;
        }
    }
}

template<int ACT, bool BIAS>
static inline void gemm32(hipStream_t s, const float* A, const float* B, const float* bias,
                          float* C, int M, int N, int K)
{
    dim3 g((N + 63) / 64, (M + 63) / 64);
    gemm_k<ACT, BIAS><<<g, dim3(256), 0, s>>>(A, B, bias, C, M, N, K);
}

// ---- split-K variant (pipelined) ----
__global__ __launch_bounds__(256)
void gemm32_sk_k(const float* __restrict__ A, const float* __restrict__ B,
                 float* __restrict__ part, int M, int N, int K, int Kc)
{
    __shared__ float As[16][68];
    __shared__ float Bs[16][68];
    const int tid = threadIdx.x;
    const int bm0 = blockIdx.y * 64;
    const int bn0 = blockIdx.x * 64;
    const int sblk = blockIdx.z;
    const int kbeg = sblk * Kc;
    const int kend = (kbeg + Kc < K) ? kbeg + Kc : K;
    const int tx = tid & 15, ty = tid >> 4;
    const int lrow = tid >> 2;
    const int lk4  = (tid & 3) << 2;
    const int m = bm0 + lrow;
    const int nn = bn0 + lrow;
    const bool aok = m < M, bok = nn < N;
    float acc[4][4] = {{0.f,0.f,0.f,0.f},{0.f,0.f,0.f,0.f},{0.f,0.f,0.f,0.f},{0.f,0.f,0.f,0.f}};

    float4 va = {0.f,0.f,0.f,0.f}, vb = {0.f,0.f,0.f,0.f};
    if (aok) va = *(const float4*)(A + (size_t)m * K + kbeg + lk4);
    if (bok) vb = *(const float4*)(B + (size_t)nn * K + kbeg + lk4);

    for (int k0 = kbeg; k0 < kend; k0 += 16) {
        As[lk4+0][lrow]=va.x; As[lk4+1][lrow]=va.y; As[lk4+2][lrow]=va.z; As[lk4+3][lrow]=va.w;
        Bs[lk4+0][lrow]=vb.x; Bs[lk4+1][lrow]=vb.y; Bs[lk4+2][lrow]=vb.z; Bs[lk4+3][lrow]=vb.w;
        __syncthreads();
        float4 na = {0.f,0.f,0.f,0.f}, nb = {0.f,0.f,0.f,0.f};
        const bool more = (k0 + 16) < kend;
        if (more) {
            if (aok) na = *(const float4*)(A + (size_t)m * K + (k0 + 16 + lk4));
            if (bok) nb = *(const float4*)(B + (size_t)nn * K + (k0 + 16 + lk4));
        }
        #pragma unroll
        for (int k = 0; k < 16; k++) {
            const float4 av = *(const float4*)&As[k][ty << 2];
            const float4 bv = *(const float4*)&Bs[k][tx << 2];
            const float a0=av.x,a1=av.y,a2=av.z,a3=av.w;
            const float b0=bv.x,b1=bv.y,b2=bv.z,b3=bv.w;
            acc[0][0]=fmaf(a0,b0,acc[0][0]); acc[0][1]=fmaf(a0,b1,acc[0][1]);
            acc[0][2]=fmaf(a0,b2,acc[0][2]); acc[0][3]=fmaf(a0,b3,acc[0][3]);
            acc[1][0]=fmaf(a1,b0,acc[1][0]); acc[1][1]=fmaf(a1,b1,acc[1][1]);
            acc[1][2]=fmaf(a1,b2,acc[1][2]); acc[1][3]=fmaf(a1,b3,acc[1][3]);
            acc[2][0]=fmaf(a2,b0,acc[2][0]); acc[2][1]=fmaf(a2,b1,acc[2][1]);
            acc[2][2]=fmaf(a2,b2,acc[2][2]); acc[2][3]=fmaf(a2,b3,acc[2][3]);
            acc[3][0]=fmaf(a3,b0,acc[3][0]); acc[3][1]=fmaf(a3,b1,acc[3][1]);
            acc[3][2]=fmaf(a3,b2,acc[3][2]); acc[3][3]=fmaf(a3,b3,acc[3][3]);
        }
        __syncthreads();
        va = na; vb = nb;
    }
    float* P = part + (size_t)sblk * M * N;
    #pragma unroll
    for (int i = 0; i < 4; i++) {
        const int mm = bm0 + (ty << 2) + i;
        if (mm >= M) continue;
        #pragma unroll
        for (int jj = 0; jj < 4; jj++) {
            const int nc = bn0 + (tx << 2) + jj;
            if (nc >= N) continue;
            P[(size_t)mm * N + nc] = acc[i][jj];
        }
    }
}

template<int ACT, bool BIAS>
__global__ void sk_reduce_k(const float* __restrict__ part, const float* __restrict__ bias,
                            float* __restrict__ C, int MN, int N, int S)
{
    const int i4 = (blockIdx.x * 256 + threadIdx.x) * 4;
    if (i4 >= MN) return;
    float4 a = *(const float4*)(part + i4);
    for (int s = 1; s < S; s++) {
        const float4 b = *(const float4*)(part + (size_t)s * MN + i4);
        a.x += b.x; a.y += b.y; a.z += b.z; a.w += b.w;
    }
    if (BIAS) {
        const int n = i4 % N;
        a.x += bias[n]; a.y += bias[n + 1]; a.z += bias[n + 2]; a.w += bias[n + 3];
    }
    if (ACT == 1) {
        a.x = fmaxf(a.x, 0.f); a.y = fmaxf(a.y, 0.f);
        a.z = fmaxf(a.z, 0.f); a.w = fmaxf(a.w, 0.f);
    }
    *(float4*)(C + i4) = a;
}

template<int ACT, bool BIAS>
static inline void gemm32_sk(hipStream_t s, const float* A, const float* B, const float* bias,
                             float* C, float* part, int M, int N, int K, int S)
{
    const int Kc = ((K / S + 15) / 16) * 16;
    dim3 g((N + 63) / 64, (M + 63) / 64, S);
    gemm32_sk_k<<<g, dim3(256), 0, s>>>(A, B, part, M, N, K, Kc);
    const int MN = M * N;
    sk_reduce_k<ACT, BIAS><<<dim3((MN / 4 + 255) / 256), dim3(256), 0, s>>>(part, bias, C, MN, N, S);
}

// ============================ bf16 MFMA GEMM (pipelined) ============================
// BT_NT: B is [N,K] row-major bf16.
// BT_CONV2: 3x3 SAME conv, NHWC: B = bf16 image [imH*imW, 256], A = weights [O][j*256+c].
enum { BT_NT = 0, BT_CONV2 = 2 };

template<int BT, int ACT, int BAX, bool ADDMAT>
__global__ __launch_bounds__(256)
void bgemm_k(const unsigned short* __restrict__ A, const unsigned short* __restrict__ B,
             const float* __restrict__ bias, const float* __restrict__ Dmat, int Dld,
             float* __restrict__ C, int M, int N, int K, int imH, int imW)
{
    __shared__ unsigned short Asl[128][40];
    __shared__ unsigned short Bsl[128][40];
    const int tid  = threadIdx.x;
    const int lane = tid & 63;
    const int wid  = tid >> 6;
    const int quad = lane >> 4;
    const int l15  = lane & 15;
    const int wy = wid >> 1, wx = wid & 1;
    const int bm0 = blockIdx.y * 128;
    const int bn0 = blockIdx.x * 128;

    floatx4 zero = {0.f, 0.f, 0.f, 0.f};
    floatx4 acc[4][4];
    #pragma unroll
    for (int i = 0; i < 4; i++)
        #pragma unroll
        for (int j = 0; j < 4; j++) acc[i][j] = zero;

    const int srow = tid >> 1;          // 0..127
    const int skc  = (tid & 1) << 4;    // 0 or 16

    const int mrow = bm0 + srow;
    const bool aok = mrow < M;
    const int nrow = bn0 + srow;
    const bool bok = nrow < N;

    // CONV2 geometry (per-thread, fixed)
    int cy = 0, cx = 0;
    bool cok = false;
    if (BT == BT_CONV2) {
        cok = nrow < N;
        const int pp = cok ? nrow : 0;
        cy = pp / imW; cx = pp - cy * imW;
    }

    uint4 va0 = {0,0,0,0}, va1 = {0,0,0,0}, vb0 = {0,0,0,0}, vb1 = {0,0,0,0};

    auto loadA = [&](int k0, uint4& r0, uint4& r1) {
        r0 = (uint4){0,0,0,0}; r1 = (uint4){0,0,0,0};
        if (aok) {
            const uint4* p = (const uint4*)(A + (size_t)mrow * K + k0 + skc);
            r0 = p[0]; r1 = p[1];
        }
    };
    auto loadB = [&](int k0, uint4& r0, uint4& r1) {
        r0 = (uint4){0,0,0,0}; r1 = (uint4){0,0,0,0};
        if (BT == BT_NT) {
            if (bok) {
                const uint4* p = (const uint4*)(B + (size_t)nrow * K + k0 + skc);
                r0 = p[0]; r1 = p[1];
            }
        } else {
            const int jj = k0 >> 8;                 // tap 0..8 (uniform per chunk)
            const int j3 = jj / 3;
            const int dy = j3 - 1, dx = jj - j3 * 3 - 1;
            const int c0 = k0 & 255;
            const int yy = cy + dy, xx = cx + dx;
            if (cok && (unsigned)yy < (unsigned)imH && (unsigned)xx < (unsigned)imW) {
                const uint4* p = (const uint4*)(B + ((size_t)yy * imW + xx) * 256 + c0 + skc);
                r0 = p[0]; r1 = p[1];
            }
        }
    };

    loadA(0, va0, va1);
    loadB(0, vb0, vb1);

    for (int k0 = 0; k0 < K; k0 += 32) {
        *(uint4*)&Asl[srow][skc]     = va0;
        *(uint4*)&Asl[srow][skc + 8] = va1;
        *(uint4*)&Bsl[srow][skc]     = vb0;
        *(uint4*)&Bsl[srow][skc + 8] = vb1;
        __syncthreads();
        uint4 na0, na1, nb0, nb1;
        const bool more = (k0 + 32) < K;
        if (more) { loadA(k0 + 32, na0, na1); loadB(k0 + 32, nb0, nb1); }
        short8 af[4], bfr[4];
        #pragma unroll
        for (int i = 0; i < 4; i++)
            af[i] = *(const short8*)&Asl[wy * 64 + i * 16 + l15][quad * 8];
        #pragma unroll
        for (int j = 0; j < 4; j++)
            bfr[j] = *(const short8*)&Bsl[wx * 64 + j * 16 + l15][quad * 8];
        #pragma unroll
        for (int i = 0; i < 4; i++)
            #pragma unroll
            for (int j = 0; j < 4; j++)
                acc[i][j] = __builtin_amdgcn_mfma_f32_16x16x32_bf16(af[i], bfr[j], acc[i][j], 0, 0, 0);
        __syncthreads();
        if (more) { va0 = na0; va1 = na1; vb0 = nb0; vb1 = nb1; }
    }

    #pragma unroll
    for (int i = 0; i < 4; i++) {
        #pragma unroll
        for (int r = 0; r < 4; r++) {
            const int m = bm0 + wy * 64 + i * 16 + quad * 4 + r;
            if (m >= M) continue;
            #pragma unroll
            for (int j = 0; j < 4; j++) {
                const int n = bn0 + wx * 64 + j * 16 + l15;
                if (n >= N) continue;
                float v = acc[i][j][r];
                if (bias != nullptr) v += (BAX == 0) ? bias[m] : bias[n];
                if (ACT == 1) v = fmaxf(v, 0.f);
                if (ADDMAT) v += Dmat[(size_t)m * Dld + n];
                C[(size_t)m * N + n] = v;
            }
        }
    }
}

template<int BT, int ACT, int BAX, bool ADDMAT>
static inline void bgemm(hipStream_t s, const unsigned short* A, const unsigned short* B,
                         const float* bias, const float* D, int Dld, float* C,
                         int M, int N, int K, int imH = 0, int imW = 0)
{
    dim3 g((N + 127) / 128, (M + 127) / 128);
    bgemm_k<BT, ACT, BAX, ADDMAT><<<g, dim3(256), 0, s>>>(A, B, bias, D, Dld, C, M, N, K, imH, imW);
}

// ============================ cast / reorder kernels ============================
__global__ void cast_bf16_k(const float* __restrict__ in, unsigned short* __restrict__ out, int total)
{
    const int i4 = (blockIdx.x * 256 + threadIdx.x) * 4;
    if (i4 + 4 <= total) {
        const float4 v = *(const float4*)(in + i4);
        ushort4 o;
        o.x = f2bf(v.x); o.y = f2bf(v.y); o.z = f2bf(v.z); o.w = f2bf(v.w);
        *(ushort4*)(out + i4) = o;
    } else {
        for (int i = i4; i < total; i++) out[i] = f2bf(in[i]);
    }
}

static inline void cast_bf(hipStream_t s, const float* in, unsigned short* out, int total)
{
    cast_bf16_k<<<dim3((total / 4 + 255) / 256), dim3(256), 0, s>>>(in, out, total);
}

// transposing cast: fp32 [K,N] -> bf16 [N,K]; dual-source variant via z-grid
__device__ __forceinline__ void cast_t_body(const float* __restrict__ in,
                                            unsigned short* __restrict__ out, int K, int N)
{
    __shared__ float tile[64][65];
    const int n0 = blockIdx.x * 64;
    const int k0 = blockIdx.y * 64;
    const int t = threadIdx.x;
    const int r = t >> 2;
    const int c4 = (t & 3) << 4;
    {
        const int k = k0 + r;
        if (k < K && n0 + c4 + 16 <= N) {
            const float4* p = (const float4*)(in + (size_t)k * N + n0 + c4);
            *(float4*)&tile[r][c4]      = p[0];
            *(float4*)&tile[r][c4 + 4]  = p[1];
            *(float4*)&tile[r][c4 + 8]  = p[2];
            *(float4*)&tile[r][c4 + 12] = p[3];
        } else {
            for (int i = 0; i < 16; i++)
                tile[r][c4 + i] = (k < K && n0 + c4 + i < N) ? in[(size_t)k * N + n0 + c4 + i] : 0.f;
        }
    }
    __syncthreads();
    const int n = n0 + r;
    if (n >= N) return;
    unsigned short tmp[16];
    #pragma unroll
    for (int i = 0; i < 16; i++) tmp[i] = f2bf(tile[c4 + i][r]);
    if (k0 + 64 <= K) {
        *(uint4*)(out + (size_t)n * K + k0 + c4)     = *(uint4*)&tmp[0];
        *(uint4*)(out + (size_t)n * K + k0 + c4 + 8) = *(uint4*)&tmp[8];
    } else {
        for (int i = 0; i < 16; i++)
            if (k0 + c4 + i < K) out[(size_t)n * K + k0 + c4 + i] = tmp[i];
    }
}

__global__ void cast_t_k(const float* __restrict__ in, unsigned short* __restrict__ out, int K, int N)
{
    cast_t_body(in, out, K, N);
}

__global__ void cast_t2_k(const float* __restrict__ in0, const float* __restrict__ in1,
                          unsigned short* __restrict__ out0, unsigned short* __restrict__ out1,
                          int K, int N)
{
    if (blockIdx.z == 0) cast_t_body(in0, out0, K, N);
    else                 cast_t_body(in1, out1, K, N);
}

static inline void cast_t(hipStream_t s, const float* in, unsigned short* out, int K, int N)
{
    cast_t_k<<<dim3((N + 63) / 64, (K + 63) / 64), dim3(256), 0, s>>>(in, out, K, N);
}

static inline void cast_t2(hipStream_t s, const float* in0, const float* in1,
                           unsigned short* out0, unsigned short* out1, int K, int N)
{
    cast_t2_k<<<dim3((N + 63) / 64, (K + 63) / 64, 2), dim3(256), 0, s>>>(in0, in1, out0, out1, K, N);
}

// conv3x3 weight reorder: fp32 [O][C][3][3] -> bf16 [O][j*256+c]
__global__ void reorder_w3_k(const float* __restrict__ in, unsigned short* __restrict__ out)
{
    const int idx = blockIdx.x * 256 + threadIdx.x;
    if (idx >= 589824) return;
    const int o = idx / 2304;
    const int r = idx - o * 2304;
    const int j = r >> 8;
    const int c = r & 255;
    out[idx] = f2bf(in[(size_t)o * 2304 + c * 9 + j]);
}

// ============================ small kernels ============================
__global__ void extract_patches_k(const float* __restrict__ f, float* __restrict__ patches,
                                  int nw, int H, int total)
{
    int idx = blockIdx.x * 256 + threadIdx.x;
    if (idx >= total) return;
    int q = idx % 6400;
    int p = idx / 6400;
    int c = q / 25;
    int rem = q - c * 25;
    int a = rem / 5, b = rem - (rem / 5) * 5;
    int ih = p / nw, iw = p - (p / nw) * nw;
    patches[idx] = f[(size_t)c * H * H + (size_t)(ih * 5 + a) * H + (iw * 5 + b)];
}

__global__ void topk_feat_k(const float* __restrict__ score, int* __restrict__ srcCols, int n)
{
    const int r = blockIdx.x;
    const int lane = threadIdx.x;
    const float* row = score + (size_t)r * n;
    int   sel[KNN];
    float selv[KNN];
    #pragma unroll
    for (int t = 0; t < KNN; t++) {
        float best = -__builtin_huge_valf();
        int   bidx = 0x7fffffff;
        for (int c = lane; c < n; c += 64) {
            bool taken = false;
            #pragma unroll
            for (int u = 0; u < KNN; u++)
                if (u < t && sel[u] == c) taken = true;
            if (taken) continue;
            float v = row[c];
            if (v > best || (v == best && c < bidx)) { best = v; bidx = c; }
        }
        #pragma unroll
        for (int off = 32; off > 0; off >>= 1) {
            float ov = __shfl_down(best, off);
            int   oi = __shfl_down(bidx, off);
            if (ov > best || (ov == best && oi < bidx)) { best = ov; bidx = oi; }
        }
        best = __shfl(best, 0);
        bidx = __shfl(bidx, 0);
        sel[t] = bidx; selv[t] = best;
    }
    if (lane < KNN) {
        int c = -1; float v = 0.f;
        #pragma unroll
        for (int t = 0; t < KNN; t++)
            if (lane == t) { c = sel[t]; v = selv[t]; }
        srcCols[r * KNN + lane] = (c > r && v != 0.0f) ? c : -1;
    }
}

__global__ void topk_spatial_k(int* __restrict__ srcCols, int n, int nw)
{
    const int r = blockIdx.x;
    const int lane = threadIdx.x;
    const int ri = r / nw, rj = r - (r / nw) * nw;
    int sel[KNN];
    #pragma unroll
    for (int t = 0; t < KNN; t++) {
        int bkey = 0x7fffffff;
        for (int c = lane; c < n; c += 64) {
            bool taken = false;
            #pragma unroll
            for (int u = 0; u < KNN; u++)
                if (u < t && sel[u] == c) taken = true;
            if (taken) continue;
            const int ci = c / nw, cj = c - (c / nw) * nw;
            const int dy = (ri - ci) * 5, dx = (rj - cj) * 5;
            const int d2 = dy * dy + dx * dx;
            const int key = (d2 << 11) | c;
            if (key < bkey) bkey = key;
        }
        #pragma unroll
        for (int off = 32; off > 0; off >>= 1) {
            int ok = __shfl_down(bkey, off);
            if (ok < bkey) bkey = ok;
        }
        bkey = __shfl(bkey, 0);
        sel[t] = bkey & 2047;
    }
    if (lane < KNN) {
        int c = -1;
        #pragma unroll
        for (int t = 0; t < KNN; t++) if (lane == t) c = sel[t];
        srcCols[r * KNN + lane] = (c > r) ? c : -1;
    }
}

__global__ void gat_logits_k(const float* __restrict__ xl, const float* __restrict__ xr,
                             int xstride, const float* __restrict__ att,
                             const int* __restrict__ srcCols,
                             float* __restrict__ e, int n, int H)
{
    const int wid = (blockIdx.x * blockDim.x + threadIdx.x) >> 6;
    const int lane = threadIdx.x & 63;
    if (wid >= n * 8 * H) return;
    const int h = wid % H;
    const int es = wid / H;
    const int r = es >> 3, s = es & 7;
    int src;
    if (s == 7) src = r;
    else { src = srcCols[r * KNN + s]; if (src < 0) return; }
    const float* pl = xl + (size_t)src * xstride + h * 256;
    const float* pr = xr + (size_t)r * xstride + h * 256;
    const float* pa = att + (size_t)h * 256;
    float sum = 0.f;
    #pragma unroll
    for (int it = 0; it < 4; it++) {
        const int d = lane + it * 64;
        float m = pl[d] + pr[d];
        m = (m > 0.f) ? m : 0.2f * m;
        sum += m * pa[d];
    }
    #pragma unroll
    for (int off = 32; off > 0; off >>= 1) sum += __shfl_down(sum, off);
    if (lane == 0) e[(size_t)es * H + h] = sum;
}

__global__ void gat_aggregate_k(const float* __restrict__ xl, int xstride,
                                const float* __restrict__ e,
                                const int* __restrict__ srcCols, const float* __restrict__ bias,
                                float* __restrict__ out, int n, int H, int ostride, int ooff)
{
    const int wid = (blockIdx.x * blockDim.x + threadIdx.x) >> 6;
    const int lane = threadIdx.x & 63;
    if (wid >= n * H) return;
    const int h = wid % H;
    const int r = wid / H;
    const float eself = e[(size_t)(r * 8 + 7) * H + h];
    float mx = eself;
    #pragma unroll
    for (int ss = 0; ss < KNN; ss++) {
        const int c = srcCols[r * KNN + ss];
        if (c >= 0) mx = fmaxf(mx, e[(size_t)(r * 8 + ss) * H + h]);
    }
    float denom = expf(eself - mx);
    #pragma unroll
    for (int ss = 0; ss < KNN; ss++) {
        const int c = srcCols[r * KNN + ss];
        if (c >= 0) denom += expf(e[(size_t)(r * 8 + ss) * H + h] - mx);
    }
    const float inv = 1.f / (denom + 1e-16f);
    const int d0 = lane << 2;
    float o0, o1, o2, o3;
    {
        const float a = expf(eself - mx) * inv;
        const float4 v = *(const float4*)(xl + (size_t)r * xstride + h * 256 + d0);
        o0 = a * v.x; o1 = a * v.y; o2 = a * v.z; o3 = a * v.w;
    }
    #pragma unroll
    for (int ss = 0; ss < KNN; ss++) {
        const int c = srcCols[r * KNN + ss];
        if (c < 0) continue;
        const float a = expf(e[(size_t)(r * 8 + ss) * H + h] - mx) * inv;
        const float4 v = *(const float4*)(xl + (size_t)c * xstride + h * 256 + d0);
        o0 = fmaf(a, v.x, o0); o1 = fmaf(a, v.y, o1);
        o2 = fmaf(a, v.z, o2); o3 = fmaf(a, v.w, o3);
    }
    const float* bb = bias + (size_t)h * 256 + d0;
    o0 += bb[0]; o1 += bb[1]; o2 += bb[2]; o3 += bb[3];
    o0 = (o0 > 0.f) ? o0 : (expf(o0) - 1.f);
    o1 = (o1 > 0.f) ? o1 : (expf(o1) - 1.f);
    o2 = (o2 > 0.f) ? o2 : (expf(o2) - 1.f);
    o3 = (o3 > 0.f) ? o3 : (expf(o3) - 1.f);
    float4 res = {o0, o1, o2, o3};
    *(float4*)(out + (size_t)r * ostride + ooff + (size_t)h * 256 + d0) = res;
}

__global__ void scatter_convT_k(const float* __restrict__ f, const float* __restrict__ U,
                                const float* __restrict__ bias, float* __restrict__ xs,
                                int nw, int H, int total)
{
    int idx = blockIdx.x * 256 + threadIdx.x;
    if (idx >= total) return;
    int x = idx % H;
    int t = idx / H;
    int y = t % H;
    int o = t / H;
    int j = y / 5, a = y - j * 5;
    int i = x / 5, b = x - i * 5;
    int p = i * nw + j;
    float v = U[(size_t)p * 6400 + o * 25 + a * 5 + b] + bias[o];
    v = fmaxf(v, 0.f);
    xs[idx] = f[idx] + v;
}

__global__ void upsample_add_k(float* __restrict__ acc, const float* __restrict__ last,
                               int H, int Hs, int total)
{
    int idx = blockIdx.x * 256 + threadIdx.x;
    if (idx >= total) return;
    int x = idx % H;
    int t = idx / H;
    int y = t % H;
    int c = t / H;
    acc[idx] += last[(size_t)c * Hs * Hs + (size_t)(y >> 1) * Hs + (x >> 1)];
}

// ============================ orchestration ============================
static void run_level(void* const* d_in, float* ws, int l, int H, hipStream_t s)
{
    const float* f = (const float*)d_in[l];
    const int nh = H / 5, nw = nh, n = nh * nw, HW = H * H;

    const float* convT_w = (const float*)d_in[6]  + (size_t)l * 1638400;
    const float* convT_b = (const float*)d_in[7]  + l * 256;
    const float* conv1_w = (const float*)d_in[8]  + (size_t)l * 1638400;
    const float* conv1_b = (const float*)d_in[9]  + l * 256;
    const float* fc2_w   = (const float*)d_in[10] + (size_t)l * 65536;
    const float* fc2_b   = (const float*)d_in[11] + l * 256;
    const float* fc3_w   = (const float*)d_in[12] + (size_t)l * 131072;
    const float* fc3_b   = (const float*)d_in[13] + l * 256;
    const float* g1_wl   = (const float*)d_in[14] + (size_t)l * 524288;
    const float* g1_bl   = (const float*)d_in[15] + l * 2048;
    const float* g1_wr   = (const float*)d_in[16] + (size_t)l * 524288;
    const float* g1_br   = (const float*)d_in[17] + l * 2048;
    const float* g1_att  = (const float*)d_in[18] + l * 2048;
    const float* g1_bias = (const float*)d_in[19] + l * 2048;
    const float* g2_wl   = (const float*)d_in[20] + (size_t)l * 524288;
    const float* g2_bl   = (const float*)d_in[21] + l * 256;
    const float* g2_wr   = (const float*)d_in[22] + (size_t)l * 524288;
    const float* g2_br   = (const float*)d_in[23] + l * 256;
    const float* g2_att  = (const float*)d_in[24] + l * 256;
    const float* g2_bias = (const float*)d_in[25] + l * 256;
    const float* g3_wl   = (const float*)d_in[26] + (size_t)l * 524288;
    const float* g3_bl   = (const float*)d_in[27] + l * 2048;
    const float* g3_wr   = (const float*)d_in[28] + (size_t)l * 524288;
    const float* g3_br   = (const float*)d_in[29] + l * 2048;
    const float* g3_att  = (const float*)d_in[30] + l * 2048;
    const float* g3_bias = (const float*)d_in[31] + l * 2048;
    const float* g4_wl   = (const float*)d_in[32] + (size_t)l * 524288;
    const float* g4_bl   = (const float*)d_in[33] + l * 256;
    const float* g4_wr   = (const float*)d_in[34] + (size_t)l * 524288;
    const float* g4_br   = (const float*)d_in[35] + l * 256;
    const float* g4_att  = (const float*)d_in[36] + l * 256;
    const float* g4_bias = (const float*)d_in[37] + l * 256;

    float* patches = ws + OFF_ARENA;   // also U
    float* xs    = ws + (l == 0 ? OFF_XS0 : OFF_XS1);
    float* emb   = ws + OFF_EMB;
    float* emb2  = ws + OFF_EMB2;
    float* score = ws + OFF_LAST;
    float* xlr   = ws + OFF_XL;        // [n][4096] fused xl|xr (g1/g3); also split-K partials
    float* h1    = ws + OFF_H1;
    float* xlr2  = ws + OFF_XL2;       // [n][512]  fused xl|xr (g2/g4)
    float* cat   = ws + OFF_CAT;
    float* hc    = ws + OFF_HC;
    float* bcat  = ws + OFF_HC;        // bias concat scratch (hc written only after GATs)
    float* ebuf  = ws + OFF_E;
    int* srcF = (int*)(ws + OFF_SRCF);
    int* srcS = (int*)(ws + OFF_SRCS);
    unsigned short* ba = (unsigned short*)(ws + OFF_BF_A);
    unsigned short* bw = (unsigned short*)(ws + OFF_BF_W);

    { int tot = n * 6400;
      extract_patches_k<<<dim3((tot + 255) / 256), dim3(256), 0, s>>>(f, patches, nw, H, tot); }

    // exact fp32 path feeding the top-k graph selection (split-K for occupancy)
    gemm32_sk<1, true>(s, patches, conv1_w, conv1_b, emb, xlr, n, 256, 6400, 16);
    gemm32<1, true>(s, emb, fc2_w, fc2_b, emb2, n, 256, 256);
    gemm32<0, false>(s, emb2, emb2, nullptr, score, n, n, 256);
    topk_feat_k<<<dim3(n), dim3(64), 0, s>>>(score, srcF, n);
    topk_spatial_k<<<dim3(n), dim3(64), 0, s>>>(srcS, n, nw);

    // g1: feature graph, emb2 -> h1 [n,2048], heads=8 (fused wl|wr, N=4096)
    cast_bf(s, emb2, ba, n * 256);
    cast_t2(s, g1_wl, g1_wr, bw, bw + 2048 * 256, 256, 2048);
    hipMemcpyAsync(bcat, g1_bl, 2048 * sizeof(float), hipMemcpyDeviceToDevice, s);
    hipMemcpyAsync(bcat + 2048, g1_br, 2048 * sizeof(float), hipMemcpyDeviceToDevice, s);
    bgemm<BT_NT, 0, 1, false>(s, ba, bw, bcat, nullptr, 0, xlr, n, 4096, 256);
    { int tw = n * 8 * 8;
      gat_logits_k<<<dim3((tw + 3) / 4), dim3(256), 0, s>>>(xlr, xlr + 2048, 4096, g1_att, srcF, ebuf, n, 8);
      int aw = n * 8;
      gat_aggregate_k<<<dim3((aw + 3) / 4), dim3(256), 0, s>>>(xlr, 4096, ebuf, srcF, g1_bias, h1, n, 8, 2048, 0); }

    // g2: feature graph, h1 -> cat[:, :256], heads=1 (fused, N=512)
    cast_bf(s, h1, ba, n * 2048);
    cast_t2(s, g2_wl, g2_wr, bw, bw + 256 * 2048, 2048, 256);
    hipMemcpyAsync(bcat, g2_bl, 256 * sizeof(float), hipMemcpyDeviceToDevice, s);
    hipMemcpyAsync(bcat + 256, g2_br, 256 * sizeof(float), hipMemcpyDeviceToDevice, s);
    bgemm<BT_NT, 0, 1, false>(s, ba, bw, bcat, nullptr, 0, xlr2, n, 512, 2048);
    { int tw = n * 8;
      gat_logits_k<<<dim3((tw + 3) / 4), dim3(256), 0, s>>>(xlr2, xlr2 + 256, 512, g2_att, srcF, ebuf, n, 1);
      int aw = n;
      gat_aggregate_k<<<dim3((aw + 3) / 4), dim3(256), 0, s>>>(xlr2, 512, ebuf, srcF, g2_bias, cat, n, 1, 512, 0); }

    // g3: spatial graph, emb2 -> h1 [n,2048], heads=8
    cast_bf(s, emb2, ba, n * 256);
    cast_t2(s, g3_wl, g3_wr, bw, bw + 2048 * 256, 256, 2048);
    hipMemcpyAsync(bcat, g3_bl, 2048 * sizeof(float), hipMemcpyDeviceToDevice, s);
    hipMemcpyAsync(bcat + 2048, g3_br, 2048 * sizeof(float), hipMemcpyDeviceToDevice, s);
    bgemm<BT_NT, 0, 1, false>(s, ba, bw, bcat, nullptr, 0, xlr, n, 4096, 256);
    { int tw = n * 8 * 8;
      gat_logits_k<<<dim3((tw + 3) / 4), dim3(256), 0, s>>>(xlr, xlr + 2048, 4096, g3_att, srcS, ebuf, n, 8);
      int aw = n * 8;
      gat_aggregate_k<<<dim3((aw + 3) / 4), dim3(256), 0, s>>>(xlr, 4096, ebuf, srcS, g3_bias, h1, n, 8, 2048, 0); }

    // g4: spatial graph, h1 -> cat[:, 256:], heads=1
    cast_bf(s, h1, ba, n * 2048);
    cast_t2(s, g4_wl, g4_wr, bw, bw + 256 * 2048, 2048, 256);
    hipMemcpyAsync(bcat, g4_bl, 256 * sizeof(float), hipMemcpyDeviceToDevice, s);
    hipMemcpyAsync(bcat + 256, g4_br, 256 * sizeof(float), hipMemcpyDeviceToDevice, s);
    bgemm<BT_NT, 0, 1, false>(s, ba, bw, bcat, nullptr, 0, xlr2, n, 512, 2048);
    { int tw = n * 8;
      gat_logits_k<<<dim3((tw + 3) / 4), dim3(256), 0, s>>>(xlr2, xlr2 + 256, 512, g4_att, srcS, ebuf, n, 1);
      int aw = n;
      gat_aggregate_k<<<dim3((aw + 3) / 4), dim3(256), 0, s>>>(xlr2, 512, ebuf, srcS, g4_bias, cat, n, 1, 512, 256); }

    // hc = relu(cat @ fc3_w^T + fc3_b) + h2
    cast_bf(s, cat, ba, n * 512);
    cast_bf(s, fc3_w, bw, 131072);
    bgemm<BT_NT, 1, 1, true>(s, ba, bw, fc3_b, cat + 256, 512, hc, n, 256, 512);
    // U = hc @ convT_w
    cast_bf(s, hc, ba, n * 256);
    cast_t(s, convT_w, bw, 256, 6400);
    bgemm<BT_NT, 0, 1, false>(s, ba, bw, nullptr, nullptr, 0, patches, n, 6400, 256);
    { int tot = 256 * HW;
      scatter_convT_k<<<dim3((tot + 255) / 256), dim3(256), 0, s>>>(f, patches, convT_b, xs, nw, H, tot); }
}

extern "C" void kernel_launch(void* const* d_in, const int* in_sizes, int n_in,
                              void* d_out, int out_size, void* d_ws, size_t ws_size,
                              hipStream_t stream)
{
    float* ws  = (float*)d_ws;
    float* out = (float*)d_out;

    run_level(d_in, ws, 0, 200, stream);
    run_level(d_in, ws, 1, 100, stream);

    const float* inner_w = (const float*)d_in[2];
    const float* inner_b = (const float*)d_in[3];
    const float* layer_w = (const float*)d_in[4];
    const float* layer_b = (const float*)d_in[5];
    float* xs0    = ws + OFF_XS0;
    float* xs1    = ws + OFF_XS1;
    float* last   = ws + OFF_LAST;
    float* inner0 = ws + OFF_ARENA;
    unsigned short* bimg = (unsigned short*)(ws + OFF_XL);               // [HW,256] bf16
    unsigned short* bw1  = (unsigned short*)(ws + OFF_BF_W);             // 1x1 weights
    unsigned short* bwc  = (unsigned short*)(ws + OFF_BF_W + 100000);    // conv3x3 reordered

    // ---- level 1: last = conv1x1(xs1); out1 = conv3x3(last) ----
    cast_t(stream, xs1, bimg, 256, 10000);                    // [10000,256] bf16
    cast_bf(stream, inner_w + 65536, bw1, 65536);
    bgemm<BT_NT, 0, 0, false>(stream, bw1, bimg, inner_b + 256, nullptr, 0,
                              last, 256, 10000, 256);
    reorder_w3_k<<<dim3((589824 + 255) / 256), dim3(256), 0, stream>>>(layer_w + 589824, bwc);
    cast_t(stream, last, bimg, 256, 10000);                   // NHWC image of last
    bgemm<BT_CONV2, 0, 0, false>(stream, bwc, bimg, layer_b + 256, nullptr, 0,
                                 out + 10240000, 256, 10000, 2304, 100, 100);

    // ---- level 0: inner0 = conv1x1(xs0) + nearest(last); out0 = conv3x3(inner0) ----
    cast_t(stream, xs0, bimg, 256, 40000);                    // [40000,256] bf16
    cast_bf(stream, inner_w, bw1, 65536);
    bgemm<BT_NT, 0, 0, false>(stream, bw1, bimg, inner_b, nullptr, 0,
                              inner0, 256, 40000, 256);
    { int tot = 256 * 40000;
      upsample_add_k<<<dim3((tot + 255) / 256), dim3(256), 0, stream>>>(inner0, last, 200, 100, tot); }
    reorder_w3_k<<<dim3((589824 + 255) / 256), dim3(256), 0, stream>>>(layer_w, bwc);
    cast_t(stream, inner0, bimg, 256, 40000);                 // NHWC image of inner0
    bgemm<BT_CONV2, 0, 0, false>(stream, bwc, bimg, layer_b, nullptr, 0,
                                 out, 256, 40000, 2304, 200, 200);
}

// Round 6
// 1262.245 us; speedup vs baseline: 3.5001x; 1.1444x over previous
//
#include <hip/hip_runtime.h>
#include <cstdint>
#include <cstddef>
#include <math.h>

#define KNN 7

using short8  = __attribute__((ext_vector_type(8))) short;
using floatx4 = __attribute__((ext_vector_type(4))) float;

// ---------------- workspace layout (in floats) ----------------
static const size_t OFF_ARENA = 0;          // 10,240,000  patches / split-K partials / U / inner0
static const size_t OFF_XS0   = 10240000;   // 10,240,000
static const size_t OFF_XS1   = 20480000;   //  2,560,000
static const size_t OFF_LAST  = 23040000;   //  2,560,000  score (GNN) / last (FPN)
static const size_t OFF_EMB   = 25600000;   //    409,600
static const size_t OFF_EMB2  = 26009600;   //    409,600
static const size_t OFF_XL    = 26419200;   //  6,553,600 xlr / fp32-splitK part / FPN bf16 img
static const size_t OFF_H1    = 32972800;   //  3,276,800
static const size_t OFF_XL2   = 36249600;   //    819,200 (xlr2)
static const size_t OFF_CAT   = 37068800;   //    819,200
static const size_t OFF_HC    = 37888000;   //    409,600
static const size_t OFF_SRCF  = 38400000;   //     11,200 ints
static const size_t OFF_SRCS  = 38411200;   //     11,200 ints
static const size_t OFF_BF_A  = 38422400;   //  1,700,000 floats = 3.4M bf16 (A casts)
static const size_t OFF_BF_W  = 40122400;   //    850,000 floats = 1.7M bf16 (W casts)
// total ~164 MB

static __device__ __forceinline__ unsigned short f2bf(float f) {
    union { float f; unsigned u; } v; v.f = f;
    unsigned u = v.u;
    unsigned r = u + 0x7fffu + ((u >> 16) & 1u);   // RNE
    return (unsigned short)(r >> 16);
}

// ============================ fp32 tiled GEMM (NT; exact path) ============
template<int ACT, bool BIAS>
__global__ __launch_bounds__(256)
void gemm_k(const float* __restrict__ A, const float* __restrict__ B,
            const float* __restrict__ bias, float* __restrict__ C, int M, int N, int K)
{
    __shared__ float As[16][68];
    __shared__ float Bs[16][68];
    const int tid = threadIdx.x;
    const int bm0 = blockIdx.y * 64;
    const int bn0 = blockIdx.x * 64;
    const int tx = tid & 15, ty = tid >> 4;
    const int lrow = tid >> 2;
    const int lk4  = (tid & 3) << 2;
    const int m = bm0 + lrow;
    const int nn = bn0 + lrow;
    const bool aok = m < M, bok = nn < N;
    float acc[4][4] = {{0.f,0.f,0.f,0.f},{0.f,0.f,0.f,0.f},{0.f,0.f,0.f,0.f},{0.f,0.f,0.f,0.f}};

    float4 va = {0.f,0.f,0.f,0.f}, vb = {0.f,0.f,0.f,0.f};
    if (aok) va = *(const float4*)(A + (size_t)m * K + lk4);
    if (bok) vb = *(const float4*)(B + (size_t)nn * K + lk4);

    for (int k0 = 0; k0 < K; k0 += 16) {
        As[lk4+0][lrow]=va.x; As[lk4+1][lrow]=va.y; As[lk4+2][lrow]=va.z; As[lk4+3][lrow]=va.w;
        Bs[lk4+0][lrow]=vb.x; Bs[lk4+1][lrow]=vb.y; Bs[lk4+2][lrow]=vb.z; Bs[lk4+3][lrow]=vb.w;
        __syncthreads();
        float4 na = {0.f,0.f,0.f,0.f}, nb = {0.f,0.f,0.f,0.f};
        const bool more = (k0 + 16) < K;
        if (more) {
            if (aok) na = *(const float4*)(A + (size_t)m * K + (k0 + 16 + lk4));
            if (bok) nb = *(const float4*)(B + (size_t)nn * K + (k0 + 16 + lk4));
        }
        #pragma unroll
        for (int k = 0; k < 16; k++) {
            const float4 av = *(const float4*)&As[k][ty << 2];
            const float4 bv = *(const float4*)&Bs[k][tx << 2];
            const float a0=av.x,a1=av.y,a2=av.z,a3=av.w;
            const float b0=bv.x,b1=bv.y,b2=bv.z,b3=bv.w;
            acc[0][0]=fmaf(a0,b0,acc[0][0]); acc[0][1]=fmaf(a0,b1,acc[0][1]);
            acc[0][2]=fmaf(a0,b2,acc[0][2]); acc[0][3]=fmaf(a0,b3,acc[0][3]);
            acc[1][0]=fmaf(a1,b0,acc[1][0]); acc[1][1]=fmaf(a1,b1,acc[1][1]);
            acc[1][2]=fmaf(a1,b2,acc[1][2]); acc[1][3]=fmaf(a1,b3,acc[1][3]);
            acc[2][0]=fmaf(a2,b0,acc[2][0]); acc[2][1]=fmaf(a2,b1,acc[2][1]);
            acc[2][2]=fmaf(a2,b2,acc[2][2]); acc[2][3]=fmaf(a2,b3,acc[2][3]);
            acc[3][0]=fmaf(a3,b0,acc[3][0]); acc[3][1]=fmaf(a3,b1,acc[3][1]);
            acc[3][2]=fmaf(a3,b2,acc[3][2]); acc[3][3]=fmaf(a3,b3,acc[3][3]);
        }
        __syncthreads();
        va = na; vb = nb;
    }
    #pragma unroll
    for (int i = 0; i < 4; i++) {
        const int mm = bm0 + (ty << 2) + i;
        if (mm >= M) continue;
        #pragma unroll
        for (int jj = 0; jj < 4; jj++) {
            const int nc = bn0 + (tx << 2) + jj;
            if (nc >= N) continue;
            float v = acc[i][jj];
            if (BIAS) v += bias[nc];
            if (ACT == 1) v = fmaxf(v, 0.f);
            C[(size_t)mm * N + nc] = v;
        }
    }
}

template<int ACT, bool BIAS>
static inline void gemm32(hipStream_t s, const float* A, const float* B, const float* bias,
                          float* C, int M, int N, int K)
{
    dim3 g((N + 63) / 64, (M + 63) / 64);
    gemm_k<ACT, BIAS><<<g, dim3(256), 0, s>>>(A, B, bias, C, M, N, K);
}

// ---- fp32 split-K ----
__global__ __launch_bounds__(256)
void gemm32_sk_k(const float* __restrict__ A, const float* __restrict__ B,
                 float* __restrict__ part, int M, int N, int K, int Kc)
{
    __shared__ float As[16][68];
    __shared__ float Bs[16][68];
    const int tid = threadIdx.x;
    const int bm0 = blockIdx.y * 64;
    const int bn0 = blockIdx.x * 64;
    const int sblk = blockIdx.z;
    const int kbeg = sblk * Kc;
    const int kend = (kbeg + Kc < K) ? kbeg + Kc : K;
    const int tx = tid & 15, ty = tid >> 4;
    const int lrow = tid >> 2;
    const int lk4  = (tid & 3) << 2;
    const int m = bm0 + lrow;
    const int nn = bn0 + lrow;
    const bool aok = m < M, bok = nn < N;
    float acc[4][4] = {{0.f,0.f,0.f,0.f},{0.f,0.f,0.f,0.f},{0.f,0.f,0.f,0.f},{0.f,0.f,0.f,0.f}};

    float4 va = {0.f,0.f,0.f,0.f}, vb = {0.f,0.f,0.f,0.f};
    if (aok) va = *(const float4*)(A + (size_t)m * K + kbeg + lk4);
    if (bok) vb = *(const float4*)(B + (size_t)nn * K + kbeg + lk4);

    for (int k0 = kbeg; k0 < kend; k0 += 16) {
        As[lk4+0][lrow]=va.x; As[lk4+1][lrow]=va.y; As[lk4+2][lrow]=va.z; As[lk4+3][lrow]=va.w;
        Bs[lk4+0][lrow]=vb.x; Bs[lk4+1][lrow]=vb.y; Bs[lk4+2][lrow]=vb.z; Bs[lk4+3][lrow]=vb.w;
        __syncthreads();
        float4 na = {0.f,0.f,0.f,0.f}, nb = {0.f,0.f,0.f,0.f};
        const bool more = (k0 + 16) < kend;
        if (more) {
            if (aok) na = *(const float4*)(A + (size_t)m * K + (k0 + 16 + lk4));
            if (bok) nb = *(const float4*)(B + (size_t)nn * K + (k0 + 16 + lk4));
        }
        #pragma unroll
        for (int k = 0; k < 16; k++) {
            const float4 av = *(const float4*)&As[k][ty << 2];
            const float4 bv = *(const float4*)&Bs[k][tx << 2];
            const float a0=av.x,a1=av.y,a2=av.z,a3=av.w;
            const float b0=bv.x,b1=bv.y,b2=bv.z,b3=bv.w;
            acc[0][0]=fmaf(a0,b0,acc[0][0]); acc[0][1]=fmaf(a0,b1,acc[0][1]);
            acc[0][2]=fmaf(a0,b2,acc[0][2]); acc[0][3]=fmaf(a0,b3,acc[0][3]);
            acc[1][0]=fmaf(a1,b0,acc[1][0]); acc[1][1]=fmaf(a1,b1,acc[1][1]);
            acc[1][2]=fmaf(a1,b2,acc[1][2]); acc[1][3]=fmaf(a1,b3,acc[1][3]);
            acc[2][0]=fmaf(a2,b0,acc[2][0]); acc[2][1]=fmaf(a2,b1,acc[2][1]);
            acc[2][2]=fmaf(a2,b2,acc[2][2]); acc[2][3]=fmaf(a2,b3,acc[2][3]);
            acc[3][0]=fmaf(a3,b0,acc[3][0]); acc[3][1]=fmaf(a3,b1,acc[3][1]);
            acc[3][2]=fmaf(a3,b2,acc[3][2]); acc[3][3]=fmaf(a3,b3,acc[3][3]);
        }
        __syncthreads();
        va = na; vb = nb;
    }
    float* P = part + (size_t)sblk * M * N;
    #pragma unroll
    for (int i = 0; i < 4; i++) {
        const int mm = bm0 + (ty << 2) + i;
        if (mm >= M) continue;
        #pragma unroll
        for (int jj = 0; jj < 4; jj++) {
            const int nc = bn0 + (tx << 2) + jj;
            if (nc >= N) continue;
            P[(size_t)mm * N + nc] = acc[i][jj];
        }
    }
}

template<int ACT, bool BIAS>
__global__ void sk_reduce_k(const float* __restrict__ part, const float* __restrict__ bias,
                            float* __restrict__ C, int MN, int N, int S)
{
    const int i4 = (blockIdx.x * 256 + threadIdx.x) * 4;
    if (i4 >= MN) return;
    float4 a = *(const float4*)(part + i4);
    for (int s = 1; s < S; s++) {
        const float4 b = *(const float4*)(part + (size_t)s * MN + i4);
        a.x += b.x; a.y += b.y; a.z += b.z; a.w += b.w;
    }
    if (BIAS) {
        const int n = i4 % N;
        a.x += bias[n]; a.y += bias[n + 1]; a.z += bias[n + 2]; a.w += bias[n + 3];
    }
    if (ACT == 1) {
        a.x = fmaxf(a.x, 0.f); a.y = fmaxf(a.y, 0.f);
        a.z = fmaxf(a.z, 0.f); a.w = fmaxf(a.w, 0.f);
    }
    *(float4*)(C + i4) = a;
}

template<int ACT, bool BIAS>
static inline void gemm32_sk(hipStream_t s, const float* A, const float* B, const float* bias,
                             float* C, float* part, int M, int N, int K, int S)
{
    const int Kc = ((K / S + 15) / 16) * 16;
    dim3 g((N + 63) / 64, (M + 63) / 64, S);
    gemm32_sk_k<<<g, dim3(256), 0, s>>>(A, B, part, M, N, K, Kc);
    const int MN = M * N;
    sk_reduce_k<ACT, BIAS><<<dim3((MN / 4 + 255) / 256), dim3(256), 0, s>>>(part, bias, C, MN, N, S);
}

// ============================ bf16 MFMA GEMM (depth-2 pipelined) ============================
// BT_NT: B is [N,K] row-major bf16.
// BT_CONV2: 3x3 SAME conv NHWC: B = bf16 image [imH*imW,256], A = weights [O][j*256+c].
enum { BT_NT = 0, BT_CONV2 = 2 };

template<int BT, int ACT, int BAX, bool ADDMAT>
__global__ __launch_bounds__(256)
void bgemm_k(const unsigned short* __restrict__ A, const unsigned short* __restrict__ B,
             const float* __restrict__ bias, const float* __restrict__ bias2, int nsplit,
             const float* __restrict__ Dmat, int Dld,
             float* __restrict__ C, int M, int N, int K, int imH, int imW)
{
    __shared__ unsigned short Asl[128][40];
    __shared__ unsigned short Bsl[128][40];
    const int tid  = threadIdx.x;
    const int lane = tid & 63;
    const int wid  = tid >> 6;
    const int quad = lane >> 4;
    const int l15  = lane & 15;
    const int wy = wid >> 1, wx = wid & 1;
    const int bm0 = blockIdx.y * 128;
    const int bn0 = blockIdx.x * 128;

    floatx4 zero = {0.f, 0.f, 0.f, 0.f};
    floatx4 acc[4][4];
    #pragma unroll
    for (int i = 0; i < 4; i++)
        #pragma unroll
        for (int j = 0; j < 4; j++) acc[i][j] = zero;

    const int srow = tid >> 1;
    const int skc  = (tid & 1) << 4;
    const int mrow = bm0 + srow;
    const bool aok = mrow < M;
    const int nrow = bn0 + srow;
    const bool bok = nrow < N;

    int cy = 0, cx = 0; bool cok = false;
    if (BT == BT_CONV2) {
        cok = nrow < N;
        const int pp = cok ? nrow : 0;
        cy = pp / imW; cx = pp - cy * imW;
    }

    auto loadA = [&](int k0, uint4& r0, uint4& r1) {
        r0 = (uint4){0,0,0,0}; r1 = (uint4){0,0,0,0};
        if (aok) {
            const uint4* p = (const uint4*)(A + (size_t)mrow * K + k0 + skc);
            r0 = p[0]; r1 = p[1];
        }
    };
    auto loadB = [&](int k0, uint4& r0, uint4& r1) {
        r0 = (uint4){0,0,0,0}; r1 = (uint4){0,0,0,0};
        if (BT == BT_NT) {
            if (bok) {
                const uint4* p = (const uint4*)(B + (size_t)nrow * K + k0 + skc);
                r0 = p[0]; r1 = p[1];
            }
        } else {
            const int jj = k0 >> 8;
            const int j3 = jj / 3;
            const int dy = j3 - 1, dx = jj - j3 * 3 - 1;
            const int c0 = k0 & 255;
            const int yy = cy + dy, xx = cx + dx;
            if (cok && (unsigned)yy < (unsigned)imH && (unsigned)xx < (unsigned)imW) {
                const uint4* p = (const uint4*)(B + ((size_t)yy * imW + xx) * 256 + c0 + skc);
                r0 = p[0]; r1 = p[1];
            }
        }
    };
    auto stage = [&](const uint4& a0, const uint4& a1, const uint4& b0, const uint4& b1) {
        *(uint4*)&Asl[srow][skc]     = a0;
        *(uint4*)&Asl[srow][skc + 8] = a1;
        *(uint4*)&Bsl[srow][skc]     = b0;
        *(uint4*)&Bsl[srow][skc + 8] = b1;
    };
    auto compute = [&]() {
        short8 af[4], bfr[4];
        #pragma unroll
        for (int i = 0; i < 4; i++)
            af[i] = *(const short8*)&Asl[wy * 64 + i * 16 + l15][quad * 8];
        #pragma unroll
        for (int j = 0; j < 4; j++)
            bfr[j] = *(const short8*)&Bsl[wx * 64 + j * 16 + l15][quad * 8];
        #pragma unroll
        for (int i = 0; i < 4; i++)
            #pragma unroll
            for (int j = 0; j < 4; j++)
                acc[i][j] = __builtin_amdgcn_mfma_f32_16x16x32_bf16(af[i], bfr[j], acc[i][j], 0, 0, 0);
    };

    uint4 a00, a01, b00, b01, a10, a11, b10, b11;
    loadA(0, a00, a01); loadB(0, b00, b01);
    if (32 < K) { loadA(32, a10, a11); loadB(32, b10, b11); }

    for (int k0 = 0; k0 < K; k0 += 64) {
        stage(a00, a01, b00, b01);
        __syncthreads();
        if (k0 + 64 < K) { loadA(k0 + 64, a00, a01); loadB(k0 + 64, b00, b01); }
        compute();
        __syncthreads();
        if (k0 + 32 < K) {
            stage(a10, a11, b10, b11);
            __syncthreads();
            if (k0 + 96 < K) { loadA(k0 + 96, a10, a11); loadB(k0 + 96, b10, b11); }
            compute();
            __syncthreads();
        }
    }

    #pragma unroll
    for (int i = 0; i < 4; i++) {
        #pragma unroll
        for (int r = 0; r < 4; r++) {
            const int m = bm0 + wy * 64 + i * 16 + quad * 4 + r;
            if (m >= M) continue;
            #pragma unroll
            for (int j = 0; j < 4; j++) {
                const int n = bn0 + wx * 64 + j * 16 + l15;
                if (n >= N) continue;
                float v = acc[i][j][r];
                if (bias != nullptr)
                    v += (BAX == 0) ? bias[m] : (n < nsplit ? bias[n] : bias2[n - nsplit]);
                if (ACT == 1) v = fmaxf(v, 0.f);
                if (ADDMAT) v += Dmat[(size_t)m * Dld + n];
                C[(size_t)m * N + n] = v;
            }
        }
    }
}

template<int BT, int ACT, int BAX, bool ADDMAT>
static inline void bgemm(hipStream_t s, const unsigned short* A, const unsigned short* B,
                         const float* bias, const float* bias2, int nsplit,
                         const float* D, int Dld, float* C,
                         int M, int N, int K, int imH = 0, int imW = 0)
{
    dim3 g((N + 127) / 128, (M + 127) / 128);
    bgemm_k<BT, ACT, BAX, ADDMAT><<<g, dim3(256), 0, s>>>(A, B, bias, bias2, nsplit,
                                                          D, Dld, C, M, N, K, imH, imW);
}

// ---- bf16 split-K (NT only): partials fp32 ----
__global__ __launch_bounds__(256)
void bgemm_sk_k(const unsigned short* __restrict__ A, const unsigned short* __restrict__ B,
                float* __restrict__ part, int M, int N, int K, int Kc)
{
    __shared__ unsigned short Asl[128][40];
    __shared__ unsigned short Bsl[128][40];
    const int tid  = threadIdx.x;
    const int lane = tid & 63;
    const int wid  = tid >> 6;
    const int quad = lane >> 4;
    const int l15  = lane & 15;
    const int wy = wid >> 1, wx = wid & 1;
    const int bm0 = blockIdx.y * 128;
    const int bn0 = blockIdx.x * 128;
    const int kbeg = blockIdx.z * Kc;
    const int kend = (kbeg + Kc < K) ? kbeg + Kc : K;

    floatx4 zero = {0.f, 0.f, 0.f, 0.f};
    floatx4 acc[4][4];
    #pragma unroll
    for (int i = 0; i < 4; i++)
        #pragma unroll
        for (int j = 0; j < 4; j++) acc[i][j] = zero;

    const int srow = tid >> 1;
    const int skc  = (tid & 1) << 4;
    const int mrow = bm0 + srow;
    const bool aok = mrow < M;
    const int nrow = bn0 + srow;
    const bool bok = nrow < N;

    auto loadA = [&](int k0, uint4& r0, uint4& r1) {
        r0 = (uint4){0,0,0,0}; r1 = (uint4){0,0,0,0};
        if (aok) {
            const uint4* p = (const uint4*)(A + (size_t)mrow * K + k0 + skc);
            r0 = p[0]; r1 = p[1];
        }
    };
    auto loadB = [&](int k0, uint4& r0, uint4& r1) {
        r0 = (uint4){0,0,0,0}; r1 = (uint4){0,0,0,0};
        if (bok) {
            const uint4* p = (const uint4*)(B + (size_t)nrow * K + k0 + skc);
            r0 = p[0]; r1 = p[1];
        }
    };
    auto stage = [&](const uint4& a0, const uint4& a1, const uint4& b0, const uint4& b1) {
        *(uint4*)&Asl[srow][skc]     = a0;
        *(uint4*)&Asl[srow][skc + 8] = a1;
        *(uint4*)&Bsl[srow][skc]     = b0;
        *(uint4*)&Bsl[srow][skc + 8] = b1;
    };
    auto compute = [&]() {
        short8 af[4], bfr[4];
        #pragma unroll
        for (int i = 0; i < 4; i++)
            af[i] = *(const short8*)&Asl[wy * 64 + i * 16 + l15][quad * 8];
        #pragma unroll
        for (int j = 0; j < 4; j++)
            bfr[j] = *(const short8*)&Bsl[wx * 64 + j * 16 + l15][quad * 8];
        #pragma unroll
        for (int i = 0; i < 4; i++)
            #pragma unroll
            for (int j = 0; j < 4; j++)
                acc[i][j] = __builtin_amdgcn_mfma_f32_16x16x32_bf16(af[i], bfr[j], acc[i][j], 0, 0, 0);
    };

    uint4 a00, a01, b00, b01, a10, a11, b10, b11;
    loadA(kbeg, a00, a01); loadB(kbeg, b00, b01);
    if (kbeg + 32 < kend) { loadA(kbeg + 32, a10, a11); loadB(kbeg + 32, b10, b11); }

    for (int k0 = kbeg; k0 < kend; k0 += 64) {
        stage(a00, a01, b00, b01);
        __syncthreads();
        if (k0 + 64 < kend) { loadA(k0 + 64, a00, a01); loadB(k0 + 64, b00, b01); }
        compute();
        __syncthreads();
        if (k0 + 32 < kend) {
            stage(a10, a11, b10, b11);
            __syncthreads();
            if (k0 + 96 < kend) { loadA(k0 + 96, a10, a11); loadB(k0 + 96, b10, b11); }
            compute();
            __syncthreads();
        }
    }

    float* P = part + (size_t)blockIdx.z * M * N;
    #pragma unroll
    for (int i = 0; i < 4; i++) {
        #pragma unroll
        for (int r = 0; r < 4; r++) {
            const int m = bm0 + wy * 64 + i * 16 + quad * 4 + r;
            if (m >= M) continue;
            #pragma unroll
            for (int j = 0; j < 4; j++) {
                const int n = bn0 + wx * 64 + j * 16 + l15;
                if (n >= N) continue;
                P[(size_t)m * N + n] = acc[i][j][r];
            }
        }
    }
}

// reduce S slabs + dual-bias(axis n) + relu + addmat
template<int ACT, bool ADDMAT>
__global__ void bsk_reduce_k(const float* __restrict__ part,
                             const float* __restrict__ bias, const float* __restrict__ bias2,
                             int nsplit, const float* __restrict__ Dmat, int Dld,
                             float* __restrict__ C, int MN, int N, int S)
{
    const int i4 = (blockIdx.x * 256 + threadIdx.x) * 4;
    if (i4 >= MN) return;
    float4 a = *(const float4*)(part + i4);
    for (int s = 1; s < S; s++) {
        const float4 b = *(const float4*)(part + (size_t)s * MN + i4);
        a.x += b.x; a.y += b.y; a.z += b.z; a.w += b.w;
    }
    const int n = i4 % N;
    const float* bb = (n < nsplit) ? (bias + n) : (bias2 + n - nsplit);
    a.x += bb[0]; a.y += bb[1]; a.z += bb[2]; a.w += bb[3];
    if (ACT == 1) {
        a.x = fmaxf(a.x, 0.f); a.y = fmaxf(a.y, 0.f);
        a.z = fmaxf(a.z, 0.f); a.w = fmaxf(a.w, 0.f);
    }
    if (ADDMAT) {
        const int m = i4 / N;
        const float4 d = *(const float4*)(Dmat + (size_t)m * Dld + n);
        a.x += d.x; a.y += d.y; a.z += d.z; a.w += d.w;
    }
    *(float4*)(C + i4) = a;
}

template<int ACT, bool ADDMAT>
static inline void bgemm_sk(hipStream_t s, const unsigned short* A, const unsigned short* B,
                            const float* bias, const float* bias2, int nsplit,
                            const float* D, int Dld, float* C, float* part,
                            int M, int N, int K, int S)
{
    const int Kc = ((K / S + 31) / 32) * 32;
    dim3 g((N + 127) / 128, (M + 127) / 128, S);
    bgemm_sk_k<<<g, dim3(256), 0, s>>>(A, B, part, M, N, K, Kc);
    const int MN = M * N;
    bsk_reduce_k<ACT, ADDMAT><<<dim3((MN / 4 + 255) / 256), dim3(256), 0, s>>>(
        part, bias, bias2, nsplit, D, Dld, C, MN, N, S);
}

// ============================ cast / reorder kernels ============================
__global__ void cast_bf16_k(const float* __restrict__ in, unsigned short* __restrict__ out, int total)
{
    const int i4 = (blockIdx.x * 256 + threadIdx.x) * 4;
    if (i4 + 4 <= total) {
        const float4 v = *(const float4*)(in + i4);
        ushort4 o;
        o.x = f2bf(v.x); o.y = f2bf(v.y); o.z = f2bf(v.z); o.w = f2bf(v.w);
        *(ushort4*)(out + i4) = o;
    } else {
        for (int i = i4; i < total; i++) out[i] = f2bf(in[i]);
    }
}

static inline void cast_bf(hipStream_t s, const float* in, unsigned short* out, int total)
{
    cast_bf16_k<<<dim3((total / 4 + 255) / 256), dim3(256), 0, s>>>(in, out, total);
}

__device__ __forceinline__ void cast_t_body(const float* __restrict__ in,
                                            unsigned short* __restrict__ out, int K, int N)
{
    __shared__ float tile[64][65];
    const int n0 = blockIdx.x * 64;
    const int k0 = blockIdx.y * 64;
    const int t = threadIdx.x;
    const int r = t >> 2;
    const int c4 = (t & 3) << 4;
    {
        const int k = k0 + r;
        if (k < K && n0 + c4 + 16 <= N) {
            const float4* p = (const float4*)(in + (size_t)k * N + n0 + c4);
            *(float4*)&tile[r][c4]      = p[0];
            *(float4*)&tile[r][c4 + 4]  = p[1];
            *(float4*)&tile[r][c4 + 8]  = p[2];
            *(float4*)&tile[r][c4 + 12] = p[3];
        } else {
            for (int i = 0; i < 16; i++)
                tile[r][c4 + i] = (k < K && n0 + c4 + i < N) ? in[(size_t)k * N + n0 + c4 + i] : 0.f;
        }
    }
    __syncthreads();
    const int n = n0 + r;
    if (n >= N) return;
    unsigned short tmp[16];
    #pragma unroll
    for (int i = 0; i < 16; i++) tmp[i] = f2bf(tile[c4 + i][r]);
    if (k0 + 64 <= K) {
        *(uint4*)(out + (size_t)n * K + k0 + c4)     = *(uint4*)&tmp[0];
        *(uint4*)(out + (size_t)n * K + k0 + c4 + 8) = *(uint4*)&tmp[8];
    } else {
        for (int i = 0; i < 16; i++)
            if (k0 + c4 + i < K) out[(size_t)n * K + k0 + c4 + i] = tmp[i];
    }
}

__global__ void cast_t_k(const float* __restrict__ in, unsigned short* __restrict__ out, int K, int N)
{
    cast_t_body(in, out, K, N);
}

__global__ void cast_t2_k(const float* __restrict__ in0, const float* __restrict__ in1,
                          unsigned short* __restrict__ out0, unsigned short* __restrict__ out1,
                          int K, int N)
{
    if (blockIdx.z == 0) cast_t_body(in0, out0, K, N);
    else                 cast_t_body(in1, out1, K, N);
}

static inline void cast_t(hipStream_t s, const float* in, unsigned short* out, int K, int N)
{
    cast_t_k<<<dim3((N + 63) / 64, (K + 63) / 64), dim3(256), 0, s>>>(in, out, K, N);
}

static inline void cast_t2(hipStream_t s, const float* in0, const float* in1,
                           unsigned short* out0, unsigned short* out1, int K, int N)
{
    cast_t2_k<<<dim3((N + 63) / 64, (K + 63) / 64, 2), dim3(256), 0, s>>>(in0, in1, out0, out1, K, N);
}

__global__ void reorder_w3_k(const float* __restrict__ in, unsigned short* __restrict__ out)
{
    const int idx = blockIdx.x * 256 + threadIdx.x;
    if (idx >= 589824) return;
    const int o = idx / 2304;
    const int r = idx - o * 2304;
    const int j = r >> 8;
    const int c = r & 255;
    out[idx] = f2bf(in[(size_t)o * 2304 + c * 9 + j]);
}

// ============================ small kernels ============================
__global__ void extract_patches_k(const float* __restrict__ f, float* __restrict__ patches,
                                  int nw, int H, int total)
{
    int idx = blockIdx.x * 256 + threadIdx.x;
    if (idx >= total) return;
    int q = idx % 6400;
    int p = idx / 6400;
    int c = q / 25;
    int rem = q - c * 25;
    int a = rem / 5, b = rem - (rem / 5) * 5;
    int ih = p / nw, iw = p - (p / nw) * nw;
    patches[idx] = f[(size_t)c * H * H + (size_t)(ih * 5 + a) * H + (iw * 5 + b)];
}

__global__ void topk_feat_k(const float* __restrict__ score, int* __restrict__ srcCols, int n)
{
    const int r = blockIdx.x;
    const int lane = threadIdx.x;
    const float* row = score + (size_t)r * n;
    int   sel[KNN];
    float selv[KNN];
    #pragma unroll
    for (int t = 0; t < KNN; t++) {
        float best = -__builtin_huge_valf();
        int   bidx = 0x7fffffff;
        for (int c = lane; c < n; c += 64) {
            bool taken = false;
            #pragma unroll
            for (int u = 0; u < KNN; u++)
                if (u < t && sel[u] == c) taken = true;
            if (taken) continue;
            float v = row[c];
            if (v > best || (v == best && c < bidx)) { best = v; bidx = c; }
        }
        #pragma unroll
        for (int off = 32; off > 0; off >>= 1) {
            float ov = __shfl_down(best, off);
            int   oi = __shfl_down(bidx, off);
            if (ov > best || (ov == best && oi < bidx)) { best = ov; bidx = oi; }
        }
        best = __shfl(best, 0);
        bidx = __shfl(bidx, 0);
        sel[t] = bidx; selv[t] = best;
    }
    if (lane < KNN) {
        int c = -1; float v = 0.f;
        #pragma unroll
        for (int t = 0; t < KNN; t++)
            if (lane == t) { c = sel[t]; v = selv[t]; }
        srcCols[r * KNN + lane] = (c > r && v != 0.0f) ? c : -1;
    }
}

__global__ void topk_spatial_k(int* __restrict__ srcCols, int n, int nw)
{
    const int r = blockIdx.x;
    const int lane = threadIdx.x;
    const int ri = r / nw, rj = r - (r / nw) * nw;
    int sel[KNN];
    #pragma unroll
    for (int t = 0; t < KNN; t++) {
        int bkey = 0x7fffffff;
        for (int c = lane; c < n; c += 64) {
            bool taken = false;
            #pragma unroll
            for (int u = 0; u < KNN; u++)
                if (u < t && sel[u] == c) taken = true;
            if (taken) continue;
            const int ci = c / nw, cj = c - (c / nw) * nw;
            const int dy = (ri - ci) * 5, dx = (rj - cj) * 5;
            const int d2 = dy * dy + dx * dx;
            const int key = (d2 << 11) | c;
            if (key < bkey) bkey = key;
        }
        #pragma unroll
        for (int off = 32; off > 0; off >>= 1) {
            int ok = __shfl_down(bkey, off);
            if (ok < bkey) bkey = ok;
        }
        bkey = __shfl(bkey, 0);
        sel[t] = bkey & 2047;
    }
    if (lane < KNN) {
        int c = -1;
        #pragma unroll
        for (int t = 0; t < KNN; t++) if (lane == t) c = sel[t];
        srcCols[r * KNN + lane] = (c > r) ? c : -1;
    }
}

// fused GATv2: logits + softmax + aggregate in one kernel.
// x: base of fused xl|xr rows (stride xstride); xl at +0, xr at +xroff.
// One wave per (node r, head h); lane owns d0=4*lane..+3.
__global__ void gat_fused_k(const float* __restrict__ x, int xroff, int xstride,
                            const float* __restrict__ att,
                            const int* __restrict__ srcCols, const float* __restrict__ bias,
                            float* __restrict__ out, int n, int H, int ostride, int ooff)
{
    const int wid = (blockIdx.x * blockDim.x + threadIdx.x) >> 6;
    const int lane = threadIdx.x & 63;
    if (wid >= n * H) return;
    const int h = wid % H;
    const int r = wid / H;
    const int d0 = lane << 2;

    const float4 xrf  = *(const float4*)(x + (size_t)r * xstride + xroff + h * 256 + d0);
    const float4 attf = *(const float4*)(att + (size_t)h * 256 + d0);

    int srcs[8];
    #pragma unroll
    for (int s_ = 0; s_ < KNN; s_++) srcs[s_] = srcCols[r * KNN + s_];
    srcs[7] = r;

    float4 xlf[8];
    float  e[8];
    #pragma unroll
    for (int s_ = 0; s_ < 8; s_++) {
        const int c = srcs[s_];
        float4 v = {0.f, 0.f, 0.f, 0.f};
        if (c >= 0) v = *(const float4*)(x + (size_t)c * xstride + h * 256 + d0);
        xlf[s_] = v;
        float m, p = 0.f;
        m = v.x + xrf.x; m = (m > 0.f) ? m : 0.2f * m; p += m * attf.x;
        m = v.y + xrf.y; m = (m > 0.f) ? m : 0.2f * m; p += m * attf.y;
        m = v.z + xrf.z; m = (m > 0.f) ? m : 0.2f * m; p += m * attf.z;
        m = v.w + xrf.w; m = (m > 0.f) ? m : 0.2f * m; p += m * attf.w;
        #pragma unroll
        for (int off = 32; off > 0; off >>= 1) p += __shfl_down(p, off);
        e[s_] = __shfl(p, 0);
    }

    float mx = e[7];
    #pragma unroll
    for (int s_ = 0; s_ < KNN; s_++)
        if (srcs[s_] >= 0) mx = fmaxf(mx, e[s_]);
    float a[8], denom = 0.f;
    #pragma unroll
    for (int s_ = 0; s_ < 8; s_++) {
        a[s_] = (s_ == 7 || srcs[s_] >= 0) ? expf(e[s_] - mx) : 0.f;
        denom += a[s_];
    }
    const float inv = 1.f / (denom + 1e-16f);

    float o0 = 0.f, o1 = 0.f, o2 = 0.f, o3 = 0.f;
    #pragma unroll
    for (int s_ = 0; s_ < 8; s_++) {
        const float al = a[s_] * inv;
        o0 = fmaf(al, xlf[s_].x, o0); o1 = fmaf(al, xlf[s_].y, o1);
        o2 = fmaf(al, xlf[s_].z, o2); o3 = fmaf(al, xlf[s_].w, o3);
    }
    const float* bb = bias + (size_t)h * 256 + d0;
    o0 += bb[0]; o1 += bb[1]; o2 += bb[2]; o3 += bb[3];
    o0 = (o0 > 0.f) ? o0 : (expf(o0) - 1.f);
    o1 = (o1 > 0.f) ? o1 : (expf(o1) - 1.f);
    o2 = (o2 > 0.f) ? o2 : (expf(o2) - 1.f);
    o3 = (o3 > 0.f) ? o3 : (expf(o3) - 1.f);
    float4 res = {o0, o1, o2, o3};
    *(float4*)(out + (size_t)r * ostride + ooff + (size_t)h * 256 + d0) = res;
}

__global__ void scatter_convT_k(const float* __restrict__ f, const float* __restrict__ U,
                                const float* __restrict__ bias, float* __restrict__ xs,
                                int nw, int H, int total)
{
    int idx = blockIdx.x * 256 + threadIdx.x;
    if (idx >= total) return;
    int x = idx % H;
    int t = idx / H;
    int y = t % H;
    int o = t / H;
    int j = y / 5, a = y - j * 5;
    int i = x / 5, b = x - i * 5;
    int p = i * nw + j;
    float v = U[(size_t)p * 6400 + o * 25 + a * 5 + b] + bias[o];
    v = fmaxf(v, 0.f);
    xs[idx] = f[idx] + v;
}

__global__ void upsample_add_k(float* __restrict__ acc, const float* __restrict__ last,
                               int H, int Hs, int total)
{
    int idx = blockIdx.x * 256 + threadIdx.x;
    if (idx >= total) return;
    int x = idx % H;
    int t = idx / H;
    int y = t % H;
    int c = t / H;
    acc[idx] += last[(size_t)c * Hs * Hs + (size_t)(y >> 1) * Hs + (x >> 1)];
}

// ============================ orchestration ============================
static void run_level(void* const* d_in, float* ws, int l, int H, hipStream_t s)
{
    const float* f = (const float*)d_in[l];
    const int nh = H / 5, nw = nh, n = nh * nw, HW = H * H;

    const float* convT_w = (const float*)d_in[6]  + (size_t)l * 1638400;
    const float* convT_b = (const float*)d_in[7]  + l * 256;
    const float* conv1_w = (const float*)d_in[8]  + (size_t)l * 1638400;
    const float* conv1_b = (const float*)d_in[9]  + l * 256;
    const float* fc2_w   = (const float*)d_in[10] + (size_t)l * 65536;
    const float* fc2_b   = (const float*)d_in[11] + l * 256;
    const float* fc3_w   = (const float*)d_in[12] + (size_t)l * 131072;
    const float* fc3_b   = (const float*)d_in[13] + l * 256;
    const float* g1_wl   = (const float*)d_in[14] + (size_t)l * 524288;
    const float* g1_bl   = (const float*)d_in[15] + l * 2048;
    const float* g1_wr   = (const float*)d_in[16] + (size_t)l * 524288;
    const float* g1_br   = (const float*)d_in[17] + l * 2048;
    const float* g1_att  = (const float*)d_in[18] + l * 2048;
    const float* g1_bias = (const float*)d_in[19] + l * 2048;
    const float* g2_wl   = (const float*)d_in[20] + (size_t)l * 524288;
    const float* g2_bl   = (const float*)d_in[21] + l * 256;
    const float* g2_wr   = (const float*)d_in[22] + (size_t)l * 524288;
    const float* g2_br   = (const float*)d_in[23] + l * 256;
    const float* g2_att  = (const float*)d_in[24] + l * 256;
    const float* g2_bias = (const float*)d_in[25] + l * 256;
    const float* g3_wl   = (const float*)d_in[26] + (size_t)l * 524288;
    const float* g3_bl   = (const float*)d_in[27] + l * 2048;
    const float* g3_wr   = (const float*)d_in[28] + (size_t)l * 524288;
    const float* g3_br   = (const float*)d_in[29] + l * 2048;
    const float* g3_att  = (const float*)d_in[30] + l * 2048;
    const float* g3_bias = (const float*)d_in[31] + l * 2048;
    const float* g4_wl   = (const float*)d_in[32] + (size_t)l * 524288;
    const float* g4_bl   = (const float*)d_in[33] + l * 256;
    const float* g4_wr   = (const float*)d_in[34] + (size_t)l * 524288;
    const float* g4_br   = (const float*)d_in[35] + l * 256;
    const float* g4_att  = (const float*)d_in[36] + l * 256;
    const float* g4_bias = (const float*)d_in[37] + l * 256;

    float* patches = ws + OFF_ARENA;   // also split-K partials / U
    float* xs    = ws + (l == 0 ? OFF_XS0 : OFF_XS1);
    float* emb   = ws + OFF_EMB;
    float* emb2  = ws + OFF_EMB2;
    float* score = ws + OFF_LAST;
    float* xlr   = ws + OFF_XL;        // [n][4096] fused xl|xr (g1/g3); fp32 split-K partials
    float* h1    = ws + OFF_H1;
    float* xlr2  = ws + OFF_XL2;       // [n][512]  fused xl|xr (g2/g4)
    float* cat   = ws + OFF_CAT;
    float* hc    = ws + OFF_HC;
    int* srcF = (int*)(ws + OFF_SRCF);
    int* srcS = (int*)(ws + OFF_SRCS);
    unsigned short* ba = (unsigned short*)(ws + OFF_BF_A);
    unsigned short* bw = (unsigned short*)(ws + OFF_BF_W);
    float* part = ws + OFF_ARENA;      // bf16 split-K partials (patches dead after conv1)

    { int tot = n * 6400;
      extract_patches_k<<<dim3((tot + 255) / 256), dim3(256), 0, s>>>(f, patches, nw, H, tot); }

    // exact fp32 path feeding the top-k graph selection
    gemm32_sk<1, true>(s, patches, conv1_w, conv1_b, emb, xlr, n, 256, 6400, 16);
    gemm32<1, true>(s, emb, fc2_w, fc2_b, emb2, n, 256, 256);
    gemm32<0, false>(s, emb2, emb2, nullptr, score, n, n, 256);
    topk_feat_k<<<dim3(n), dim3(64), 0, s>>>(score, srcF, n);
    topk_spatial_k<<<dim3(n), dim3(64), 0, s>>>(srcS, n, nw);

    const int gatw1 = n * 8;   // waves for H=8 GATs
    const int gatw2 = n;       // waves for H=1 GATs

    // g1: feature graph, emb2 -> h1 [n,2048], heads=8 (fused wl|wr, N=4096)
    cast_bf(s, emb2, ba, n * 256);
    cast_t2(s, g1_wl, g1_wr, bw, bw + 2048 * 256, 256, 2048);
    if (n >= 1024)
        bgemm<BT_NT, 0, 1, false>(s, ba, bw, g1_bl, g1_br, 2048, nullptr, 0, xlr, n, 4096, 256);
    else
        bgemm_sk<0, false>(s, ba, bw, g1_bl, g1_br, 2048, nullptr, 0, xlr, part, n, 4096, 256, 2);
    gat_fused_k<<<dim3((gatw1 + 3) / 4), dim3(256), 0, s>>>(xlr, 2048, 4096, g1_att, srcF, g1_bias, h1, n, 8, 2048, 0);

    // g2: feature graph, h1 -> cat[:, :256], heads=1 (fused, N=512, split-K 8)
    cast_bf(s, h1, ba, n * 2048);
    cast_t2(s, g2_wl, g2_wr, bw, bw + 256 * 2048, 2048, 256);
    bgemm_sk<0, false>(s, ba, bw, g2_bl, g2_br, 256, nullptr, 0, xlr2, part, n, 512, 2048, 8);
    gat_fused_k<<<dim3((gatw2 + 3) / 4), dim3(256), 0, s>>>(xlr2, 256, 512, g2_att, srcF, g2_bias, cat, n, 1, 512, 0);

    // g3: spatial graph, emb2 -> h1 [n,2048], heads=8
    cast_bf(s, emb2, ba, n * 256);
    cast_t2(s, g3_wl, g3_wr, bw, bw + 2048 * 256, 256, 2048);
    if (n >= 1024)
        bgemm<BT_NT, 0, 1, false>(s, ba, bw, g3_bl, g3_br, 2048, nullptr, 0, xlr, n, 4096, 256);
    else
        bgemm_sk<0, false>(s, ba, bw, g3_bl, g3_br, 2048, nullptr, 0, xlr, part, n, 4096, 256, 2);
    gat_fused_k<<<dim3((gatw1 + 3) / 4), dim3(256), 0, s>>>(xlr, 2048, 4096, g3_att, srcS, g3_bias, h1, n, 8, 2048, 0);

    // g4: spatial graph, h1 -> cat[:, 256:], heads=1
    cast_bf(s, h1, ba, n * 2048);
    cast_t2(s, g4_wl, g4_wr, bw, bw + 256 * 2048, 2048, 256);
    bgemm_sk<0, false>(s, ba, bw, g4_bl, g4_br, 256, nullptr, 0, xlr2, part, n, 512, 2048, 8);
    gat_fused_k<<<dim3((gatw2 + 3) / 4), dim3(256), 0, s>>>(xlr2, 256, 512, g4_att, srcS, g4_bias, cat, n, 1, 512, 256);

    // hc = relu(cat @ fc3_w^T + fc3_b) + h2   (split-K 4)
    cast_bf(s, cat, ba, n * 512);
    cast_bf(s, fc3_w, bw, 131072);
    bgemm_sk<1, true>(s, ba, bw, fc3_b, fc3_b, 256, cat + 256, 512, hc, part, n, 256, 512, 4);
    // U = hc @ convT_w
    cast_bf(s, hc, ba, n * 256);
    cast_t(s, convT_w, bw, 256, 6400);
    bgemm<BT_NT, 0, 1, false>(s, ba, bw, nullptr, nullptr, 0, nullptr, 0, patches, n, 6400, 256);
    { int tot = 256 * HW;
      scatter_convT_k<<<dim3((tot + 255) / 256), dim3(256), 0, s>>>(f, patches, convT_b, xs, nw, H, tot); }
}

extern "C" void kernel_launch(void* const* d_in, const int* in_sizes, int n_in,
                              void* d_out, int out_size, void* d_ws, size_t ws_size,
                              hipStream_t stream)
{
    float* ws  = (float*)d_ws;
    float* out = (float*)d_out;

    run_level(d_in, ws, 0, 200, stream);
    run_level(d_in, ws, 1, 100, stream);

    const float* inner_w = (const float*)d_in[2];
    const float* inner_b = (const float*)d_in[3];
    const float* layer_w = (const float*)d_in[4];
    const float* layer_b = (const float*)d_in[5];
    float* xs0    = ws + OFF_XS0;
    float* xs1    = ws + OFF_XS1;
    float* last   = ws + OFF_LAST;
    float* inner0 = ws + OFF_ARENA;
    unsigned short* bimg = (unsigned short*)(ws + OFF_XL);               // [HW,256] bf16
    unsigned short* bw1  = (unsigned short*)(ws + OFF_BF_W);             // 1x1 weights
    unsigned short* bwc  = (unsigned short*)(ws + OFF_BF_W + 100000);    // conv3x3 reordered

    // ---- level 1: last = conv1x1(xs1); out1 = conv3x3(last) ----
    cast_t(stream, xs1, bimg, 256, 10000);
    cast_bf(stream, inner_w + 65536, bw1, 65536);
    bgemm<BT_NT, 0, 0, false>(stream, bw1, bimg, inner_b + 256, nullptr, 0, nullptr, 0,
                              last, 256, 10000, 256);
    reorder_w3_k<<<dim3((589824 + 255) / 256), dim3(256), 0, stream>>>(layer_w + 589824, bwc);
    cast_t(stream, last, bimg, 256, 10000);
    bgemm<BT_CONV2, 0, 0, false>(stream, bwc, bimg, layer_b + 256, nullptr, 0, nullptr, 0,
                                 out + 10240000, 256, 10000, 2304, 100, 100);

    // ---- level 0: inner0 = conv1x1(xs0) + nearest(last); out0 = conv3x3(inner0) ----
    cast_t(stream, xs0, bimg, 256, 40000);
    cast_bf(stream, inner_w, bw1, 65536);
    bgemm<BT_NT, 0, 0, false>(stream, bw1, bimg, inner_b, nullptr, 0, nullptr, 0,
                              inner0, 256, 40000, 256);
    { int tot = 256 * 40000;
      upsample_add_k<<<dim3((tot + 255) / 256), dim3(256), 0, stream>>>(inner0, last, 200, 100, tot); }
    reorder_w3_k<<<dim3((589824 + 255) / 256), dim3(256), 0, stream>>>(layer_w, bwc);
    cast_t(stream, inner0, bimg, 256, 40000);
    bgemm<BT_CONV2, 0, 0, false>(stream, bwc, bimg, layer_b, nullptr, 0, nullptr, 0,
                                 out, 256, 40000, 2304, 200, 200);
}